// Round 3
// baseline (4631.908 us; speedup 1.0000x reference)
//
#include <hip/hip_runtime.h>

// ---------------------------------------------------------------------------
// MashDecoderV2: 256-layer mamba stack (L=400, D=40) + 65536-query cross-attn
// decoder. f32 throughout (threshold 1.56e-2; absmax 2e-3).
//
// Round-12 = Round-10 structure + REAL spill fix (single change vs R11):
//   __attribute__((amdgpu_waves_per_eu(2, 3))) on mamba_pipe.
//   R10/R11: 640-thread blocks made the allocator target 6 waves/EU ->
//   total (unified VGPR+AGPR) budget 512/6 = 85 regs; the ~132 persistent
//   floats/thread (w_in_r/w_xp_r/w_out_r) spilled to SCRATCH (WRITE_SIZE
//   27 -> 42.6 MB, +24 MB memory traffic on the critical path; mamba
//   1820 -> 4264 us). __launch_bounds__(,2) was silently ineffective
//   (VGPR 84 -> 84, byte-identical counters). waves_per_eu(2,3) caps
//   occupancy at 3 waves/EU -> per-wave budget 512/3 = 170 regs; overflow
//   lands in AGPRs (register moves) as in R9. Cost: 1 block/CU, so PE
//   blocks run on the other ~128 CUs instead of co-residing (231 blocks
//   <= 256 CUs, still fully concurrent; pipeline residency guaranteed).
//
// Structure (from R10): 2 layers per block, 128 blocks x 640 threads, two
//   wave-aligned 320-thread groups pipelined one chunk apart; intra-block
//   handoff via double-buffered LDS; only group 1 touches global + flags ->
//   inter-block MALL hops 255 -> 127 at identical 355-stage pipeline depth.
// ---------------------------------------------------------------------------

#define CH 4
#define NCHUNK 100       // 400 / CH
#define TPB1 640         // 2 layer-groups x 320
#define NLB 128          // fused layer blocks (2 layers each)

typedef unsigned long long u64;

__device__ __forceinline__ u64 pack2(float a, float b) {
  return ((u64)__float_as_uint(b) << 32) | (u64)__float_as_uint(a);
}
__device__ __forceinline__ float unplo(u64 a) {
  return __uint_as_float((unsigned)a);
}
__device__ __forceinline__ float unphi(u64 a) {
  return __uint_as_float((unsigned)(a >> 32));
}

__global__ void init_flags(int* __restrict__ flags) {
  int i = blockIdx.x * 256 + threadIdx.x;
  if (i < 256 * 16) flags[i] = 0;
}

__global__ __launch_bounds__(TPB1)
__attribute__((amdgpu_waves_per_eu(2, 3)))
void mamba_pipe(
    const float* __restrict__ mash,
    const float* __restrict__ g_norm_w,   // (256,40)
    const float* __restrict__ g_in_w,     // (256,160,40)
    const float* __restrict__ g_conv_w,   // (256,80,4)
    const float* __restrict__ g_conv_b,   // (256,80)
    const float* __restrict__ g_xp_w,     // (256,35,80)
    const float* __restrict__ g_dt_w,     // (256,80,3)
    const float* __restrict__ g_dt_b,     // (256,80)
    const float* __restrict__ g_alog,     // (256,80,16)
    const float* __restrict__ g_D,        // (256,80)
    const float* __restrict__ g_out_w,    // (256,40,80)
    float* __restrict__ xb0,
    float* __restrict__ xb1,
    int* __restrict__ flags,
    // PE-block inputs (blocks >= NLB)
    const float* __restrict__ qry,
    const float* __restrict__ pe_w, const float* __restrict__ pe_b,
    const float* __restrict__ lnq_w, const float* __restrict__ lnq_b,
    const float* __restrict__ qw,
    float* __restrict__ qstore)           // q_t[e*65536 + n]
{
  const int tid = threadIdx.x;

  // ---------------- PE blocks: query preprocessing (separate CUs) ----------
  if (blockIdx.x >= NLB) {
    const int n = (blockIdx.x - NLB) * TPB1 + tid;
    if (n < 65536) {
      const float qx = qry[n * 3 + 0], qy = qry[n * 3 + 1], qz = qry[n * 3 + 2];
      float qe[40];
#pragma unroll
      for (int d = 0; d < 40; ++d) qe[d] = pe_b[d];
#pragma unroll 1
      for (int j = 0; j < 8; ++j) {
        float f = 3.14159265358979323846f * (float)(1 << j);
        float sx, cx, sy, cy, sz, cz;
        __sincosf(qx * f, &sx, &cx);
        __sincosf(qy * f, &sy, &cy);
        __sincosf(qz * f, &sz, &cz);
#pragma unroll
        for (int d = 0; d < 40; ++d) {
          const float* r = pe_w + d * 51;
          qe[d] += sx * r[j] + sy * r[j + 8] + sz * r[j + 16]
                 + cx * r[j + 24] + cy * r[j + 32] + cz * r[j + 40];
        }
      }
#pragma unroll
      for (int d = 0; d < 40; ++d) {
        const float* r = pe_w + d * 51;
        qe[d] += qx * r[48] + qy * r[49] + qz * r[50];
      }
      // LN -> qn (registers)
      float qn[40];
      {
        float m = 0.f;
#pragma unroll
        for (int d = 0; d < 40; ++d) m += qe[d];
        m *= (1.f / 40.f);
        float var = 0.f;
#pragma unroll
        for (int d = 0; d < 40; ++d) { float dv = qe[d] - m; var += dv * dv; }
        float rstd = rsqrtf(var * (1.f / 40.f) + 1e-5f);
#pragma unroll
        for (int d = 0; d < 40; ++d)
          qn[d] = (qe[d] - m) * rstd * lnq_w[d] + lnq_b[d];
      }
      // q-proj, fully unrolled (constant reg indices; qw scalar loads)
      float q[40];
#pragma unroll
      for (int e = 0; e < 40; ++e) {
        const float* r = qw + e * 40;
        float s = 0.f;
#pragma unroll
        for (int d = 0; d < 40; ++d) s += qn[d] * r[d];
        q[e] = s;
      }
#pragma unroll
      for (int e = 0; e < 40; ++e) qstore[e * 65536 + n] = q[e];
    }
    return;
  }

  // ---------------- fused layer blocks: 2 layers, 2 groups of 320 ----------
  const int blk = blockIdx.x;
  const int g = tid / 320;              // wave-uniform (320 = 5 waves)
  const int ltid = tid - g * 320;
  const int layer = 2 * blk + g;

  __shared__ float xz[2][640];
  __shared__ float xs[2][320];
  __shared__ float dbc[2][144];         // stride 36
  __shared__ float yb[2][320];
  __shared__ float xhist[2][240];       // conv tail
  __shared__ float ho[2][160];          // intra-block handoff (double buf)
  __shared__ float xin0[160];           // group-0 residual input

  const int e_in = ltid % 160;
  const int tA = ltid / 160;
  float w_in_r[40];                     // in_proj row with rmsnorm folded
  {
    const float4* gg = (const float4*)(g_in_w + layer * 6400 + e_in * 40);
    const float4* nw = (const float4*)(g_norm_w + layer * 40);
#pragma unroll
    for (int k = 0; k < 10; ++k) {
      float4 v = gg[k];
      float4 n = nw[k];
      w_in_r[4 * k] = v.x * n.x; w_in_r[4 * k + 1] = v.y * n.y;
      w_in_r[4 * k + 2] = v.z * n.z; w_in_r[4 * k + 3] = v.w * n.w;
    }
  }
  const int d_c = ltid % 80;
  const int t_c = ltid / 80;
  float cw[4]; float cb;
  {
    float4 v = *(const float4*)(g_conv_w + layer * 320 + d_c * 4);
    cw[0] = v.x; cw[1] = v.y; cw[2] = v.z; cw[3] = v.w;
    cb = g_conv_b[layer * 80 + d_c];
  }
  const int halfp = ltid & 1;
  const int p_x = ltid >> 1;            // <140 active for x_proj
  const int t_x = p_x / 35, e_x = p_x % 35;
  float w_xp_r[40];
  if (p_x < 140) {
    const float4* gg = (const float4*)(g_xp_w + layer * 2800 + e_x * 80 + halfp * 40);
#pragma unroll
    for (int k = 0; k < 10; ++k) {
      float4 v = gg[k];
      w_xp_r[4 * k] = v.x; w_xp_r[4 * k + 1] = v.y;
      w_xp_r[4 * k + 2] = v.z; w_xp_r[4 * k + 3] = v.w;
    }
  }
  const int d_ch = ltid >> 2;
  const int qq = ltid & 3;
  float negA[4], hst[4];
  {
    float4 v = *(const float4*)(g_alog + layer * 1280 + ltid * 4);
    negA[0] = -__expf(v.x); negA[1] = -__expf(v.y);
    negA[2] = -__expf(v.z); negA[3] = -__expf(v.w);
    hst[0] = hst[1] = hst[2] = hst[3] = 0.f;
  }
  const float dtw0 = g_dt_w[layer * 240 + d_ch * 3 + 0];
  const float dtw1 = g_dt_w[layer * 240 + d_ch * 3 + 1];
  const float dtw2 = g_dt_w[layer * 240 + d_ch * 3 + 2];
  const float dtb = g_dt_b[layer * 80 + d_ch];
  const float wD = g_D[layer * 80 + d_ch];
  const int p_o = ltid >> 1;
  const int t_o = p_o / 40, e_o = p_o % 40;
  float w_out_r[40];
  {
    const float4* gg = (const float4*)(g_out_w + layer * 3200 + e_o * 80 + halfp * 40);
#pragma unroll
    for (int k = 0; k < 10; ++k) {
      float4 v = gg[k];
      w_out_r[4 * k] = v.x; w_out_r[4 * k + 1] = v.y;
      w_out_r[4 * k + 2] = v.z; w_out_r[4 * k + 3] = v.w;
    }
  }

  for (int i = ltid; i < 240; i += 320) xhist[g][i] = 0.f;
  __syncthreads();

  // block b reads dst of block b-1; dst_b = (b&1)? xb1 : xb0
  const float* src = (blk == 0) ? mash : ((blk & 1) ? xb0 : xb1);
  float* dst = (blk & 1) ? xb1 : xb0;
  int* flag_prev = flags + (blk - 1) * 16;
  int* flag_cur = flags + blk * 16;

  // 101 iterations: group 0 runs chunks 0..99 at i, group 1 at i-1.
  for (int i = 0; i <= NCHUNK; ++i) {
    const bool act0 = (g == 0) && (i < NCHUNK);
    const bool act1 = (g == 1) && (i >= 1);
    const int c = (g == 0) ? i : (i - 1);
    const int t0 = c * CH;
    const int hb = c & 1;               // handoff slot for chunk c

    // ---- Phase A: acquire input + in_proj (rmsnorm folded) ----
    if (act0) {
      if (blk == 0) {
#pragma unroll
        for (int tt = 0; tt < 2; ++tt) {
          const int t = tA + 2 * tt;
          const float4* sp = (const float4*)(src + (t0 + t) * 40);
          float ss = 0.f, sd = 0.f;
#pragma unroll
          for (int k = 0; k < 10; ++k) {
            float4 v = sp[k];
            ss += v.x * v.x + v.y * v.y + v.z * v.z + v.w * v.w;
            sd += w_in_r[4 * k] * v.x + w_in_r[4 * k + 1] * v.y
                + w_in_r[4 * k + 2] * v.z + w_in_r[4 * k + 3] * v.w;
          }
          xz[0][t * 160 + e_in] = sd * rsqrtf(ss * (1.f / 40.f) + 1e-5f);
        }
        if (ltid < 160) xin0[ltid] = src[t0 * 40 + ltid];
      } else {
        // every group-0 wave polls (wave-uniform); loads are program-ordered
        // after the observed flag -> guaranteed fresh (producer B5-drained
        // before flag)
        while (__hip_atomic_load(flag_prev, __ATOMIC_RELAXED,
                                 __HIP_MEMORY_SCOPE_AGENT) <= i)
          __builtin_amdgcn_s_sleep(1);
#pragma unroll
        for (int tt = 0; tt < 2; ++tt) {
          const int t = tA + 2 * tt;
          const u64* sp = (const u64*)(src + (t0 + t) * 40);
          float ss = 0.f, sd = 0.f;
#pragma unroll
          for (int k = 0; k < 20; ++k) {
            u64 a = __hip_atomic_load(sp + k, __ATOMIC_RELAXED,
                                      __HIP_MEMORY_SCOPE_AGENT);
            float v0 = unplo(a), v1 = unphi(a);
            ss += v0 * v0 + v1 * v1;
            sd += w_in_r[2 * k] * v0 + w_in_r[2 * k + 1] * v1;
          }
          xz[0][t * 160 + e_in] = sd * rsqrtf(ss * (1.f / 40.f) + 1e-5f);
        }
        if (ltid < 80) {
          u64 a = __hip_atomic_load((const u64*)(src + t0 * 40) + ltid,
                                    __ATOMIC_RELAXED, __HIP_MEMORY_SCOPE_AGENT);
          xin0[2 * ltid] = unplo(a);
          xin0[2 * ltid + 1] = unphi(a);
        }
      }
    } else if (act1) {
      // input = group-0 handoff (chunk c, written last iteration)
#pragma unroll
      for (int tt = 0; tt < 2; ++tt) {
        const int t = tA + 2 * tt;
        const float4* sp = (const float4*)&ho[hb][t * 40];
        float ss = 0.f, sd = 0.f;
#pragma unroll
        for (int k = 0; k < 10; ++k) {
          float4 v = sp[k];
          ss += v.x * v.x + v.y * v.y + v.z * v.z + v.w * v.w;
          sd += w_in_r[4 * k] * v.x + w_in_r[4 * k + 1] * v.y
              + w_in_r[4 * k + 2] * v.z + w_in_r[4 * k + 3] * v.w;
        }
        xz[1][t * 160 + e_in] = sd * rsqrtf(ss * (1.f / 40.f) + 1e-5f);
      }
    }
    __syncthreads();                                   // B1: xz ready

    // ---- causal depthwise conv(4) + silu ----
    if (act0 || act1) {
      float acc = cb;
#pragma unroll
      for (int j = 0; j < 4; ++j) {
        int lt = t_c - 3 + j;
        float xv = (lt >= 0) ? xz[g][lt * 160 + d_c]
                             : xhist[g][(lt + 3) * 80 + d_c];
        acc += cw[j] * xv;
      }
      xs[g][t_c * 80 + d_c] = acc / (1.f + __expf(-acc));
    }
    __syncthreads();                                   // B2: xs ready

    // ---- x_proj: pair half-dots + shfl merge; idle threads refresh xhist --
    if (act0 || act1) {
      if (p_x < 140) {
        const float4* xp = (const float4*)&xs[g][t_x * 80 + halfp * 40];
        float s = 0.f;
#pragma unroll
        for (int k = 0; k < 10; ++k) {
          float4 v = xp[k];
          s += w_xp_r[4 * k] * v.x + w_xp_r[4 * k + 1] * v.y
             + w_xp_r[4 * k + 2] * v.z + w_xp_r[4 * k + 3] * v.w;
        }
        s += __shfl_xor(s, 1);
        if (halfp == 0) dbc[g][t_x * 36 + e_x] = s;
      } else {
        for (int k = ltid - 280; k < 240; k += 40)
          xhist[g][k] = xz[g][(1 + k / 80) * 160 + (k % 80)];
      }
    }
    __syncthreads();                                   // B3: dbc ready

    // ---- selective scan; dt inline; state in regs ----
    if (act0 || act1) {
#pragma unroll
      for (int t = 0; t < CH; ++t) {
        const float* db = &dbc[g][t * 36];
        float sdt = dtb + db[0] * dtw0 + db[1] * dtw1 + db[2] * dtw2;
        float dtval = (sdt > 15.f) ? sdt : __logf(1.f + __expf(sdt));
        float xval = xs[g][t * 80 + d_ch];
        float part = 0.f;
#pragma unroll
        for (int j = 0; j < 4; ++j) {
          int s_i = qq * 4 + j;
          float Bv = db[3 + s_i];
          float Cv = db[19 + s_i];
          hst[j] = __expf(dtval * negA[j]) * hst[j] + dtval * Bv * xval;
          part += hst[j] * Cv;
        }
        part += __shfl_xor(part, 1);
        part += __shfl_xor(part, 2);
        if (qq == 0) {
          float yv = part + xval * wD;
          float z = xz[g][t * 160 + 80 + d_ch];
          yb[g][t * 80 + d_ch] = yv * z / (1.f + __expf(-z));
        }
      }
    }
    __syncthreads();                                   // B4: yb ready

    // ---- out_proj + residual ----
    if (act0) {
      // group 0 -> LDS handoff (chunk c into slot hb)
      const float4* yp = (const float4*)&yb[0][t_o * 80 + halfp * 40];
      float s = 0.f;
#pragma unroll
      for (int k = 0; k < 10; ++k) {
        float4 v = yp[k];
        s += w_out_r[4 * k] * v.x + w_out_r[4 * k + 1] * v.y
           + w_out_r[4 * k + 2] * v.z + w_out_r[4 * k + 3] * v.w;
      }
      s += __shfl_xor(s, 1);
      if (halfp == 0) ho[hb][p_o] = xin0[p_o] + s;
    } else if (act1) {
      // group 1 -> global (paired dwordx2 coherent stores)
      const float4* yp = (const float4*)&yb[1][t_o * 80 + halfp * 40];
      float s = 0.f;
#pragma unroll
      for (int k = 0; k < 10; ++k) {
        float4 v = yp[k];
        s += w_out_r[4 * k] * v.x + w_out_r[4 * k + 1] * v.y
           + w_out_r[4 * k + 2] * v.z + w_out_r[4 * k + 3] * v.w;
      }
      s += __shfl_xor(s, 1);
      float r = ho[hb][p_o] + s;       // valid on pair leaders (halfp==0)
      float r2 = __shfl_xor(r, 2);     // leader ltid+2's value (p_o+1)
      if ((ltid & 3) == 0)             // even p_o leaders store the pair
        __hip_atomic_store((u64*)(dst + t0 * 40 + p_o), pack2(r, r2),
                           __ATOMIC_RELAXED, __HIP_MEMORY_SCOPE_AGENT);
    }
    __syncthreads();        // B5: drains vmcnt -> stores acked; handoff visible
    if (act1 && ltid == 0)
      __hip_atomic_store(flag_cur, c + 1, __ATOMIC_RELAXED,
                         __HIP_MEMORY_SCOPE_AGENT);
  }
}

// ---- context side of cross-attn: cn = LN(x_final), kv = cn @ ca_kv_w^T ----
__global__ __launch_bounds__(64) void kv_kernel(
    const float* __restrict__ xfin,
    const float* __restrict__ lnc_w, const float* __restrict__ lnc_b,
    const float* __restrict__ kv_w,
    float* __restrict__ kbuf, float* __restrict__ vbuf)
{
  int t = blockIdx.x;
  int lane = threadIdx.x;
  float x = (lane < 40) ? xfin[t * 40 + lane] : 0.f;
  float s = x;
#pragma unroll
  for (int o = 32; o >= 1; o >>= 1) s += __shfl_xor(s, o);
  float m = s * (1.f / 40.f);
  float dv = (lane < 40) ? (x - m) : 0.f;
  float v2 = dv * dv;
#pragma unroll
  for (int o = 32; o >= 1; o >>= 1) v2 += __shfl_xor(v2, o);
  float rstd = rsqrtf(v2 * (1.f / 40.f) + 1e-5f);
  __shared__ float cn[40];
  if (lane < 40) cn[lane] = dv * rstd * lnc_w[lane] + lnc_b[lane];
  __syncthreads();
  for (int e = lane; e < 80; e += 64) {
    float acc = 0.f;
#pragma unroll
    for (int d = 0; d < 40; ++d) acc += cn[d] * kv_w[e * 40 + d];
    if (e < 40) kbuf[t * 40 + e] = acc;
    else vbuf[t * 40 + (e - 40)] = acc;
  }
}

// ---- fast query decode: precomputed q, 4-way token split per query ----
__global__ __launch_bounds__(256) void query_fast(
    const float* __restrict__ qstore,    // q_t[e*65536 + n]
    const float* __restrict__ ow, const float* __restrict__ ob,
    const float* __restrict__ flw, const float* __restrict__ flb,
    const float* __restrict__ w1, const float* __restrict__ b1,
    const float* __restrict__ w2, const float* __restrict__ b2,
    const float* __restrict__ outw, const float* __restrict__ outb,
    const float* __restrict__ kbuf, const float* __restrict__ vbuf,
    float* __restrict__ out)
{
  const int tid = threadIdx.x;
  const int h = __builtin_amdgcn_readfirstlane((tid >> 6) & 3);  // wave 0..3
  const int lane = tid & 63;
  const int n = blockIdx.x * 64 + lane;
  const int p1 = tid ^ 64, p2 = tid ^ 128, p3 = tid ^ 192;
  __shared__ float colbuf[40 * 256];     // 40KB: merge staging (reused)

  // load precomputed q (coalesced per e-plane)
  float q[40];
#pragma unroll
  for (int e = 0; e < 40; ++e) q[e] = qstore[e * 65536 + n];

  // flash attention over this wave's 100 tokens, 2 tokens per step (ILP)
  float acc[40];
#pragma unroll
  for (int d = 0; d < 40; ++d) acc[d] = 0.f;
  float mx = -1e30f, l = 0.f;
  const float scale = 0.15811388300841897f;  // 40^-0.5
  const int tbeg = h * 100;
#pragma unroll 1
  for (int t = tbeg; t < tbeg + 100; t += 2) {
    const float4* ka = (const float4*)(kbuf + t * 40);
    const float4* kb = (const float4*)(kbuf + t * 40 + 40);
    float a0 = 0.f, a1 = 0.f, b0 = 0.f, b1s = 0.f;
#pragma unroll
    for (int k = 0; k < 10; ++k) {
      float4 k4 = ka[k];
      float4 j4 = kb[k];
      a0 += q[4 * k] * k4.x + q[4 * k + 1] * k4.y;
      a1 += q[4 * k + 2] * k4.z + q[4 * k + 3] * k4.w;
      b0 += q[4 * k] * j4.x + q[4 * k + 1] * j4.y;
      b1s += q[4 * k + 2] * j4.z + q[4 * k + 3] * j4.w;
    }
    float sa = (a0 + a1) * scale;
    float sb = (b0 + b1s) * scale;
    // sequential online-softmax updates (dots above carried the ILP)
    {
      if (sa > mx) {
        float corr = __expf(mx - sa);
        l *= corr;
#pragma unroll
        for (int d = 0; d < 40; ++d) acc[d] *= corr;
        mx = sa;
      }
      float p = __expf(sa - mx);
      l += p;
      const float4* vr = (const float4*)(vbuf + t * 40);
#pragma unroll
      for (int k = 0; k < 10; ++k) {
        float4 v4 = vr[k];
        acc[4 * k] += p * v4.x; acc[4 * k + 1] += p * v4.y;
        acc[4 * k + 2] += p * v4.z; acc[4 * k + 3] += p * v4.w;
      }
    }
    {
      if (sb > mx) {
        float corr = __expf(mx - sb);
        l *= corr;
#pragma unroll
        for (int d = 0; d < 40; ++d) acc[d] *= corr;
        mx = sb;
      }
      float p = __expf(sb - mx);
      l += p;
      const float4* vr = (const float4*)(vbuf + (t + 1) * 40);
#pragma unroll
      for (int k = 0; k < 10; ++k) {
        float4 v4 = vr[k];
        acc[4 * k] += p * v4.x; acc[4 * k + 1] += p * v4.y;
        acc[4 * k + 2] += p * v4.z; acc[4 * k + 3] += p * v4.w;
      }
    }
  }

  // ---- 4-way merge: m/l first (colbuf rows 0-1), then acc columns ----
  {
    float* redm = colbuf;          // [256]
    float* redl = colbuf + 256;    // [256]
    redm[tid] = mx; redl[tid] = l;
  }
  __syncthreads();                                    // B1
  float a0c, a1c, a2c, a3c, linv;
  {
    float m1 = colbuf[p1], m2 = colbuf[p2], m3 = colbuf[p3];
    float l1 = colbuf[256 + p1], l2 = colbuf[256 + p2], l3 = colbuf[256 + p3];
    float nm = fmaxf(fmaxf(mx, m1), fmaxf(m2, m3));
    a0c = __expf(mx - nm); a1c = __expf(m1 - nm);
    a2c = __expf(m2 - nm); a3c = __expf(m3 - nm);
    float L = l * a0c + l1 * a1c + l2 * a2c + l3 * a3c;
    linv = 1.f / L;
  }
  __syncthreads();                                    // B2 (m/l region free)
#pragma unroll
  for (int d = 0; d < 40; ++d) colbuf[d * 256 + tid] = acc[d];
  __syncthreads();                                    // B3
  float lat[40];
#pragma unroll
  for (int d = 0; d < 40; ++d)
    lat[d] = (acc[d] * a0c + colbuf[d * 256 + p1] * a1c
            + colbuf[d * 256 + p2] * a2c + colbuf[d * 256 + p3] * a3c) * linv;
  __syncthreads();                                    // B4 (colbuf free)

  // ---- lat2 = lat @ ca_out_w^T + ob, d-range split by wave (10 each) ----
  float lath[10];
#pragma unroll
  for (int dd = 0; dd < 10; ++dd) {
    float v = lat[dd];
    v = (h == 1) ? lat[dd + 10] : v;
    v = (h == 2) ? lat[dd + 20] : v;
    v = (h == 3) ? lat[dd + 30] : v;
    lath[dd] = v;
  }
  float lp[40];
#pragma unroll
  for (int e = 0; e < 40; ++e) lp[e] = 0.f;
#pragma unroll 1
  for (int dd = 0; dd < 10; ++dd) {
    const float lv = lath[dd];
    const int d = h * 10 + dd;
#pragma unroll
    for (int e = 0; e < 40; ++e) lp[e] += lv * ow[e * 40 + d];
  }
#pragma unroll
  for (int e = 0; e < 40; ++e) colbuf[e * 256 + tid] = lp[e];
  __syncthreads();                                    // B5
  float lat2[40];
#pragma unroll
  for (int e = 0; e < 40; ++e)
    lat2[e] = ob[e] + lp[e] + colbuf[e * 256 + p1]
            + colbuf[e * 256 + p2] + colbuf[e * 256 + p3];
  __syncthreads();                                    // B6 (colbuf free)

  // ---- LN + FFN (e-range split by wave: 40 each) ----
  float hh[40];
  {
    float m = 0.f;
#pragma unroll
    for (int d = 0; d < 40; ++d) m += lat2[d];
    m *= (1.f / 40.f);
    float var = 0.f;
#pragma unroll
    for (int d = 0; d < 40; ++d) { float dv = lat2[d] - m; var += dv * dv; }
    float rstd = rsqrtf(var * (1.f / 40.f) + 1e-5f);
#pragma unroll
    for (int d = 0; d < 40; ++d) hh[d] = (lat2[d] - m) * rstd * flw[d] + flb[d];
  }
  float ff[40];
#pragma unroll
  for (int d = 0; d < 40; ++d) ff[d] = 0.f;
#pragma unroll 1
  for (int ee = 0; ee < 40; ++ee) {
    const int e = h * 40 + ee;
    const float* r1 = w1 + e * 40;
    const float* r2 = w1 + (160 + e) * 40;
    float s0 = 0.f, s1 = 0.f;
#pragma unroll
    for (int d = 0; d < 40; ++d) { s0 += hh[d] * r1[d]; s1 += hh[d] * r2[d]; }
    float x1 = s0 + b1[e];
    float g = s1 + b1[160 + e];
    float tv = x1 * (0.5f * g * (1.f + erff(g * 0.70710678118654752f)));
#pragma unroll
    for (int d = 0; d < 40; ++d) ff[d] += tv * w2[d * 160 + e];
  }
#pragma unroll
  for (int d = 0; d < 40; ++d) colbuf[d * 256 + tid] = ff[d];
  __syncthreads();                                    // B7
  float r = outb[0];
#pragma unroll
  for (int d = 0; d < 40; ++d) {
    float f = ff[d] + colbuf[d * 256 + p1] + colbuf[d * 256 + p2]
            + colbuf[d * 256 + p3] + b2[d];
    r += (lat2[d] + f) * outw[d];
  }
  if (h == 0) out[n] = r;
}

// ---- fallback query (R8, PE inside) for small ws ----
__global__ __launch_bounds__(256) void query_kernel_fb(
    const float* __restrict__ qry,
    const float* __restrict__ pe_w, const float* __restrict__ pe_b,
    const float* __restrict__ lnq_w, const float* __restrict__ lnq_b,
    const float* __restrict__ qw,
    const float* __restrict__ ow, const float* __restrict__ ob,
    const float* __restrict__ flw, const float* __restrict__ flb,
    const float* __restrict__ w1, const float* __restrict__ b1,
    const float* __restrict__ w2, const float* __restrict__ b2,
    const float* __restrict__ outw, const float* __restrict__ outb,
    const float* __restrict__ kbuf, const float* __restrict__ vbuf,
    float* __restrict__ out)
{
  const int tid = threadIdx.x;
  const int h = __builtin_amdgcn_readfirstlane((tid >> 6) & 1);
  const int pj = tid >> 7;
  const int lane = tid & 63;
  const int n = blockIdx.x * 128 + pj * 64 + lane;
  const int ptn = tid ^ 64;
  __shared__ float colbuf[40 * 256];
  __shared__ float redm[256], redl[256];

  const float qx = qry[n * 3 + 0], qy = qry[n * 3 + 1], qz = qry[n * 3 + 2];
  float qp[40];
#pragma unroll
  for (int d = 0; d < 40; ++d) qp[d] = 0.f;
#pragma unroll
  for (int jj = 0; jj < 4; ++jj) {
    const int j = h * 4 + jj;
    float f = 3.14159265358979323846f * (float)(1 << j);
    float sx, cx, sy, cy, sz, cz;
    __sincosf(qx * f, &sx, &cx);
    __sincosf(qy * f, &sy, &cy);
    __sincosf(qz * f, &sz, &cz);
#pragma unroll
    for (int d = 0; d < 40; ++d) {
      const float* r = pe_w + d * 51;
      qp[d] += sx * r[j] + sy * r[j + 8] + sz * r[j + 16]
             + cx * r[j + 24] + cy * r[j + 32] + cz * r[j + 40];
    }
  }
#pragma unroll
  for (int d = 0; d < 40; ++d) colbuf[d * 256 + tid] = qp[d];
  __syncthreads();
  float qe[40];
#pragma unroll
  for (int d = 0; d < 40; ++d) {
    const float* r = pe_w + d * 51;
    qe[d] = pe_b[d] + qp[d] + colbuf[d * 256 + ptn]
          + qx * r[48] + qy * r[49] + qz * r[50];
  }
  __syncthreads();
  float qn[40];
  {
    float m = 0.f;
#pragma unroll
    for (int d = 0; d < 40; ++d) m += qe[d];
    m *= (1.f / 40.f);
    float var = 0.f;
#pragma unroll
    for (int d = 0; d < 40; ++d) { float dv = qe[d] - m; var += dv * dv; }
    float rstd = rsqrtf(var * (1.f / 40.f) + 1e-5f);
#pragma unroll
    for (int d = 0; d < 40; ++d) qn[d] = (qe[d] - m) * rstd * lnq_w[d] + lnq_b[d];
  }
  float qnh[20];
#pragma unroll
  for (int dd = 0; dd < 20; ++dd) qnh[dd] = h ? qn[dd + 20] : qn[dd];
  float q[40];
#pragma unroll
  for (int e = 0; e < 40; ++e) q[e] = 0.f;
#pragma unroll 1
  for (int dd = 0; dd < 20; ++dd) {
    const float qv = qnh[dd];
    const int d = h * 20 + dd;
#pragma unroll
    for (int e = 0; e < 40; ++e) q[e] += qv * qw[e * 40 + d];
  }
#pragma unroll
  for (int e = 0; e < 40; ++e) colbuf[e * 256 + tid] = q[e];
  __syncthreads();
#pragma unroll
  for (int e = 0; e < 40; ++e) q[e] += colbuf[e * 256 + ptn];
  __syncthreads();

  float acc[40];
#pragma unroll
  for (int d = 0; d < 40; ++d) acc[d] = 0.f;
  float mx = -1e30f, l = 0.f;
  const float scale = 0.15811388300841897f;
  const int tbeg = h * 200, tend = tbeg + 200;
#pragma unroll 1
  for (int t = tbeg; t < tend; ++t) {
    const float4* kr = (const float4*)(kbuf + t * 40);
    float s0 = 0.f, s1 = 0.f, s2 = 0.f, s3 = 0.f;
#pragma unroll
    for (int k = 0; k < 10; ++k) {
      float4 k4 = kr[k];
      s0 += q[4 * k] * k4.x; s1 += q[4 * k + 1] * k4.y;
      s2 += q[4 * k + 2] * k4.z; s3 += q[4 * k + 3] * k4.w;
    }
    float s = ((s0 + s1) + (s2 + s3)) * scale;
    if (s > mx) {
      float corr = __expf(mx - s);
      l *= corr;
#pragma unroll
      for (int d = 0; d < 40; ++d) acc[d] *= corr;
      mx = s;
    }
    float p = __expf(s - mx);
    l += p;
    const float4* vr = (const float4*)(vbuf + t * 40);
#pragma unroll
    for (int k = 0; k < 10; ++k) {
      float4 v4 = vr[k];
      acc[4 * k] += p * v4.x; acc[4 * k + 1] += p * v4.y;
      acc[4 * k + 2] += p * v4.z; acc[4 * k + 3] += p * v4.w;
    }
  }
#pragma unroll
  for (int d = 0; d < 40; ++d) colbuf[d * 256 + tid] = acc[d];
  redm[tid] = mx; redl[tid] = l;
  __syncthreads();
  float lat[40];
  {
    float m2 = redm[ptn];
    float l2 = redl[ptn];
    float nm = fmaxf(mx, m2);
    float a = __expf(mx - nm), b = __expf(m2 - nm);
    float lm = l * a + l2 * b;
    float linv = 1.f / lm;
#pragma unroll
    for (int d = 0; d < 40; ++d)
      lat[d] = (acc[d] * a + colbuf[d * 256 + ptn] * b) * linv;
  }
  __syncthreads();
  float lath[20];
#pragma unroll
  for (int dd = 0; dd < 20; ++dd) lath[dd] = h ? lat[dd + 20] : lat[dd];
  float lp[40];
#pragma unroll
  for (int e = 0; e < 40; ++e) lp[e] = 0.f;
#pragma unroll 1
  for (int dd = 0; dd < 20; ++dd) {
    const float lv = lath[dd];
    const int d = h * 20 + dd;
#pragma unroll
    for (int e = 0; e < 40; ++e) lp[e] += lv * ow[e * 40 + d];
  }
#pragma unroll
  for (int e = 0; e < 40; ++e) colbuf[e * 256 + tid] = lp[e];
  __syncthreads();
  float lat2[40];
#pragma unroll
  for (int e = 0; e < 40; ++e) lat2[e] = ob[e] + lp[e] + colbuf[e * 256 + ptn];
  __syncthreads();
  float hh[40];
  {
    float m = 0.f;
#pragma unroll
    for (int d = 0; d < 40; ++d) m += lat2[d];
    m *= (1.f / 40.f);
    float var = 0.f;
#pragma unroll
    for (int d = 0; d < 40; ++d) { float dv = lat2[d] - m; var += dv * dv; }
    float rstd = rsqrtf(var * (1.f / 40.f) + 1e-5f);
#pragma unroll
    for (int d = 0; d < 40; ++d) hh[d] = (lat2[d] - m) * rstd * flw[d] + flb[d];
  }
  float ff[40];
#pragma unroll
  for (int d = 0; d < 40; ++d) ff[d] = 0.f;
#pragma unroll 1
  for (int ee = 0; ee < 80; ++ee) {
    const int e = h * 80 + ee;
    const float* r1 = w1 + e * 40;
    const float* r2 = w1 + (160 + e) * 40;
    float s0 = 0.f, s1 = 0.f;
#pragma unroll
    for (int d = 0; d < 40; ++d) { s0 += hh[d] * r1[d]; s1 += hh[d] * r2[d]; }
    float x1 = s0 + b1[e];
    float g = s1 + b1[160 + e];
    float tv = x1 * (0.5f * g * (1.f + erff(g * 0.70710678118654752f)));
#pragma unroll
    for (int d = 0; d < 40; ++d) ff[d] += tv * w2[d * 160 + e];
  }
#pragma unroll
  for (int d = 0; d < 40; ++d) colbuf[d * 256 + tid] = ff[d];
  __syncthreads();
  float r = outb[0];
#pragma unroll
  for (int d = 0; d < 40; ++d) {
    float f = ff[d] + colbuf[d * 256 + ptn] + b2[d];
    r += (lat2[d] + f) * outw[d];
  }
  if (h == 0) out[n] = r;
}

extern "C" void kernel_launch(void* const* d_in, const int* in_sizes, int n_in,
                              void* d_out, int out_size, void* d_ws, size_t ws_size,
                              hipStream_t stream) {
  const float* mash   = (const float*)d_in[0];
  const float* qry    = (const float*)d_in[1];
  const float* lnw    = (const float*)d_in[2];
  const float* linw   = (const float*)d_in[3];
  const float* lconvw = (const float*)d_in[4];
  const float* lconvb = (const float*)d_in[5];
  const float* lxpw   = (const float*)d_in[6];
  const float* ldtw   = (const float*)d_in[7];
  const float* ldtb   = (const float*)d_in[8];
  const float* lAlog  = (const float*)d_in[9];
  const float* lD     = (const float*)d_in[10];
  const float* loutw  = (const float*)d_in[11];
  const float* pew    = (const float*)d_in[12];
  const float* peb    = (const float*)d_in[13];
  const float* lnqw   = (const float*)d_in[14];
  const float* lnqb   = (const float*)d_in[15];
  const float* lncw   = (const float*)d_in[16];
  const float* lncb   = (const float*)d_in[17];
  const float* qw     = (const float*)d_in[18];
  const float* kvw    = (const float*)d_in[19];
  const float* oww    = (const float*)d_in[20];
  const float* owb    = (const float*)d_in[21];
  const float* flnw   = (const float*)d_in[22];
  const float* flnb   = (const float*)d_in[23];
  const float* w1     = (const float*)d_in[24];
  const float* b1     = (const float*)d_in[25];
  const float* w2     = (const float*)d_in[26];
  const float* b2     = (const float*)d_in[27];
  const float* outw   = (const float*)d_in[28];
  const float* outb   = (const float*)d_in[29];

  // ws layout (floats): xb0[16000] xb1[16000] k[16000] v[16000]
  //                     flags[4096 ints] qstore[40*65536]
  float* wsf = (float*)d_ws;
  float* xb0 = wsf;
  float* xb1 = wsf + 16000;
  float* kbuf = wsf + 32000;
  float* vbuf = wsf + 48000;
  int* flags = (int*)(wsf + 64000);
  float* qstore = wsf + 68096;
  const size_t needed = (size_t)68096 * 4 + (size_t)40 * 65536 * 4;
  const bool pre = ws_size >= needed;   // constant across calls -> capture-safe

  hipLaunchKernelGGL(init_flags, dim3(16), dim3(256), 0, stream, flags);
  // 128 fused layer blocks (+ 103 PE blocks if pre); layer blocks dispatch 1st
  const int npe = (65536 + TPB1 - 1) / TPB1;   // 103
  hipLaunchKernelGGL(mamba_pipe, dim3(pre ? NLB + npe : NLB), dim3(TPB1), 0,
                     stream,
                     mash, lnw, linw, lconvw, lconvb, lxpw, ldtw, ldtb, lAlog,
                     lD, loutw, xb0, xb1, flags,
                     qry, pew, peb, lnqw, lnqb, qw, qstore);
  // block 127 (odd) writes xb1 -> final residual stream
  hipLaunchKernelGGL(kv_kernel, dim3(400), dim3(64), 0, stream,
                     xb1, lncw, lncb, kvw, kbuf, vbuf);
  if (pre) {
    hipLaunchKernelGGL(query_fast, dim3(1024), dim3(256), 0, stream,
                       qstore, oww, owb, flnw, flnb,
                       w1, b1, w2, b2, outw, outb, kbuf, vbuf, (float*)d_out);
  } else {
    hipLaunchKernelGGL(query_kernel_fb, dim3(512), dim3(256), 0, stream,
                       qry, pew, peb, lnqw, lnqb, qw, oww, owb, flnw, flnb,
                       w1, b1, w2, b2, outw, outb, kbuf, vbuf, (float*)d_out);
  }
}

// Round 4
// 2854.618 us; speedup vs baseline: 1.6226x; 1.6226x over previous
//
#include <hip/hip_runtime.h>

// ---------------------------------------------------------------------------
// MashDecoderV2: 256-layer mamba stack (L=400, D=40) + 65536-query cross-attn
// decoder. f32 throughout (threshold 1.56e-2; absmax 2e-3).
//
// Round-13: back to the proven R9 shape (256 single-layer blocks x 320 thr,
// VGPR 116 + AGPR overflow, no scratch) with ONE structural change:
//   CH 4 -> 8 (NCHUNK 100 -> 50). Critical path = 255*(P+f) + (NCHUNK-1)*P;
//   P (~4.3us) is latency-dominated (VALUBusy 9%), so widening chunks halves
//   the drain term at ~constant P: predicted mamba -150..-200us.
//   R10-R12 lesson: 640-thread fused blocks pin VGPR at 84 (both occupancy
//   attributes ignored) -> scratch spills; and fusion loses anyway unless
//   f > 0.77*P (it's ~0.25*P). All weight rows stay 40 floats/thread: each
//   thread pair covers tokens t and t+4 with the SAME row (x_proj/out_proj);
//   in_proj does 4 token-dots/thread; scan runs 8 steps on the same state.
// PE blocks (query preprocessing under mamba's latency shadow) and stage 2
// (kv_kernel + query_fast 4-way split) identical to R9.
// ---------------------------------------------------------------------------

#define CH 8
#define NCHUNK 50        // 400 / CH
#define TPB1 320

typedef unsigned long long u64;

__device__ __forceinline__ u64 pack2(float a, float b) {
  return ((u64)__float_as_uint(b) << 32) | (u64)__float_as_uint(a);
}
__device__ __forceinline__ float unplo(u64 a) {
  return __uint_as_float((unsigned)a);
}
__device__ __forceinline__ float unphi(u64 a) {
  return __uint_as_float((unsigned)(a >> 32));
}

__global__ void init_flags(int* __restrict__ flags) {
  int i = blockIdx.x * 256 + threadIdx.x;
  if (i < 256 * 16) flags[i] = 0;
}

__global__ __launch_bounds__(TPB1) void mamba_pipe(
    const float* __restrict__ mash,
    const float* __restrict__ g_norm_w,   // (256,40)
    const float* __restrict__ g_in_w,     // (256,160,40)
    const float* __restrict__ g_conv_w,   // (256,80,4)
    const float* __restrict__ g_conv_b,   // (256,80)
    const float* __restrict__ g_xp_w,     // (256,35,80)
    const float* __restrict__ g_dt_w,     // (256,80,3)
    const float* __restrict__ g_dt_b,     // (256,80)
    const float* __restrict__ g_alog,     // (256,80,16)
    const float* __restrict__ g_D,        // (256,80)
    const float* __restrict__ g_out_w,    // (256,40,80)
    float* __restrict__ xb0,
    float* __restrict__ xb1,
    int* __restrict__ flags,
    // PE-block inputs (blocks >= 256)
    const float* __restrict__ qry,
    const float* __restrict__ pe_w, const float* __restrict__ pe_b,
    const float* __restrict__ lnq_w, const float* __restrict__ lnq_b,
    const float* __restrict__ qw,
    float* __restrict__ qstore)           // q_t[e*65536 + n]
{
  const int tid = threadIdx.x;

  // ---------------- PE blocks: query preprocessing under mamba's shadow ----
  if (blockIdx.x >= 256) {
    const int n = (blockIdx.x - 256) * TPB1 + tid;
    if (n < 65536) {
      const float qx = qry[n * 3 + 0], qy = qry[n * 3 + 1], qz = qry[n * 3 + 2];
      float qe[40];
#pragma unroll
      for (int d = 0; d < 40; ++d) qe[d] = pe_b[d];
#pragma unroll 1
      for (int j = 0; j < 8; ++j) {
        float f = 3.14159265358979323846f * (float)(1 << j);
        float sx, cx, sy, cy, sz, cz;
        __sincosf(qx * f, &sx, &cx);
        __sincosf(qy * f, &sy, &cy);
        __sincosf(qz * f, &sz, &cz);
#pragma unroll
        for (int d = 0; d < 40; ++d) {
          const float* r = pe_w + d * 51;
          qe[d] += sx * r[j] + sy * r[j + 8] + sz * r[j + 16]
                 + cx * r[j + 24] + cy * r[j + 32] + cz * r[j + 40];
        }
      }
#pragma unroll
      for (int d = 0; d < 40; ++d) {
        const float* r = pe_w + d * 51;
        qe[d] += qx * r[48] + qy * r[49] + qz * r[50];
      }
      // LN -> qn (registers)
      float qn[40];
      {
        float m = 0.f;
#pragma unroll
        for (int d = 0; d < 40; ++d) m += qe[d];
        m *= (1.f / 40.f);
        float var = 0.f;
#pragma unroll
        for (int d = 0; d < 40; ++d) { float dv = qe[d] - m; var += dv * dv; }
        float rstd = rsqrtf(var * (1.f / 40.f) + 1e-5f);
#pragma unroll
        for (int d = 0; d < 40; ++d)
          qn[d] = (qe[d] - m) * rstd * lnq_w[d] + lnq_b[d];
      }
      // q-proj, fully unrolled (constant reg indices; qw scalar loads)
      float q[40];
#pragma unroll
      for (int e = 0; e < 40; ++e) {
        const float* r = qw + e * 40;
        float s = 0.f;
#pragma unroll
        for (int d = 0; d < 40; ++d) s += qn[d] * r[d];
        q[e] = s;
      }
#pragma unroll
      for (int e = 0; e < 40; ++e) qstore[e * 65536 + n] = q[e];
    }
    return;
  }

  // ---------------- layer blocks: R9 mamba loop widened to CH=8 ------------
  const int layer = blockIdx.x;

  __shared__ float xin0[320];       // residual input (8 tokens x 40)
  __shared__ float xz[8 * 160];     // in_proj output (x | z), 8 tokens
  __shared__ float xs[8 * 80];      // conv+silu output
  __shared__ float dbc[8 * 36];     // x_proj output, stride 36
  __shared__ float yb[8 * 80];      // scan output (gated)
  __shared__ float xhist[240];      // conv tail (prev-chunk tokens 5,6,7)

  const int e_in = tid % 160;
  const int tA = tid / 160;         // 0..1; tokens tA + 2*tt, tt=0..3
  float w_in_r[40];                 // in_proj row with rmsnorm weight folded
  {
    const float4* g = (const float4*)(g_in_w + layer * 6400 + e_in * 40);
    const float4* nw = (const float4*)(g_norm_w + layer * 40);
#pragma unroll
    for (int k = 0; k < 10; ++k) {
      float4 v = g[k];
      float4 n = nw[k];
      w_in_r[4 * k] = v.x * n.x; w_in_r[4 * k + 1] = v.y * n.y;
      w_in_r[4 * k + 2] = v.z * n.z; w_in_r[4 * k + 3] = v.w * n.w;
    }
  }
  const int d_c = tid % 80;
  const int t_c = tid / 80;         // 0..3; tokens t_c and t_c+4
  float cw[4]; float cb;
  {
    float4 v = *(const float4*)(g_conv_w + layer * 320 + d_c * 4);
    cw[0] = v.x; cw[1] = v.y; cw[2] = v.z; cw[3] = v.w;
    cb = g_conv_b[layer * 80 + d_c];
  }
  const int halfp = tid & 1;
  const int p_x = tid >> 1;              // <140 active for x_proj
  const int t_x = p_x / 35, e_x = p_x % 35;   // tokens t_x and t_x+4
  float w_xp_r[40];
  if (p_x < 140) {
    const float4* g = (const float4*)(g_xp_w + layer * 2800 + e_x * 80 + halfp * 40);
#pragma unroll
    for (int k = 0; k < 10; ++k) {
      float4 v = g[k];
      w_xp_r[4 * k] = v.x; w_xp_r[4 * k + 1] = v.y;
      w_xp_r[4 * k + 2] = v.z; w_xp_r[4 * k + 3] = v.w;
    }
  }
  const int d_ch = tid >> 2;
  const int qq = tid & 3;
  float negA[4], hst[4];
  {
    float4 v = *(const float4*)(g_alog + layer * 1280 + tid * 4);
    negA[0] = -__expf(v.x); negA[1] = -__expf(v.y);
    negA[2] = -__expf(v.z); negA[3] = -__expf(v.w);
    hst[0] = hst[1] = hst[2] = hst[3] = 0.f;
  }
  const float dtw0 = g_dt_w[layer * 240 + d_ch * 3 + 0];
  const float dtw1 = g_dt_w[layer * 240 + d_ch * 3 + 1];
  const float dtw2 = g_dt_w[layer * 240 + d_ch * 3 + 2];
  const float dtb = g_dt_b[layer * 80 + d_ch];
  const float wD = g_D[layer * 80 + d_ch];
  const int p_o = tid >> 1;              // 0..159; outputs p_o and p_o+160
  const int t_o = p_o / 40, e_o = p_o % 40;   // tokens t_o and t_o+4
  float w_out_r[40];
  {
    const float4* g = (const float4*)(g_out_w + layer * 3200 + e_o * 80 + halfp * 40);
#pragma unroll
    for (int k = 0; k < 10; ++k) {
      float4 v = g[k];
      w_out_r[4 * k] = v.x; w_out_r[4 * k + 1] = v.y;
      w_out_r[4 * k + 2] = v.z; w_out_r[4 * k + 3] = v.w;
    }
  }

  for (int i = tid; i < 240; i += TPB1) xhist[i] = 0.f;
  __syncthreads();

  const float* src = (layer == 0) ? mash : ((layer & 1) ? xb0 : xb1);
  float* dst = (layer & 1) ? xb1 : xb0;
  int* flag_prev = flags + (layer - 1) * 16;
  int* flag_cur = flags + layer * 16;

  for (int c = 0; c < NCHUNK; ++c) {
    const int t0 = c * CH;

    // ---- Phase A: ordered acquire + in_proj (rmsnorm folded), 4 tok/thr ----
    if (layer == 0) {
#pragma unroll 2
      for (int tt = 0; tt < 4; ++tt) {
        const int t = tA + 2 * tt;
        const float4* sp = (const float4*)(src + (t0 + t) * 40);
        float ss = 0.f, sd = 0.f;
#pragma unroll
        for (int k = 0; k < 10; ++k) {
          float4 v = sp[k];
          ss += v.x * v.x + v.y * v.y + v.z * v.z + v.w * v.w;
          sd += w_in_r[4 * k] * v.x + w_in_r[4 * k + 1] * v.y
              + w_in_r[4 * k + 2] * v.z + w_in_r[4 * k + 3] * v.w;
        }
        xz[t * 160 + e_in] = sd * rsqrtf(ss * (1.f / 40.f) + 1e-5f);
      }
      xin0[tid] = src[t0 * 40 + tid];
    } else {
      // every wave polls (wave-uniform); loads are program-ordered after the
      // observed flag -> guaranteed fresh (producer B5-drained before flag)
      while (__hip_atomic_load(flag_prev, __ATOMIC_RELAXED,
                               __HIP_MEMORY_SCOPE_AGENT) <= c)
        __builtin_amdgcn_s_sleep(1);
#pragma unroll 2
      for (int tt = 0; tt < 4; ++tt) {
        const int t = tA + 2 * tt;
        const u64* sp = (const u64*)(src + (t0 + t) * 40);
        float ss = 0.f, sd = 0.f;
#pragma unroll
        for (int k = 0; k < 20; ++k) {
          u64 a = __hip_atomic_load(sp + k, __ATOMIC_RELAXED,
                                    __HIP_MEMORY_SCOPE_AGENT);
          float v0 = unplo(a), v1 = unphi(a);
          ss += v0 * v0 + v1 * v1;
          sd += w_in_r[2 * k] * v0 + w_in_r[2 * k + 1] * v1;
        }
        xz[t * 160 + e_in] = sd * rsqrtf(ss * (1.f / 40.f) + 1e-5f);
      }
      if (tid < 160) {
        u64 a = __hip_atomic_load((const u64*)(src + t0 * 40) + tid,
                                  __ATOMIC_RELAXED, __HIP_MEMORY_SCOPE_AGENT);
        xin0[2 * tid] = unplo(a);
        xin0[2 * tid + 1] = unphi(a);
      }
    }
    __syncthreads();                                   // B1: xz, xin0 ready

    // ---- causal depthwise conv(4) + silu, 2 tokens/thread ----
#pragma unroll
    for (int tt = 0; tt < 2; ++tt) {
      const int t = t_c + 4 * tt;
      float acc = cb;
#pragma unroll
      for (int j = 0; j < 4; ++j) {
        int lt = t - 3 + j;
        float xv = (lt >= 0) ? xz[lt * 160 + d_c] : xhist[(lt + 3) * 80 + d_c];
        acc += cw[j] * xv;
      }
      xs[t * 80 + d_c] = acc / (1.f + __expf(-acc));
    }
    __syncthreads();                                   // B2: xs ready

    // ---- x_proj: pair half-dots + shfl merge, 2 tokens/pair; idle threads
    //      refresh xhist (tokens 5,6,7 -> history for next chunk) ----
    if (p_x < 140) {
#pragma unroll
      for (int tt = 0; tt < 2; ++tt) {
        const int t = t_x + 4 * tt;
        const float4* xp = (const float4*)&xs[t * 80 + halfp * 40];
        float s = 0.f;
#pragma unroll
        for (int k = 0; k < 10; ++k) {
          float4 v = xp[k];
          s += w_xp_r[4 * k] * v.x + w_xp_r[4 * k + 1] * v.y
             + w_xp_r[4 * k + 2] * v.z + w_xp_r[4 * k + 3] * v.w;
        }
        s += __shfl_xor(s, 1);
        if (halfp == 0) dbc[t * 36 + e_x] = s;
      }
    } else {
      for (int k = tid - 280; k < 240; k += 40)
        xhist[k] = xz[(5 + k / 80) * 160 + (k % 80)];
    }
    __syncthreads();                                   // B3: dbc ready

    // ---- selective scan; dt inline; state in regs; 8 steps ----
#pragma unroll
    for (int t = 0; t < CH; ++t) {
      const float* db = &dbc[t * 36];
      float sdt = dtb + db[0] * dtw0 + db[1] * dtw1 + db[2] * dtw2;
      float dtval = (sdt > 15.f) ? sdt : __logf(1.f + __expf(sdt));
      float xval = xs[t * 80 + d_ch];
      float part = 0.f;
#pragma unroll
      for (int j = 0; j < 4; ++j) {
        int s_i = qq * 4 + j;
        float Bv = db[3 + s_i];
        float Cv = db[19 + s_i];
        hst[j] = __expf(dtval * negA[j]) * hst[j] + dtval * Bv * xval;
        part += hst[j] * Cv;
      }
      part += __shfl_xor(part, 1);
      part += __shfl_xor(part, 2);
      if (qq == 0) {
        float yv = part + xval * wD;
        float z = xz[t * 160 + 80 + d_ch];
        yb[t * 80 + d_ch] = yv * z / (1.f + __expf(-z));
      }
    }
    __syncthreads();                                   // B4: yb ready

    // ---- out_proj + residual, 2 tokens/pair -> paired dwordx2 stores ----
    {
      float sa, sb;
      {
        const float4* yp = (const float4*)&yb[t_o * 80 + halfp * 40];
        float s = 0.f;
#pragma unroll
        for (int k = 0; k < 10; ++k) {
          float4 v = yp[k];
          s += w_out_r[4 * k] * v.x + w_out_r[4 * k + 1] * v.y
             + w_out_r[4 * k + 2] * v.z + w_out_r[4 * k + 3] * v.w;
        }
        sa = s + __shfl_xor(s, 1);
      }
      {
        const float4* yp = (const float4*)&yb[(t_o + 4) * 80 + halfp * 40];
        float s = 0.f;
#pragma unroll
        for (int k = 0; k < 10; ++k) {
          float4 v = yp[k];
          s += w_out_r[4 * k] * v.x + w_out_r[4 * k + 1] * v.y
             + w_out_r[4 * k + 2] * v.z + w_out_r[4 * k + 3] * v.w;
        }
        sb = s + __shfl_xor(s, 1);
      }
      float ra = xin0[p_o] + sa;         // valid on pair leaders (halfp==0)
      float rb = xin0[p_o + 160] + sb;
      float ra2 = __shfl_xor(ra, 2);     // leader tid+2's value (p_o+1)
      float rb2 = __shfl_xor(rb, 2);
      if ((tid & 3) == 0) {              // even p_o leaders store pairs
        __hip_atomic_store((u64*)(dst + t0 * 40 + p_o), pack2(ra, ra2),
                           __ATOMIC_RELAXED, __HIP_MEMORY_SCOPE_AGENT);
        __hip_atomic_store((u64*)(dst + t0 * 40 + p_o + 160), pack2(rb, rb2),
                           __ATOMIC_RELAXED, __HIP_MEMORY_SCOPE_AGENT);
      }
    }
    __syncthreads();        // B5: drains vmcnt -> all stores acked at IF$
    if (tid == 0)
      __hip_atomic_store(flag_cur, c + 1, __ATOMIC_RELAXED,
                         __HIP_MEMORY_SCOPE_AGENT);
  }
}

// ---- context side of cross-attn: cn = LN(x_final), kv = cn @ ca_kv_w^T ----
__global__ __launch_bounds__(64) void kv_kernel(
    const float* __restrict__ xfin,
    const float* __restrict__ lnc_w, const float* __restrict__ lnc_b,
    const float* __restrict__ kv_w,
    float* __restrict__ kbuf, float* __restrict__ vbuf)
{
  int t = blockIdx.x;
  int lane = threadIdx.x;
  float x = (lane < 40) ? xfin[t * 40 + lane] : 0.f;
  float s = x;
#pragma unroll
  for (int o = 32; o >= 1; o >>= 1) s += __shfl_xor(s, o);
  float m = s * (1.f / 40.f);
  float dv = (lane < 40) ? (x - m) : 0.f;
  float v2 = dv * dv;
#pragma unroll
  for (int o = 32; o >= 1; o >>= 1) v2 += __shfl_xor(v2, o);
  float rstd = rsqrtf(v2 * (1.f / 40.f) + 1e-5f);
  __shared__ float cn[40];
  if (lane < 40) cn[lane] = dv * rstd * lnc_w[lane] + lnc_b[lane];
  __syncthreads();
  for (int e = lane; e < 80; e += 64) {
    float acc = 0.f;
#pragma unroll
    for (int d = 0; d < 40; ++d) acc += cn[d] * kv_w[e * 40 + d];
    if (e < 40) kbuf[t * 40 + e] = acc;
    else vbuf[t * 40 + (e - 40)] = acc;
  }
}

// ---- fast query decode: precomputed q, 4-way token split per query ----
__global__ __launch_bounds__(256) void query_fast(
    const float* __restrict__ qstore,    // q_t[e*65536 + n]
    const float* __restrict__ ow, const float* __restrict__ ob,
    const float* __restrict__ flw, const float* __restrict__ flb,
    const float* __restrict__ w1, const float* __restrict__ b1,
    const float* __restrict__ w2, const float* __restrict__ b2,
    const float* __restrict__ outw, const float* __restrict__ outb,
    const float* __restrict__ kbuf, const float* __restrict__ vbuf,
    float* __restrict__ out)
{
  const int tid = threadIdx.x;
  const int h = __builtin_amdgcn_readfirstlane((tid >> 6) & 3);  // wave 0..3
  const int lane = tid & 63;
  const int n = blockIdx.x * 64 + lane;
  const int p1 = tid ^ 64, p2 = tid ^ 128, p3 = tid ^ 192;
  __shared__ float colbuf[40 * 256];     // 40KB: merge staging (reused)

  // load precomputed q (coalesced per e-plane)
  float q[40];
#pragma unroll
  for (int e = 0; e < 40; ++e) q[e] = qstore[e * 65536 + n];

  // flash attention over this wave's 100 tokens, 2 tokens per step (ILP)
  float acc[40];
#pragma unroll
  for (int d = 0; d < 40; ++d) acc[d] = 0.f;
  float mx = -1e30f, l = 0.f;
  const float scale = 0.15811388300841897f;  // 40^-0.5
  const int tbeg = h * 100;
#pragma unroll 1
  for (int t = tbeg; t < tbeg + 100; t += 2) {
    const float4* ka = (const float4*)(kbuf + t * 40);
    const float4* kb = (const float4*)(kbuf + t * 40 + 40);
    float a0 = 0.f, a1 = 0.f, b0 = 0.f, b1s = 0.f;
#pragma unroll
    for (int k = 0; k < 10; ++k) {
      float4 k4 = ka[k];
      float4 j4 = kb[k];
      a0 += q[4 * k] * k4.x + q[4 * k + 1] * k4.y;
      a1 += q[4 * k + 2] * k4.z + q[4 * k + 3] * k4.w;
      b0 += q[4 * k] * j4.x + q[4 * k + 1] * j4.y;
      b1s += q[4 * k + 2] * j4.z + q[4 * k + 3] * j4.w;
    }
    float sa = (a0 + a1) * scale;
    float sb = (b0 + b1s) * scale;
    // sequential online-softmax updates (dots above carried the ILP)
    {
      if (sa > mx) {
        float corr = __expf(mx - sa);
        l *= corr;
#pragma unroll
        for (int d = 0; d < 40; ++d) acc[d] *= corr;
        mx = sa;
      }
      float p = __expf(sa - mx);
      l += p;
      const float4* vr = (const float4*)(vbuf + t * 40);
#pragma unroll
      for (int k = 0; k < 10; ++k) {
        float4 v4 = vr[k];
        acc[4 * k] += p * v4.x; acc[4 * k + 1] += p * v4.y;
        acc[4 * k + 2] += p * v4.z; acc[4 * k + 3] += p * v4.w;
      }
    }
    {
      if (sb > mx) {
        float corr = __expf(mx - sb);
        l *= corr;
#pragma unroll
        for (int d = 0; d < 40; ++d) acc[d] *= corr;
        mx = sb;
      }
      float p = __expf(sb - mx);
      l += p;
      const float4* vr = (const float4*)(vbuf + (t + 1) * 40);
#pragma unroll
      for (int k = 0; k < 10; ++k) {
        float4 v4 = vr[k];
        acc[4 * k] += p * v4.x; acc[4 * k + 1] += p * v4.y;
        acc[4 * k + 2] += p * v4.z; acc[4 * k + 3] += p * v4.w;
      }
    }
  }

  // ---- 4-way merge: m/l first (colbuf rows 0-1), then acc columns ----
  {
    float* redm = colbuf;          // [256]
    float* redl = colbuf + 256;    // [256]
    redm[tid] = mx; redl[tid] = l;
  }
  __syncthreads();                                    // B1
  float a0c, a1c, a2c, a3c, linv;
  {
    float m1 = colbuf[p1], m2 = colbuf[p2], m3 = colbuf[p3];
    float l1 = colbuf[256 + p1], l2 = colbuf[256 + p2], l3 = colbuf[256 + p3];
    float nm = fmaxf(fmaxf(mx, m1), fmaxf(m2, m3));
    a0c = __expf(mx - nm); a1c = __expf(m1 - nm);
    a2c = __expf(m2 - nm); a3c = __expf(m3 - nm);
    float L = l * a0c + l1 * a1c + l2 * a2c + l3 * a3c;
    linv = 1.f / L;
  }
  __syncthreads();                                    // B2 (m/l region free)
#pragma unroll
  for (int d = 0; d < 40; ++d) colbuf[d * 256 + tid] = acc[d];
  __syncthreads();                                    // B3
  float lat[40];
#pragma unroll
  for (int d = 0; d < 40; ++d)
    lat[d] = (acc[d] * a0c + colbuf[d * 256 + p1] * a1c
            + colbuf[d * 256 + p2] * a2c + colbuf[d * 256 + p3] * a3c) * linv;
  __syncthreads();                                    // B4 (colbuf free)

  // ---- lat2 = lat @ ca_out_w^T + ob, d-range split by wave (10 each) ----
  float lath[10];
#pragma unroll
  for (int dd = 0; dd < 10; ++dd) {
    float v = lat[dd];
    v = (h == 1) ? lat[dd + 10] : v;
    v = (h == 2) ? lat[dd + 20] : v;
    v = (h == 3) ? lat[dd + 30] : v;
    lath[dd] = v;
  }
  float lp[40];
#pragma unroll
  for (int e = 0; e < 40; ++e) lp[e] = 0.f;
#pragma unroll 1
  for (int dd = 0; dd < 10; ++dd) {
    const float lv = lath[dd];
    const int d = h * 10 + dd;
#pragma unroll
    for (int e = 0; e < 40; ++e) lp[e] += lv * ow[e * 40 + d];
  }
#pragma unroll
  for (int e = 0; e < 40; ++e) colbuf[e * 256 + tid] = lp[e];
  __syncthreads();                                    // B5
  float lat2[40];
#pragma unroll
  for (int e = 0; e < 40; ++e)
    lat2[e] = ob[e] + lp[e] + colbuf[e * 256 + p1]
            + colbuf[e * 256 + p2] + colbuf[e * 256 + p3];
  __syncthreads();                                    // B6 (colbuf free)

  // ---- LN + FFN (e-range split by wave: 40 each) ----
  float hh[40];
  {
    float m = 0.f;
#pragma unroll
    for (int d = 0; d < 40; ++d) m += lat2[d];
    m *= (1.f / 40.f);
    float var = 0.f;
#pragma unroll
    for (int d = 0; d < 40; ++d) { float dv = lat2[d] - m; var += dv * dv; }
    float rstd = rsqrtf(var * (1.f / 40.f) + 1e-5f);
#pragma unroll
    for (int d = 0; d < 40; ++d) hh[d] = (lat2[d] - m) * rstd * flw[d] + flb[d];
  }
  float ff[40];
#pragma unroll
  for (int d = 0; d < 40; ++d) ff[d] = 0.f;
#pragma unroll 1
  for (int ee = 0; ee < 40; ++ee) {
    const int e = h * 40 + ee;
    const float* r1 = w1 + e * 40;
    const float* r2 = w1 + (160 + e) * 40;
    float s0 = 0.f, s1 = 0.f;
#pragma unroll
    for (int d = 0; d < 40; ++d) { s0 += hh[d] * r1[d]; s1 += hh[d] * r2[d]; }
    float x1 = s0 + b1[e];
    float g = s1 + b1[160 + e];
    float tv = x1 * (0.5f * g * (1.f + erff(g * 0.70710678118654752f)));
#pragma unroll
    for (int d = 0; d < 40; ++d) ff[d] += tv * w2[d * 160 + e];
  }
#pragma unroll
  for (int d = 0; d < 40; ++d) colbuf[d * 256 + tid] = ff[d];
  __syncthreads();                                    // B7
  float r = outb[0];
#pragma unroll
  for (int d = 0; d < 40; ++d) {
    float f = ff[d] + colbuf[d * 256 + p1] + colbuf[d * 256 + p2]
            + colbuf[d * 256 + p3] + b2[d];
    r += (lat2[d] + f) * outw[d];
  }
  if (h == 0) out[n] = r;
}

// ---- fallback query (R8, PE inside) for small ws ----
__global__ __launch_bounds__(256) void query_kernel_fb(
    const float* __restrict__ qry,
    const float* __restrict__ pe_w, const float* __restrict__ pe_b,
    const float* __restrict__ lnq_w, const float* __restrict__ lnq_b,
    const float* __restrict__ qw,
    const float* __restrict__ ow, const float* __restrict__ ob,
    const float* __restrict__ flw, const float* __restrict__ flb,
    const float* __restrict__ w1, const float* __restrict__ b1,
    const float* __restrict__ w2, const float* __restrict__ b2,
    const float* __restrict__ outw, const float* __restrict__ outb,
    const float* __restrict__ kbuf, const float* __restrict__ vbuf,
    float* __restrict__ out)
{
  const int tid = threadIdx.x;
  const int h = __builtin_amdgcn_readfirstlane((tid >> 6) & 1);
  const int pj = tid >> 7;
  const int lane = tid & 63;
  const int n = blockIdx.x * 128 + pj * 64 + lane;
  const int ptn = tid ^ 64;
  __shared__ float colbuf[40 * 256];
  __shared__ float redm[256], redl[256];

  const float qx = qry[n * 3 + 0], qy = qry[n * 3 + 1], qz = qry[n * 3 + 2];
  float qp[40];
#pragma unroll
  for (int d = 0; d < 40; ++d) qp[d] = 0.f;
#pragma unroll
  for (int jj = 0; jj < 4; ++jj) {
    const int j = h * 4 + jj;
    float f = 3.14159265358979323846f * (float)(1 << j);
    float sx, cx, sy, cy, sz, cz;
    __sincosf(qx * f, &sx, &cx);
    __sincosf(qy * f, &sy, &cy);
    __sincosf(qz * f, &sz, &cz);
#pragma unroll
    for (int d = 0; d < 40; ++d) {
      const float* r = pe_w + d * 51;
      qp[d] += sx * r[j] + sy * r[j + 8] + sz * r[j + 16]
             + cx * r[j + 24] + cy * r[j + 32] + cz * r[j + 40];
    }
  }
#pragma unroll
  for (int d = 0; d < 40; ++d) colbuf[d * 256 + tid] = qp[d];
  __syncthreads();
  float qe[40];
#pragma unroll
  for (int d = 0; d < 40; ++d) {
    const float* r = pe_w + d * 51;
    qe[d] = pe_b[d] + qp[d] + colbuf[d * 256 + ptn]
          + qx * r[48] + qy * r[49] + qz * r[50];
  }
  __syncthreads();
  float qn[40];
  {
    float m = 0.f;
#pragma unroll
    for (int d = 0; d < 40; ++d) m += qe[d];
    m *= (1.f / 40.f);
    float var = 0.f;
#pragma unroll
    for (int d = 0; d < 40; ++d) { float dv = qe[d] - m; var += dv * dv; }
    float rstd = rsqrtf(var * (1.f / 40.f) + 1e-5f);
#pragma unroll
    for (int d = 0; d < 40; ++d) qn[d] = (qe[d] - m) * rstd * lnq_w[d] + lnq_b[d];
  }
  float qnh[20];
#pragma unroll
  for (int dd = 0; dd < 20; ++dd) qnh[dd] = h ? qn[dd + 20] : qn[dd];
  float q[40];
#pragma unroll
  for (int e = 0; e < 40; ++e) q[e] = 0.f;
#pragma unroll 1
  for (int dd = 0; dd < 20; ++dd) {
    const float qv = qnh[dd];
    const int d = h * 20 + dd;
#pragma unroll
    for (int e = 0; e < 40; ++e) q[e] += qv * qw[e * 40 + d];
  }
#pragma unroll
  for (int e = 0; e < 40; ++e) colbuf[e * 256 + tid] = q[e];
  __syncthreads();
#pragma unroll
  for (int e = 0; e < 40; ++e) q[e] += colbuf[e * 256 + ptn];
  __syncthreads();

  float acc[40];
#pragma unroll
  for (int d = 0; d < 40; ++d) acc[d] = 0.f;
  float mx = -1e30f, l = 0.f;
  const float scale = 0.15811388300841897f;
  const int tbeg = h * 200, tend = tbeg + 200;
#pragma unroll 1
  for (int t = tbeg; t < tend; ++t) {
    const float4* kr = (const float4*)(kbuf + t * 40);
    float s0 = 0.f, s1 = 0.f, s2 = 0.f, s3 = 0.f;
#pragma unroll
    for (int k = 0; k < 10; ++k) {
      float4 k4 = kr[k];
      s0 += q[4 * k] * k4.x; s1 += q[4 * k + 1] * k4.y;
      s2 += q[4 * k + 2] * k4.z; s3 += q[4 * k + 3] * k4.w;
    }
    float s = ((s0 + s1) + (s2 + s3)) * scale;
    if (s > mx) {
      float corr = __expf(mx - s);
      l *= corr;
#pragma unroll
      for (int d = 0; d < 40; ++d) acc[d] *= corr;
      mx = s;
    }
    float p = __expf(s - mx);
    l += p;
    const float4* vr = (const float4*)(vbuf + t * 40);
#pragma unroll
    for (int k = 0; k < 10; ++k) {
      float4 v4 = vr[k];
      acc[4 * k] += p * v4.x; acc[4 * k + 1] += p * v4.y;
      acc[4 * k + 2] += p * v4.z; acc[4 * k + 3] += p * v4.w;
    }
  }
#pragma unroll
  for (int d = 0; d < 40; ++d) colbuf[d * 256 + tid] = acc[d];
  redm[tid] = mx; redl[tid] = l;
  __syncthreads();
  float lat[40];
  {
    float m2 = redm[ptn];
    float l2 = redl[ptn];
    float nm = fmaxf(mx, m2);
    float a = __expf(mx - nm), b = __expf(m2 - nm);
    float lm = l * a + l2 * b;
    float linv = 1.f / lm;
#pragma unroll
    for (int d = 0; d < 40; ++d)
      lat[d] = (acc[d] * a + colbuf[d * 256 + ptn] * b) * linv;
  }
  __syncthreads();
  float lath[20];
#pragma unroll
  for (int dd = 0; dd < 20; ++dd) lath[dd] = h ? lat[dd + 20] : lat[dd];
  float lp[40];
#pragma unroll
  for (int e = 0; e < 40; ++e) lp[e] = 0.f;
#pragma unroll 1
  for (int dd = 0; dd < 20; ++dd) {
    const float lv = lath[dd];
    const int d = h * 20 + dd;
#pragma unroll
    for (int e = 0; e < 40; ++e) lp[e] += lv * ow[e * 40 + d];
  }
#pragma unroll
  for (int e = 0; e < 40; ++e) colbuf[e * 256 + tid] = lp[e];
  __syncthreads();
  float lat2[40];
#pragma unroll
  for (int e = 0; e < 40; ++e) lat2[e] = ob[e] + lp[e] + colbuf[e * 256 + ptn];
  __syncthreads();
  float hh[40];
  {
    float m = 0.f;
#pragma unroll
    for (int d = 0; d < 40; ++d) m += lat2[d];
    m *= (1.f / 40.f);
    float var = 0.f;
#pragma unroll
    for (int d = 0; d < 40; ++d) { float dv = lat2[d] - m; var += dv * dv; }
    float rstd = rsqrtf(var * (1.f / 40.f) + 1e-5f);
#pragma unroll
    for (int d = 0; d < 40; ++d) hh[d] = (lat2[d] - m) * rstd * flw[d] + flb[d];
  }
  float ff[40];
#pragma unroll
  for (int d = 0; d < 40; ++d) ff[d] = 0.f;
#pragma unroll 1
  for (int ee = 0; ee < 80; ++ee) {
    const int e = h * 80 + ee;
    const float* r1 = w1 + e * 40;
    const float* r2 = w1 + (160 + e) * 40;
    float s0 = 0.f, s1 = 0.f;
#pragma unroll
    for (int d = 0; d < 40; ++d) { s0 += hh[d] * r1[d]; s1 += hh[d] * r2[d]; }
    float x1 = s0 + b1[e];
    float g = s1 + b1[160 + e];
    float tv = x1 * (0.5f * g * (1.f + erff(g * 0.70710678118654752f)));
#pragma unroll
    for (int d = 0; d < 40; ++d) ff[d] += tv * w2[d * 160 + e];
  }
#pragma unroll
  for (int d = 0; d < 40; ++d) colbuf[d * 256 + tid] = ff[d];
  __syncthreads();
  float r = outb[0];
#pragma unroll
  for (int d = 0; d < 40; ++d) {
    float f = ff[d] + colbuf[d * 256 + ptn] + b2[d];
    r += (lat2[d] + f) * outw[d];
  }
  if (h == 0) out[n] = r;
}

extern "C" void kernel_launch(void* const* d_in, const int* in_sizes, int n_in,
                              void* d_out, int out_size, void* d_ws, size_t ws_size,
                              hipStream_t stream) {
  const float* mash   = (const float*)d_in[0];
  const float* qry    = (const float*)d_in[1];
  const float* lnw    = (const float*)d_in[2];
  const float* linw   = (const float*)d_in[3];
  const float* lconvw = (const float*)d_in[4];
  const float* lconvb = (const float*)d_in[5];
  const float* lxpw   = (const float*)d_in[6];
  const float* ldtw   = (const float*)d_in[7];
  const float* ldtb   = (const float*)d_in[8];
  const float* lAlog  = (const float*)d_in[9];
  const float* lD     = (const float*)d_in[10];
  const float* loutw  = (const float*)d_in[11];
  const float* pew    = (const float*)d_in[12];
  const float* peb    = (const float*)d_in[13];
  const float* lnqw   = (const float*)d_in[14];
  const float* lnqb   = (const float*)d_in[15];
  const float* lncw   = (const float*)d_in[16];
  const float* lncb   = (const float*)d_in[17];
  const float* qw     = (const float*)d_in[18];
  const float* kvw    = (const float*)d_in[19];
  const float* oww    = (const float*)d_in[20];
  const float* owb    = (const float*)d_in[21];
  const float* flnw   = (const float*)d_in[22];
  const float* flnb   = (const float*)d_in[23];
  const float* w1     = (const float*)d_in[24];
  const float* b1     = (const float*)d_in[25];
  const float* w2     = (const float*)d_in[26];
  const float* b2     = (const float*)d_in[27];
  const float* outw   = (const float*)d_in[28];
  const float* outb   = (const float*)d_in[29];

  // ws layout (floats): xb0[16000] xb1[16000] k[16000] v[16000]
  //                     flags[4096 ints] qstore[40*65536]
  float* wsf = (float*)d_ws;
  float* xb0 = wsf;
  float* xb1 = wsf + 16000;
  float* kbuf = wsf + 32000;
  float* vbuf = wsf + 48000;
  int* flags = (int*)(wsf + 64000);
  float* qstore = wsf + 68096;
  const size_t needed = (size_t)68096 * 4 + (size_t)40 * 65536 * 4;
  const bool pre = ws_size >= needed;   // constant across calls -> capture-safe

  hipLaunchKernelGGL(init_flags, dim3(16), dim3(256), 0, stream, flags);
  // 256 layer blocks + (pre ? 205 PE blocks : 0); layer blocks dispatch first
  hipLaunchKernelGGL(mamba_pipe, dim3(pre ? 461 : 256), dim3(TPB1), 0, stream,
                     mash, lnw, linw, lconvw, lconvb, lxpw, ldtw, ldtb, lAlog,
                     lD, loutw, xb0, xb1, flags,
                     qry, pew, peb, lnqw, lnqb, qw, qstore);
  // layer 255 (odd) writes xb1
  hipLaunchKernelGGL(kv_kernel, dim3(400), dim3(64), 0, stream,
                     xb1, lncw, lncb, kvw, kbuf, vbuf);
  if (pre) {
    hipLaunchKernelGGL(query_fast, dim3(1024), dim3(256), 0, stream,
                       qstore, oww, owb, flnw, flnb,
                       w1, b1, w2, b2, outw, outb, kbuf, vbuf, (float*)d_out);
  } else {
    hipLaunchKernelGGL(query_kernel_fb, dim3(512), dim3(256), 0, stream,
                       qry, pew, peb, lnqw, lnqb, qw, oww, owb, flnw, flnb,
                       w1, b1, w2, b2, outw, outb, kbuf, vbuf, (float*)d_out);
  }
}

// Round 5
// 2678.230 us; speedup vs baseline: 1.7295x; 1.0659x over previous
//
#include <hip/hip_runtime.h>

// ---------------------------------------------------------------------------
// MashDecoderV2: 256-layer mamba stack (L=400, D=40) + 65536-query cross-attn
// decoder. f32 throughout (threshold 1.56e-2; absmax 2e-3).
//
// Round-14: CH=2 + 4-phase layer body. Measured model from R9 (CH=4, 1820us)
// and R13 (CH=8, 2497us): P(CH) = L + c*CH with L~1.5us, c~0.74us/token;
// T = 255*(P+f) + (400/CH)*P is minimized at CH~2 (predicted ~1590us), NOT
// large CH (R13's mistake). Additionally L shrinks by one phase: at CH=2 each
// in_proj thread owns column e for BOTH tokens, so the depthwise conv folds
// inline into Phase A with its 3-token history in REGISTERS (h0,h1,h2) ->
// conv phase, its barrier, xhist LDS and refresh logic all deleted.
// Iteration: A(acquire+in_proj+conv+silu) -> B1 -> x_proj -> B2 ->
// scan(2 steps) -> B3 -> out_proj+store -> B4 -> flag. 320-thread blocks
// (R9's proven register regime: VGPR ~120 + AGPR overflow, no scratch).
// PE blocks + stage 2 (kv_kernel, query_fast) identical to R9/R13.
// ---------------------------------------------------------------------------

#define CH 2
#define NCHUNK 200       // 400 / CH
#define TPB1 320

typedef unsigned long long u64;

__device__ __forceinline__ u64 pack2(float a, float b) {
  return ((u64)__float_as_uint(b) << 32) | (u64)__float_as_uint(a);
}
__device__ __forceinline__ float unplo(u64 a) {
  return __uint_as_float((unsigned)a);
}
__device__ __forceinline__ float unphi(u64 a) {
  return __uint_as_float((unsigned)(a >> 32));
}

__global__ void init_flags(int* __restrict__ flags) {
  int i = blockIdx.x * 256 + threadIdx.x;
  if (i < 256 * 16) flags[i] = 0;
}

__global__ __launch_bounds__(TPB1) void mamba_pipe(
    const float* __restrict__ mash,
    const float* __restrict__ g_norm_w,   // (256,40)
    const float* __restrict__ g_in_w,     // (256,160,40)
    const float* __restrict__ g_conv_w,   // (256,80,4)
    const float* __restrict__ g_conv_b,   // (256,80)
    const float* __restrict__ g_xp_w,     // (256,35,80)
    const float* __restrict__ g_dt_w,     // (256,80,3)
    const float* __restrict__ g_dt_b,     // (256,80)
    const float* __restrict__ g_alog,     // (256,80,16)
    const float* __restrict__ g_D,        // (256,80)
    const float* __restrict__ g_out_w,    // (256,40,80)
    float* __restrict__ xb0,
    float* __restrict__ xb1,
    int* __restrict__ flags,
    // PE-block inputs (blocks >= 256)
    const float* __restrict__ qry,
    const float* __restrict__ pe_w, const float* __restrict__ pe_b,
    const float* __restrict__ lnq_w, const float* __restrict__ lnq_b,
    const float* __restrict__ qw,
    float* __restrict__ qstore)           // q_t[e*65536 + n]
{
  const int tid = threadIdx.x;

  // ---------------- PE blocks: query preprocessing under mamba's shadow ----
  if (blockIdx.x >= 256) {
    const int n = (blockIdx.x - 256) * TPB1 + tid;
    if (n < 65536) {
      const float qx = qry[n * 3 + 0], qy = qry[n * 3 + 1], qz = qry[n * 3 + 2];
      float qe[40];
#pragma unroll
      for (int d = 0; d < 40; ++d) qe[d] = pe_b[d];
#pragma unroll 1
      for (int j = 0; j < 8; ++j) {
        float f = 3.14159265358979323846f * (float)(1 << j);
        float sx, cx, sy, cy, sz, cz;
        __sincosf(qx * f, &sx, &cx);
        __sincosf(qy * f, &sy, &cy);
        __sincosf(qz * f, &sz, &cz);
#pragma unroll
        for (int d = 0; d < 40; ++d) {
          const float* r = pe_w + d * 51;
          qe[d] += sx * r[j] + sy * r[j + 8] + sz * r[j + 16]
                 + cx * r[j + 24] + cy * r[j + 32] + cz * r[j + 40];
        }
      }
#pragma unroll
      for (int d = 0; d < 40; ++d) {
        const float* r = pe_w + d * 51;
        qe[d] += qx * r[48] + qy * r[49] + qz * r[50];
      }
      // LN -> qn (registers)
      float qn[40];
      {
        float m = 0.f;
#pragma unroll
        for (int d = 0; d < 40; ++d) m += qe[d];
        m *= (1.f / 40.f);
        float var = 0.f;
#pragma unroll
        for (int d = 0; d < 40; ++d) { float dv = qe[d] - m; var += dv * dv; }
        float rstd = rsqrtf(var * (1.f / 40.f) + 1e-5f);
#pragma unroll
        for (int d = 0; d < 40; ++d)
          qn[d] = (qe[d] - m) * rstd * lnq_w[d] + lnq_b[d];
      }
      // q-proj, fully unrolled (constant reg indices; qw scalar loads)
      float q[40];
#pragma unroll
      for (int e = 0; e < 40; ++e) {
        const float* r = qw + e * 40;
        float s = 0.f;
#pragma unroll
        for (int d = 0; d < 40; ++d) s += qn[d] * r[d];
        q[e] = s;
      }
#pragma unroll
      for (int e = 0; e < 40; ++e) qstore[e * 65536 + n] = q[e];
    }
    return;
  }

  // ---------------- layer blocks: CH=2, 4-phase body ----------------------
  const int layer = blockIdx.x;

  __shared__ float xs[2][80];       // conv+silu output (2 tokens)
  __shared__ float zb[2][80];       // z gate
  __shared__ float dbc[2][36];      // x_proj output (35 + pad)
  __shared__ float yb[2][80];       // scan output (gated)
  __shared__ float xin0[80];        // residual input (2 tokens x 40)

  // role E (tid<160): in_proj column e for BOTH tokens; e<80 also conv inline
  float w_in_r[40];                 // in_proj row with rmsnorm weight folded
  if (tid < 160) {
    const float4* g = (const float4*)(g_in_w + layer * 6400 + tid * 40);
    const float4* nw = (const float4*)(g_norm_w + layer * 40);
#pragma unroll
    for (int k = 0; k < 10; ++k) {
      float4 v = g[k];
      float4 n = nw[k];
      w_in_r[4 * k] = v.x * n.x; w_in_r[4 * k + 1] = v.y * n.y;
      w_in_r[4 * k + 2] = v.z * n.z; w_in_r[4 * k + 3] = v.w * n.w;
    }
  }
  float cw0, cw1, cw2, cw3, cb;
  float h0 = 0.f, h1 = 0.f, h2 = 0.f;   // conv history: tokens t0-3,t0-2,t0-1
  if (tid < 80) {
    float4 v = *(const float4*)(g_conv_w + layer * 320 + tid * 4);
    cw0 = v.x; cw1 = v.y; cw2 = v.z; cw3 = v.w;
    cb = g_conv_b[layer * 80 + tid];
  }
  const int halfp = tid & 1;
  const int p_x = tid >> 1;              // <70 active for x_proj
  const int t_x = p_x / 35, e_x = p_x % 35;
  float w_xp_r[40];
  if (p_x < 70) {
    const float4* g = (const float4*)(g_xp_w + layer * 2800 + e_x * 80 + halfp * 40);
#pragma unroll
    for (int k = 0; k < 10; ++k) {
      float4 v = g[k];
      w_xp_r[4 * k] = v.x; w_xp_r[4 * k + 1] = v.y;
      w_xp_r[4 * k + 2] = v.z; w_xp_r[4 * k + 3] = v.w;
    }
  }
  const int d_ch = tid >> 2;
  const int qq = tid & 3;
  float negA[4], hst[4];
  {
    float4 v = *(const float4*)(g_alog + layer * 1280 + tid * 4);
    negA[0] = -__expf(v.x); negA[1] = -__expf(v.y);
    negA[2] = -__expf(v.z); negA[3] = -__expf(v.w);
    hst[0] = hst[1] = hst[2] = hst[3] = 0.f;
  }
  const float dtw0 = g_dt_w[layer * 240 + d_ch * 3 + 0];
  const float dtw1 = g_dt_w[layer * 240 + d_ch * 3 + 1];
  const float dtw2 = g_dt_w[layer * 240 + d_ch * 3 + 2];
  const float dtb = g_dt_b[layer * 80 + d_ch];
  const float wD = g_D[layer * 80 + d_ch];
  const int p_o = tid >> 1;              // <80 active for out_proj
  const int t_o = p_o / 40, e_o = p_o % 40;
  float w_out_r[40];
  if (p_o < 80) {
    const float4* g = (const float4*)(g_out_w + layer * 3200 + e_o * 80 + halfp * 40);
#pragma unroll
    for (int k = 0; k < 10; ++k) {
      float4 v = g[k];
      w_out_r[4 * k] = v.x; w_out_r[4 * k + 1] = v.y;
      w_out_r[4 * k + 2] = v.z; w_out_r[4 * k + 3] = v.w;
    }
  }
  __syncthreads();

  const float* src = (layer == 0) ? mash : ((layer & 1) ? xb0 : xb1);
  float* dst = (layer & 1) ? xb1 : xb0;
  int* flag_prev = flags + (layer - 1) * 16;
  int* flag_cur = flags + layer * 16;

  for (int c = 0; c < NCHUNK; ++c) {
    const int t0 = c * CH;

    // ---- Phase A: acquire + in_proj (both tokens) + inline conv + silu ----
    float xzv0 = 0.f, xzv1 = 0.f;
    if (layer == 0) {
      if (tid < 160) {
#pragma unroll
        for (int t = 0; t < 2; ++t) {
          const float4* sp = (const float4*)(src + (t0 + t) * 40);
          float ss = 0.f, sd = 0.f;
#pragma unroll
          for (int k = 0; k < 10; ++k) {
            float4 v = sp[k];
            ss += v.x * v.x + v.y * v.y + v.z * v.z + v.w * v.w;
            sd += w_in_r[4 * k] * v.x + w_in_r[4 * k + 1] * v.y
                + w_in_r[4 * k + 2] * v.z + w_in_r[4 * k + 3] * v.w;
          }
          float v = sd * rsqrtf(ss * (1.f / 40.f) + 1e-5f);
          if (t == 0) xzv0 = v; else xzv1 = v;
        }
      } else if (tid < 240) {
        xin0[tid - 160] = src[t0 * 40 + (tid - 160)];
      }
    } else {
      // every wave polls (wave-uniform); loads are program-ordered after the
      // observed flag -> guaranteed fresh (producer B4-drained before flag)
      while (__hip_atomic_load(flag_prev, __ATOMIC_RELAXED,
                               __HIP_MEMORY_SCOPE_AGENT) <= c)
        __builtin_amdgcn_s_sleep(1);
      if (tid < 160) {
#pragma unroll
        for (int t = 0; t < 2; ++t) {
          const u64* sp = (const u64*)(src + (t0 + t) * 40);
          float ss = 0.f, sd = 0.f;
#pragma unroll
          for (int k = 0; k < 20; ++k) {
            u64 a = __hip_atomic_load(sp + k, __ATOMIC_RELAXED,
                                      __HIP_MEMORY_SCOPE_AGENT);
            float v0 = unplo(a), v1 = unphi(a);
            ss += v0 * v0 + v1 * v1;
            sd += w_in_r[2 * k] * v0 + w_in_r[2 * k + 1] * v1;
          }
          float v = sd * rsqrtf(ss * (1.f / 40.f) + 1e-5f);
          if (t == 0) xzv0 = v; else xzv1 = v;
        }
      } else if (tid < 200) {
        u64 a = __hip_atomic_load((const u64*)(src + t0 * 40) + (tid - 160),
                                  __ATOMIC_RELAXED, __HIP_MEMORY_SCOPE_AGENT);
        xin0[2 * (tid - 160)] = unplo(a);
        xin0[2 * (tid - 160) + 1] = unphi(a);
      }
    }
    if (tid < 80) {
      // depthwise conv(4) inline, history in registers
      float c0 = cb + cw0 * h0 + cw1 * h1 + cw2 * h2 + cw3 * xzv0;
      float c1 = cb + cw0 * h1 + cw1 * h2 + cw2 * xzv0 + cw3 * xzv1;
      xs[0][tid] = c0 / (1.f + __expf(-c0));
      xs[1][tid] = c1 / (1.f + __expf(-c1));
      h0 = h2; h1 = xzv0; h2 = xzv1;    // history -> tokens t0-1, t0, t0+1
    } else if (tid < 160) {
      zb[0][tid - 80] = xzv0;
      zb[1][tid - 80] = xzv1;
    }
    __syncthreads();                                   // B1: xs, zb, xin0

    // ---- x_proj: pair half-dots + shfl merge (2 tokens x 35 outputs) ----
    if (p_x < 70) {
      const float4* xp = (const float4*)&xs[t_x][halfp * 40];
      float s = 0.f;
#pragma unroll
      for (int k = 0; k < 10; ++k) {
        float4 v = xp[k];
        s += w_xp_r[4 * k] * v.x + w_xp_r[4 * k + 1] * v.y
           + w_xp_r[4 * k + 2] * v.z + w_xp_r[4 * k + 3] * v.w;
      }
      s += __shfl_xor(s, 1);
      if (halfp == 0) dbc[t_x][e_x] = s;
    }
    __syncthreads();                                   // B2: dbc ready

    // ---- selective scan; dt inline; state in regs; 2 steps ----
#pragma unroll
    for (int t = 0; t < CH; ++t) {
      const float* db = &dbc[t][0];
      float sdt = dtb + db[0] * dtw0 + db[1] * dtw1 + db[2] * dtw2;
      float dtval = (sdt > 15.f) ? sdt : __logf(1.f + __expf(sdt));
      float xval = xs[t][d_ch];
      float part = 0.f;
#pragma unroll
      for (int j = 0; j < 4; ++j) {
        int s_i = qq * 4 + j;
        float Bv = db[3 + s_i];
        float Cv = db[19 + s_i];
        hst[j] = __expf(dtval * negA[j]) * hst[j] + dtval * Bv * xval;
        part += hst[j] * Cv;
      }
      part += __shfl_xor(part, 1);
      part += __shfl_xor(part, 2);
      if (qq == 0) {
        float yv = part + xval * wD;
        float z = zb[t][d_ch];
        yb[t][d_ch] = yv * z / (1.f + __expf(-z));
      }
    }
    __syncthreads();                                   // B3: yb ready

    // ---- out_proj + residual -> paired dwordx2 coherent stores ----
    if (p_o < 80) {
      const float4* yp = (const float4*)&yb[t_o][halfp * 40];
      float s = 0.f;
#pragma unroll
      for (int k = 0; k < 10; ++k) {
        float4 v = yp[k];
        s += w_out_r[4 * k] * v.x + w_out_r[4 * k + 1] * v.y
           + w_out_r[4 * k + 2] * v.z + w_out_r[4 * k + 3] * v.w;
      }
      s += __shfl_xor(s, 1);
      float r = xin0[p_o] + s;         // valid on pair leaders (halfp==0)
      float r2 = __shfl_xor(r, 2);     // leader tid+2's value (p_o+1)
      if ((tid & 3) == 0)              // even p_o leaders store the pair
        __hip_atomic_store((u64*)(dst + t0 * 40 + p_o), pack2(r, r2),
                           __ATOMIC_RELAXED, __HIP_MEMORY_SCOPE_AGENT);
    }
    __syncthreads();        // B4: drains vmcnt -> all stores acked at IF$
    if (tid == 0)
      __hip_atomic_store(flag_cur, c + 1, __ATOMIC_RELAXED,
                         __HIP_MEMORY_SCOPE_AGENT);
  }
}

// ---- context side of cross-attn: cn = LN(x_final), kv = cn @ ca_kv_w^T ----
__global__ __launch_bounds__(64) void kv_kernel(
    const float* __restrict__ xfin,
    const float* __restrict__ lnc_w, const float* __restrict__ lnc_b,
    const float* __restrict__ kv_w,
    float* __restrict__ kbuf, float* __restrict__ vbuf)
{
  int t = blockIdx.x;
  int lane = threadIdx.x;
  float x = (lane < 40) ? xfin[t * 40 + lane] : 0.f;
  float s = x;
#pragma unroll
  for (int o = 32; o >= 1; o >>= 1) s += __shfl_xor(s, o);
  float m = s * (1.f / 40.f);
  float dv = (lane < 40) ? (x - m) : 0.f;
  float v2 = dv * dv;
#pragma unroll
  for (int o = 32; o >= 1; o >>= 1) v2 += __shfl_xor(v2, o);
  float rstd = rsqrtf(v2 * (1.f / 40.f) + 1e-5f);
  __shared__ float cn[40];
  if (lane < 40) cn[lane] = dv * rstd * lnc_w[lane] + lnc_b[lane];
  __syncthreads();
  for (int e = lane; e < 80; e += 64) {
    float acc = 0.f;
#pragma unroll
    for (int d = 0; d < 40; ++d) acc += cn[d] * kv_w[e * 40 + d];
    if (e < 40) kbuf[t * 40 + e] = acc;
    else vbuf[t * 40 + (e - 40)] = acc;
  }
}

// ---- fast query decode: precomputed q, 4-way token split per query ----
__global__ __launch_bounds__(256) void query_fast(
    const float* __restrict__ qstore,    // q_t[e*65536 + n]
    const float* __restrict__ ow, const float* __restrict__ ob,
    const float* __restrict__ flw, const float* __restrict__ flb,
    const float* __restrict__ w1, const float* __restrict__ b1,
    const float* __restrict__ w2, const float* __restrict__ b2,
    const float* __restrict__ outw, const float* __restrict__ outb,
    const float* __restrict__ kbuf, const float* __restrict__ vbuf,
    float* __restrict__ out)
{
  const int tid = threadIdx.x;
  const int h = __builtin_amdgcn_readfirstlane((tid >> 6) & 3);  // wave 0..3
  const int lane = tid & 63;
  const int n = blockIdx.x * 64 + lane;
  const int p1 = tid ^ 64, p2 = tid ^ 128, p3 = tid ^ 192;
  __shared__ float colbuf[40 * 256];     // 40KB: merge staging (reused)

  // load precomputed q (coalesced per e-plane)
  float q[40];
#pragma unroll
  for (int e = 0; e < 40; ++e) q[e] = qstore[e * 65536 + n];

  // flash attention over this wave's 100 tokens, 2 tokens per step (ILP)
  float acc[40];
#pragma unroll
  for (int d = 0; d < 40; ++d) acc[d] = 0.f;
  float mx = -1e30f, l = 0.f;
  const float scale = 0.15811388300841897f;  // 40^-0.5
  const int tbeg = h * 100;
#pragma unroll 1
  for (int t = tbeg; t < tbeg + 100; t += 2) {
    const float4* ka = (const float4*)(kbuf + t * 40);
    const float4* kb = (const float4*)(kbuf + t * 40 + 40);
    float a0 = 0.f, a1 = 0.f, b0 = 0.f, b1s = 0.f;
#pragma unroll
    for (int k = 0; k < 10; ++k) {
      float4 k4 = ka[k];
      float4 j4 = kb[k];
      a0 += q[4 * k] * k4.x + q[4 * k + 1] * k4.y;
      a1 += q[4 * k + 2] * k4.z + q[4 * k + 3] * k4.w;
      b0 += q[4 * k] * j4.x + q[4 * k + 1] * j4.y;
      b1s += q[4 * k + 2] * j4.z + q[4 * k + 3] * j4.w;
    }
    float sa = (a0 + a1) * scale;
    float sb = (b0 + b1s) * scale;
    // sequential online-softmax updates (dots above carried the ILP)
    {
      if (sa > mx) {
        float corr = __expf(mx - sa);
        l *= corr;
#pragma unroll
        for (int d = 0; d < 40; ++d) acc[d] *= corr;
        mx = sa;
      }
      float p = __expf(sa - mx);
      l += p;
      const float4* vr = (const float4*)(vbuf + t * 40);
#pragma unroll
      for (int k = 0; k < 10; ++k) {
        float4 v4 = vr[k];
        acc[4 * k] += p * v4.x; acc[4 * k + 1] += p * v4.y;
        acc[4 * k + 2] += p * v4.z; acc[4 * k + 3] += p * v4.w;
      }
    }
    {
      if (sb > mx) {
        float corr = __expf(mx - sb);
        l *= corr;
#pragma unroll
        for (int d = 0; d < 40; ++d) acc[d] *= corr;
        mx = sb;
      }
      float p = __expf(sb - mx);
      l += p;
      const float4* vr = (const float4*)(vbuf + (t + 1) * 40);
#pragma unroll
      for (int k = 0; k < 10; ++k) {
        float4 v4 = vr[k];
        acc[4 * k] += p * v4.x; acc[4 * k + 1] += p * v4.y;
        acc[4 * k + 2] += p * v4.z; acc[4 * k + 3] += p * v4.w;
      }
    }
  }

  // ---- 4-way merge: m/l first (colbuf rows 0-1), then acc columns ----
  {
    float* redm = colbuf;          // [256]
    float* redl = colbuf + 256;    // [256]
    redm[tid] = mx; redl[tid] = l;
  }
  __syncthreads();                                    // B1
  float a0c, a1c, a2c, a3c, linv;
  {
    float m1 = colbuf[p1], m2 = colbuf[p2], m3 = colbuf[p3];
    float l1 = colbuf[256 + p1], l2 = colbuf[256 + p2], l3 = colbuf[256 + p3];
    float nm = fmaxf(fmaxf(mx, m1), fmaxf(m2, m3));
    a0c = __expf(mx - nm); a1c = __expf(m1 - nm);
    a2c = __expf(m2 - nm); a3c = __expf(m3 - nm);
    float L = l * a0c + l1 * a1c + l2 * a2c + l3 * a3c;
    linv = 1.f / L;
  }
  __syncthreads();                                    // B2 (m/l region free)
#pragma unroll
  for (int d = 0; d < 40; ++d) colbuf[d * 256 + tid] = acc[d];
  __syncthreads();                                    // B3
  float lat[40];
#pragma unroll
  for (int d = 0; d < 40; ++d)
    lat[d] = (acc[d] * a0c + colbuf[d * 256 + p1] * a1c
            + colbuf[d * 256 + p2] * a2c + colbuf[d * 256 + p3] * a3c) * linv;
  __syncthreads();                                    // B4 (colbuf free)

  // ---- lat2 = lat @ ca_out_w^T + ob, d-range split by wave (10 each) ----
  float lath[10];
#pragma unroll
  for (int dd = 0; dd < 10; ++dd) {
    float v = lat[dd];
    v = (h == 1) ? lat[dd + 10] : v;
    v = (h == 2) ? lat[dd + 20] : v;
    v = (h == 3) ? lat[dd + 30] : v;
    lath[dd] = v;
  }
  float lp[40];
#pragma unroll
  for (int e = 0; e < 40; ++e) lp[e] = 0.f;
#pragma unroll 1
  for (int dd = 0; dd < 10; ++dd) {
    const float lv = lath[dd];
    const int d = h * 10 + dd;
#pragma unroll
    for (int e = 0; e < 40; ++e) lp[e] += lv * ow[e * 40 + d];
  }
#pragma unroll
  for (int e = 0; e < 40; ++e) colbuf[e * 256 + tid] = lp[e];
  __syncthreads();                                    // B5
  float lat2[40];
#pragma unroll
  for (int e = 0; e < 40; ++e)
    lat2[e] = ob[e] + lp[e] + colbuf[e * 256 + p1]
            + colbuf[e * 256 + p2] + colbuf[e * 256 + p3];
  __syncthreads();                                    // B6 (colbuf free)

  // ---- LN + FFN (e-range split by wave: 40 each) ----
  float hh[40];
  {
    float m = 0.f;
#pragma unroll
    for (int d = 0; d < 40; ++d) m += lat2[d];
    m *= (1.f / 40.f);
    float var = 0.f;
#pragma unroll
    for (int d = 0; d < 40; ++d) { float dv = lat2[d] - m; var += dv * dv; }
    float rstd = rsqrtf(var * (1.f / 40.f) + 1e-5f);
#pragma unroll
    for (int d = 0; d < 40; ++d) hh[d] = (lat2[d] - m) * rstd * flw[d] + flb[d];
  }
  float ff[40];
#pragma unroll
  for (int d = 0; d < 40; ++d) ff[d] = 0.f;
#pragma unroll 1
  for (int ee = 0; ee < 40; ++ee) {
    const int e = h * 40 + ee;
    const float* r1 = w1 + e * 40;
    const float* r2 = w1 + (160 + e) * 40;
    float s0 = 0.f, s1 = 0.f;
#pragma unroll
    for (int d = 0; d < 40; ++d) { s0 += hh[d] * r1[d]; s1 += hh[d] * r2[d]; }
    float x1 = s0 + b1[e];
    float g = s1 + b1[160 + e];
    float tv = x1 * (0.5f * g * (1.f + erff(g * 0.70710678118654752f)));
#pragma unroll
    for (int d = 0; d < 40; ++d) ff[d] += tv * w2[d * 160 + e];
  }
#pragma unroll
  for (int d = 0; d < 40; ++d) colbuf[d * 256 + tid] = ff[d];
  __syncthreads();                                    // B7
  float r = outb[0];
#pragma unroll
  for (int d = 0; d < 40; ++d) {
    float f = ff[d] + colbuf[d * 256 + p1] + colbuf[d * 256 + p2]
            + colbuf[d * 256 + p3] + b2[d];
    r += (lat2[d] + f) * outw[d];
  }
  if (h == 0) out[n] = r;
}

// ---- fallback query (R8, PE inside) for small ws ----
__global__ __launch_bounds__(256) void query_kernel_fb(
    const float* __restrict__ qry,
    const float* __restrict__ pe_w, const float* __restrict__ pe_b,
    const float* __restrict__ lnq_w, const float* __restrict__ lnq_b,
    const float* __restrict__ qw,
    const float* __restrict__ ow, const float* __restrict__ ob,
    const float* __restrict__ flw, const float* __restrict__ flb,
    const float* __restrict__ w1, const float* __restrict__ b1,
    const float* __restrict__ w2, const float* __restrict__ b2,
    const float* __restrict__ outw, const float* __restrict__ outb,
    const float* __restrict__ kbuf, const float* __restrict__ vbuf,
    float* __restrict__ out)
{
  const int tid = threadIdx.x;
  const int h = __builtin_amdgcn_readfirstlane((tid >> 6) & 1);
  const int pj = tid >> 7;
  const int lane = tid & 63;
  const int n = blockIdx.x * 128 + pj * 64 + lane;
  const int ptn = tid ^ 64;
  __shared__ float colbuf[40 * 256];
  __shared__ float redm[256], redl[256];

  const float qx = qry[n * 3 + 0], qy = qry[n * 3 + 1], qz = qry[n * 3 + 2];
  float qp[40];
#pragma unroll
  for (int d = 0; d < 40; ++d) qp[d] = 0.f;
#pragma unroll
  for (int jj = 0; jj < 4; ++jj) {
    const int j = h * 4 + jj;
    float f = 3.14159265358979323846f * (float)(1 << j);
    float sx, cx, sy, cy, sz, cz;
    __sincosf(qx * f, &sx, &cx);
    __sincosf(qy * f, &sy, &cy);
    __sincosf(qz * f, &sz, &cz);
#pragma unroll
    for (int d = 0; d < 40; ++d) {
      const float* r = pe_w + d * 51;
      qp[d] += sx * r[j] + sy * r[j + 8] + sz * r[j + 16]
             + cx * r[j + 24] + cy * r[j + 32] + cz * r[j + 40];
    }
  }
#pragma unroll
  for (int d = 0; d < 40; ++d) colbuf[d * 256 + tid] = qp[d];
  __syncthreads();
  float qe[40];
#pragma unroll
  for (int d = 0; d < 40; ++d) {
    const float* r = pe_w + d * 51;
    qe[d] = pe_b[d] + qp[d] + colbuf[d * 256 + ptn]
          + qx * r[48] + qy * r[49] + qz * r[50];
  }
  __syncthreads();
  float qn[40];
  {
    float m = 0.f;
#pragma unroll
    for (int d = 0; d < 40; ++d) m += qe[d];
    m *= (1.f / 40.f);
    float var = 0.f;
#pragma unroll
    for (int d = 0; d < 40; ++d) { float dv = qe[d] - m; var += dv * dv; }
    float rstd = rsqrtf(var * (1.f / 40.f) + 1e-5f);
#pragma unroll
    for (int d = 0; d < 40; ++d) qn[d] = (qe[d] - m) * rstd * lnq_w[d] + lnq_b[d];
  }
  float qnh[20];
#pragma unroll
  for (int dd = 0; dd < 20; ++dd) qnh[dd] = h ? qn[dd + 20] : qn[dd];
  float q[40];
#pragma unroll
  for (int e = 0; e < 40; ++e) q[e] = 0.f;
#pragma unroll 1
  for (int dd = 0; dd < 20; ++dd) {
    const float qv = qnh[dd];
    const int d = h * 20 + dd;
#pragma unroll
    for (int e = 0; e < 40; ++e) q[e] += qv * qw[e * 40 + d];
  }
#pragma unroll
  for (int e = 0; e < 40; ++e) colbuf[e * 256 + tid] = q[e];
  __syncthreads();
#pragma unroll
  for (int e = 0; e < 40; ++e) q[e] += colbuf[e * 256 + ptn];
  __syncthreads();

  float acc[40];
#pragma unroll
  for (int d = 0; d < 40; ++d) acc[d] = 0.f;
  float mx = -1e30f, l = 0.f;
  const float scale = 0.15811388300841897f;
  const int tbeg = h * 200, tend = tbeg + 200;
#pragma unroll 1
  for (int t = tbeg; t < tend; ++t) {
    const float4* kr = (const float4*)(kbuf + t * 40);
    float s0 = 0.f, s1 = 0.f, s2 = 0.f, s3 = 0.f;
#pragma unroll
    for (int k = 0; k < 10; ++k) {
      float4 k4 = kr[k];
      s0 += q[4 * k] * k4.x; s1 += q[4 * k + 1] * k4.y;
      s2 += q[4 * k + 2] * k4.z; s3 += q[4 * k + 3] * k4.w;
    }
    float s = ((s0 + s1) + (s2 + s3)) * scale;
    if (s > mx) {
      float corr = __expf(mx - s);
      l *= corr;
#pragma unroll
      for (int d = 0; d < 40; ++d) acc[d] *= corr;
      mx = s;
    }
    float p = __expf(s - mx);
    l += p;
    const float4* vr = (const float4*)(vbuf + t * 40);
#pragma unroll
    for (int k = 0; k < 10; ++k) {
      float4 v4 = vr[k];
      acc[4 * k] += p * v4.x; acc[4 * k + 1] += p * v4.y;
      acc[4 * k + 2] += p * v4.z; acc[4 * k + 3] += p * v4.w;
    }
  }
#pragma unroll
  for (int d = 0; d < 40; ++d) colbuf[d * 256 + tid] = acc[d];
  redm[tid] = mx; redl[tid] = l;
  __syncthreads();
  float lat[40];
  {
    float m2 = redm[ptn];
    float l2 = redl[ptn];
    float nm = fmaxf(mx, m2);
    float a = __expf(mx - nm), b = __expf(m2 - nm);
    float lm = l * a + l2 * b;
    float linv = 1.f / lm;
#pragma unroll
    for (int d = 0; d < 40; ++d)
      lat[d] = (acc[d] * a + colbuf[d * 256 + ptn] * b) * linv;
  }
  __syncthreads();
  float lath[20];
#pragma unroll
  for (int dd = 0; dd < 20; ++dd) lath[dd] = h ? lat[dd + 20] : lat[dd];
  float lp[40];
#pragma unroll
  for (int e = 0; e < 40; ++e) lp[e] = 0.f;
#pragma unroll 1
  for (int dd = 0; dd < 20; ++dd) {
    const float lv = lath[dd];
    const int d = h * 20 + dd;
#pragma unroll
    for (int e = 0; e < 40; ++e) lp[e] += lv * ow[e * 40 + d];
  }
#pragma unroll
  for (int e = 0; e < 40; ++e) colbuf[e * 256 + tid] = lp[e];
  __syncthreads();
  float lat2[40];
#pragma unroll
  for (int e = 0; e < 40; ++e) lat2[e] = ob[e] + lp[e] + colbuf[e * 256 + ptn];
  __syncthreads();
  float hh[40];
  {
    float m = 0.f;
#pragma unroll
    for (int d = 0; d < 40; ++d) m += lat2[d];
    m *= (1.f / 40.f);
    float var = 0.f;
#pragma unroll
    for (int d = 0; d < 40; ++d) { float dv = lat2[d] - m; var += dv * dv; }
    float rstd = rsqrtf(var * (1.f / 40.f) + 1e-5f);
#pragma unroll
    for (int d = 0; d < 40; ++d) hh[d] = (lat2[d] - m) * rstd * flw[d] + flb[d];
  }
  float ff[40];
#pragma unroll
  for (int d = 0; d < 40; ++d) ff[d] = 0.f;
#pragma unroll 1
  for (int ee = 0; ee < 80; ++ee) {
    const int e = h * 80 + ee;
    const float* r1 = w1 + e * 40;
    const float* r2 = w1 + (160 + e) * 40;
    float s0 = 0.f, s1 = 0.f;
#pragma unroll
    for (int d = 0; d < 40; ++d) { s0 += hh[d] * r1[d]; s1 += hh[d] * r2[d]; }
    float x1 = s0 + b1[e];
    float g = s1 + b1[160 + e];
    float tv = x1 * (0.5f * g * (1.f + erff(g * 0.70710678118654752f)));
#pragma unroll
    for (int d = 0; d < 40; ++d) ff[d] += tv * w2[d * 160 + e];
  }
#pragma unroll
  for (int d = 0; d < 40; ++d) colbuf[d * 256 + tid] = ff[d];
  __syncthreads();
  float r = outb[0];
#pragma unroll
  for (int d = 0; d < 40; ++d) {
    float f = ff[d] + colbuf[d * 256 + ptn] + b2[d];
    r += (lat2[d] + f) * outw[d];
  }
  if (h == 0) out[n] = r;
}

extern "C" void kernel_launch(void* const* d_in, const int* in_sizes, int n_in,
                              void* d_out, int out_size, void* d_ws, size_t ws_size,
                              hipStream_t stream) {
  const float* mash   = (const float*)d_in[0];
  const float* qry    = (const float*)d_in[1];
  const float* lnw    = (const float*)d_in[2];
  const float* linw   = (const float*)d_in[3];
  const float* lconvw = (const float*)d_in[4];
  const float* lconvb = (const float*)d_in[5];
  const float* lxpw   = (const float*)d_in[6];
  const float* ldtw   = (const float*)d_in[7];
  const float* ldtb   = (const float*)d_in[8];
  const float* lAlog  = (const float*)d_in[9];
  const float* lD     = (const float*)d_in[10];
  const float* loutw  = (const float*)d_in[11];
  const float* pew    = (const float*)d_in[12];
  const float* peb    = (const float*)d_in[13];
  const float* lnqw   = (const float*)d_in[14];
  const float* lnqb   = (const float*)d_in[15];
  const float* lncw   = (const float*)d_in[16];
  const float* lncb   = (const float*)d_in[17];
  const float* qw     = (const float*)d_in[18];
  const float* kvw    = (const float*)d_in[19];
  const float* oww    = (const float*)d_in[20];
  const float* owb    = (const float*)d_in[21];
  const float* flnw   = (const float*)d_in[22];
  const float* flnb   = (const float*)d_in[23];
  const float* w1     = (const float*)d_in[24];
  const float* b1     = (const float*)d_in[25];
  const float* w2     = (const float*)d_in[26];
  const float* b2     = (const float*)d_in[27];
  const float* outw   = (const float*)d_in[28];
  const float* outb   = (const float*)d_in[29];

  // ws layout (floats): xb0[16000] xb1[16000] k[16000] v[16000]
  //                     flags[4096 ints] qstore[40*65536]
  float* wsf = (float*)d_ws;
  float* xb0 = wsf;
  float* xb1 = wsf + 16000;
  float* kbuf = wsf + 32000;
  float* vbuf = wsf + 48000;
  int* flags = (int*)(wsf + 64000);
  float* qstore = wsf + 68096;
  const size_t needed = (size_t)68096 * 4 + (size_t)40 * 65536 * 4;
  const bool pre = ws_size >= needed;   // constant across calls -> capture-safe

  hipLaunchKernelGGL(init_flags, dim3(16), dim3(256), 0, stream, flags);
  // 256 layer blocks + (pre ? 205 PE blocks : 0); layer blocks dispatch first
  hipLaunchKernelGGL(mamba_pipe, dim3(pre ? 461 : 256), dim3(TPB1), 0, stream,
                     mash, lnw, linw, lconvw, lconvb, lxpw, ldtw, ldtb, lAlog,
                     lD, loutw, xb0, xb1, flags,
                     qry, pew, peb, lnqw, lnqb, qw, qstore);
  // layer 255 (odd) writes xb1
  hipLaunchKernelGGL(kv_kernel, dim3(400), dim3(64), 0, stream,
                     xb1, lncw, lncb, kvw, kbuf, vbuf);
  if (pre) {
    hipLaunchKernelGGL(query_fast, dim3(1024), dim3(256), 0, stream,
                       qstore, oww, owb, flnw, flnb,
                       w1, b1, w2, b2, outw, outb, kbuf, vbuf, (float*)d_out);
  } else {
    hipLaunchKernelGGL(query_kernel_fb, dim3(512), dim3(256), 0, stream,
                       qry, pew, peb, lnqw, lnqb, qw, oww, owb, flnw, flnb,
                       w1, b1, w2, b2, outw, outb, kbuf, vbuf, (float*)d_out);
  }
}

// Round 6
// 2500.935 us; speedup vs baseline: 1.8521x; 1.0709x over previous
//
#include <hip/hip_runtime.h>

// ---------------------------------------------------------------------------
// MashDecoderV2: 256-layer mamba stack (L=400, D=40) + 65536-query cross-attn
// decoder. f32 throughout (threshold 1.56e-2).
//
// Round-15: CH=4 with PREFETCHED acquire. Measured across R9/R13/R14:
// P(CH<=4) ~ 4.4us floor, independent of compute/barriers -> floor is two
// serialized MALL round trips (acquire load at Phase-A head; store drain at
// B-last) + poll. This round moves the acquire off the critical path:
//  - tail of iteration c: publish flag, then load chunk c+1 (80 thr x u64)
//    into registers; latency hides across the loop boundary.
//  - loop top: write regs -> xcur LDS (B0); Phase A reads LDS (broadcast).
//  - flag_prev pre-check issued before out_proj; poll usually hits cached
//    value (steady-state skew covers it).
//  - conv folded inline into Phase A with register history (R14 pattern,
//    4 tokens): conv phase/xhist deleted. 5 barriers/iter.
// T ~ 3.0-3.3us -> mamba ~ 255*(f+T) + 99*T ~ 1450-1600us (vs 1820 R9 best).
// 320-thread blocks (proven register regime). PE blocks + stage 2 unchanged.
// ---------------------------------------------------------------------------

#define CH 4
#define NCHUNK 100       // 400 / CH
#define TPB1 320

typedef unsigned long long u64;

__device__ __forceinline__ u64 pack2(float a, float b) {
  return ((u64)__float_as_uint(b) << 32) | (u64)__float_as_uint(a);
}
__device__ __forceinline__ float unplo(u64 a) {
  return __uint_as_float((unsigned)a);
}
__device__ __forceinline__ float unphi(u64 a) {
  return __uint_as_float((unsigned)(a >> 32));
}

__global__ void init_flags(int* __restrict__ flags) {
  int i = blockIdx.x * 256 + threadIdx.x;
  if (i < 256 * 16) flags[i] = 0;
}

__global__ __launch_bounds__(TPB1) void mamba_pipe(
    const float* __restrict__ mash,
    const float* __restrict__ g_norm_w,   // (256,40)
    const float* __restrict__ g_in_w,     // (256,160,40)
    const float* __restrict__ g_conv_w,   // (256,80,4)
    const float* __restrict__ g_conv_b,   // (256,80)
    const float* __restrict__ g_xp_w,     // (256,35,80)
    const float* __restrict__ g_dt_w,     // (256,80,3)
    const float* __restrict__ g_dt_b,     // (256,80)
    const float* __restrict__ g_alog,     // (256,80,16)
    const float* __restrict__ g_D,        // (256,80)
    const float* __restrict__ g_out_w,    // (256,40,80)
    float* __restrict__ xb0,
    float* __restrict__ xb1,
    int* __restrict__ flags,
    // PE-block inputs (blocks >= 256)
    const float* __restrict__ qry,
    const float* __restrict__ pe_w, const float* __restrict__ pe_b,
    const float* __restrict__ lnq_w, const float* __restrict__ lnq_b,
    const float* __restrict__ qw,
    float* __restrict__ qstore)           // q_t[e*65536 + n]
{
  const int tid = threadIdx.x;

  // ---------------- PE blocks: query preprocessing under mamba's shadow ----
  if (blockIdx.x >= 256) {
    const int n = (blockIdx.x - 256) * TPB1 + tid;
    if (n < 65536) {
      const float qx = qry[n * 3 + 0], qy = qry[n * 3 + 1], qz = qry[n * 3 + 2];
      float qe[40];
#pragma unroll
      for (int d = 0; d < 40; ++d) qe[d] = pe_b[d];
#pragma unroll 1
      for (int j = 0; j < 8; ++j) {
        float f = 3.14159265358979323846f * (float)(1 << j);
        float sx, cx, sy, cy, sz, cz;
        __sincosf(qx * f, &sx, &cx);
        __sincosf(qy * f, &sy, &cy);
        __sincosf(qz * f, &sz, &cz);
#pragma unroll
        for (int d = 0; d < 40; ++d) {
          const float* r = pe_w + d * 51;
          qe[d] += sx * r[j] + sy * r[j + 8] + sz * r[j + 16]
                 + cx * r[j + 24] + cy * r[j + 32] + cz * r[j + 40];
        }
      }
#pragma unroll
      for (int d = 0; d < 40; ++d) {
        const float* r = pe_w + d * 51;
        qe[d] += qx * r[48] + qy * r[49] + qz * r[50];
      }
      // LN -> qn (registers)
      float qn[40];
      {
        float m = 0.f;
#pragma unroll
        for (int d = 0; d < 40; ++d) m += qe[d];
        m *= (1.f / 40.f);
        float var = 0.f;
#pragma unroll
        for (int d = 0; d < 40; ++d) { float dv = qe[d] - m; var += dv * dv; }
        float rstd = rsqrtf(var * (1.f / 40.f) + 1e-5f);
#pragma unroll
        for (int d = 0; d < 40; ++d)
          qn[d] = (qe[d] - m) * rstd * lnq_w[d] + lnq_b[d];
      }
      // q-proj, fully unrolled (constant reg indices; qw scalar loads)
      float q[40];
#pragma unroll
      for (int e = 0; e < 40; ++e) {
        const float* r = qw + e * 40;
        float s = 0.f;
#pragma unroll
        for (int d = 0; d < 40; ++d) s += qn[d] * r[d];
        q[e] = s;
      }
#pragma unroll
      for (int e = 0; e < 40; ++e) qstore[e * 65536 + n] = q[e];
    }
    return;
  }

  // ---------------- layer blocks: CH=4, prefetch pipeline ------------------
  const int layer = blockIdx.x;

  __shared__ __align__(16) float xcur[2][160];  // raw input (4 tok x 40)
  __shared__ float xs[4][80];       // conv+silu output
  __shared__ float zb[4][80];       // z gate
  __shared__ float dbc[4][36];      // x_proj output (35 + pad)
  __shared__ float yb[4][80];       // scan output (gated)

  // role A (tid<160): in_proj column e=tid for ALL 4 tokens; e<80 conv inline
  float w_in_r[40];                 // in_proj row with rmsnorm weight folded
  if (tid < 160) {
    const float4* g = (const float4*)(g_in_w + layer * 6400 + tid * 40);
    const float4* nw = (const float4*)(g_norm_w + layer * 40);
#pragma unroll
    for (int k = 0; k < 10; ++k) {
      float4 v = g[k];
      float4 n = nw[k];
      w_in_r[4 * k] = v.x * n.x; w_in_r[4 * k + 1] = v.y * n.y;
      w_in_r[4 * k + 2] = v.z * n.z; w_in_r[4 * k + 3] = v.w * n.w;
    }
  }
  float cw0, cw1, cw2, cw3, cb;
  float h0 = 0.f, h1 = 0.f, h2 = 0.f;   // conv history: tokens t0-3,t0-2,t0-1
  if (tid < 80) {
    float4 v = *(const float4*)(g_conv_w + layer * 320 + tid * 4);
    cw0 = v.x; cw1 = v.y; cw2 = v.z; cw3 = v.w;
    cb = g_conv_b[layer * 80 + tid];
  }
  const int halfp = tid & 1;
  const int p_x = tid >> 1;              // <140 active for x_proj
  const int t_x = p_x / 35, e_x = p_x % 35;
  float w_xp_r[40];
  if (p_x < 140) {
    const float4* g = (const float4*)(g_xp_w + layer * 2800 + e_x * 80 + halfp * 40);
#pragma unroll
    for (int k = 0; k < 10; ++k) {
      float4 v = g[k];
      w_xp_r[4 * k] = v.x; w_xp_r[4 * k + 1] = v.y;
      w_xp_r[4 * k + 2] = v.z; w_xp_r[4 * k + 3] = v.w;
    }
  }
  const int d_ch = tid >> 2;
  const int qq = tid & 3;
  float negA[4], hst[4];
  {
    float4 v = *(const float4*)(g_alog + layer * 1280 + tid * 4);
    negA[0] = -__expf(v.x); negA[1] = -__expf(v.y);
    negA[2] = -__expf(v.z); negA[3] = -__expf(v.w);
    hst[0] = hst[1] = hst[2] = hst[3] = 0.f;
  }
  const float dtw0 = g_dt_w[layer * 240 + d_ch * 3 + 0];
  const float dtw1 = g_dt_w[layer * 240 + d_ch * 3 + 1];
  const float dtw2 = g_dt_w[layer * 240 + d_ch * 3 + 2];
  const float dtb = g_dt_b[layer * 80 + d_ch];
  const float wD = g_D[layer * 80 + d_ch];
  const int p_o = tid >> 1;              // 0..159: token t_o, dim e_o
  const int t_o = p_o / 40, e_o = p_o % 40;
  float w_out_r[40];
  {
    const float4* g = (const float4*)(g_out_w + layer * 3200 + e_o * 80 + halfp * 40);
#pragma unroll
    for (int k = 0; k < 10; ++k) {
      float4 v = g[k];
      w_out_r[4 * k] = v.x; w_out_r[4 * k + 1] = v.y;
      w_out_r[4 * k + 2] = v.z; w_out_r[4 * k + 3] = v.w;
    }
  }

  const float* src = (layer == 0) ? mash : ((layer & 1) ? xb0 : xb1);
  float* dst = (layer & 1) ? xb1 : xb0;
  int* flag_prev = flags + (layer - 1) * 16;
  int* flag_cur = flags + layer * 16;

  // ---- prologue: acquire chunk 0 into pf registers ----
  u64 pf = 0;
  if (layer > 0) {
    while (__hip_atomic_load(flag_prev, __ATOMIC_RELAXED,
                             __HIP_MEMORY_SCOPE_AGENT) < 1)
      __builtin_amdgcn_s_sleep(1);
  }
  if (tid < 80)
    pf = __hip_atomic_load((const u64*)src + tid, __ATOMIC_RELAXED,
                           __HIP_MEMORY_SCOPE_AGENT);

  for (int c = 0; c < NCHUNK; ++c) {
    const int t0 = c * CH;
    const int cbi = c & 1;

    // ---- deliver prefetched input to LDS ----
    if (tid < 80) {
      xcur[cbi][2 * tid] = unplo(pf);
      xcur[cbi][2 * tid + 1] = unphi(pf);
    }
    __syncthreads();                                   // B0: xcur ready

    // ---- Phase A: in_proj (4 tokens, LDS broadcast) + inline conv + silu --
    if (tid < 160) {
      float xzv[4];
#pragma unroll
      for (int t = 0; t < 4; ++t) {
        const float4* xp = (const float4*)&xcur[cbi][t * 40];
        float ss = 0.f, sd = 0.f;
#pragma unroll
        for (int k = 0; k < 10; ++k) {
          float4 v = xp[k];
          ss += v.x * v.x + v.y * v.y + v.z * v.z + v.w * v.w;
          sd += w_in_r[4 * k] * v.x + w_in_r[4 * k + 1] * v.y
              + w_in_r[4 * k + 2] * v.z + w_in_r[4 * k + 3] * v.w;
        }
        xzv[t] = sd * rsqrtf(ss * (1.f / 40.f) + 1e-5f);
      }
      if (tid < 80) {
        // depthwise conv(4), history in registers
        float c0 = cb + cw0 * h0 + cw1 * h1 + cw2 * h2 + cw3 * xzv[0];
        float c1 = cb + cw0 * h1 + cw1 * h2 + cw2 * xzv[0] + cw3 * xzv[1];
        float c2 = cb + cw0 * h2 + cw1 * xzv[0] + cw2 * xzv[1] + cw3 * xzv[2];
        float c3 = cb + cw0 * xzv[0] + cw1 * xzv[1] + cw2 * xzv[2] + cw3 * xzv[3];
        xs[0][tid] = c0 / (1.f + __expf(-c0));
        xs[1][tid] = c1 / (1.f + __expf(-c1));
        xs[2][tid] = c2 / (1.f + __expf(-c2));
        xs[3][tid] = c3 / (1.f + __expf(-c3));
        h0 = xzv[1]; h1 = xzv[2]; h2 = xzv[3];
      } else {
        zb[0][tid - 80] = xzv[0];
        zb[1][tid - 80] = xzv[1];
        zb[2][tid - 80] = xzv[2];
        zb[3][tid - 80] = xzv[3];
      }
    }
    __syncthreads();                                   // B1: xs, zb ready

    // ---- x_proj: pair half-dots + shfl merge (4 tokens x 35 outputs) ----
    if (p_x < 140) {
      const float4* xp = (const float4*)&xs[t_x][halfp * 40];
      float s = 0.f;
#pragma unroll
      for (int k = 0; k < 10; ++k) {
        float4 v = xp[k];
        s += w_xp_r[4 * k] * v.x + w_xp_r[4 * k + 1] * v.y
           + w_xp_r[4 * k + 2] * v.z + w_xp_r[4 * k + 3] * v.w;
      }
      s += __shfl_xor(s, 1);
      if (halfp == 0) dbc[t_x][e_x] = s;
    }
    __syncthreads();                                   // B2: dbc ready

    // ---- selective scan; dt inline; state in regs; 4 steps ----
#pragma unroll
    for (int t = 0; t < CH; ++t) {
      const float* db = &dbc[t][0];
      float sdt = dtb + db[0] * dtw0 + db[1] * dtw1 + db[2] * dtw2;
      float dtval = (sdt > 15.f) ? sdt : __logf(1.f + __expf(sdt));
      float xval = xs[t][d_ch];
      float part = 0.f;
#pragma unroll
      for (int j = 0; j < 4; ++j) {
        int s_i = qq * 4 + j;
        float Bv = db[3 + s_i];
        float Cv = db[19 + s_i];
        hst[j] = __expf(dtval * negA[j]) * hst[j] + dtval * Bv * xval;
        part += hst[j] * Cv;
      }
      part += __shfl_xor(part, 1);
      part += __shfl_xor(part, 2);
      if (qq == 0) {
        float yv = part + xval * wD;
        float z = zb[t][d_ch];
        yb[t][d_ch] = yv * z / (1.f + __expf(-z));
      }
    }
    __syncthreads();                                   // B3: yb ready

    // ---- early flag check (latency hides under out_proj + B4 drain) ----
    int fv = 0;
    const bool needpoll = (layer > 0) && (c + 1 < NCHUNK);
    if (needpoll)
      fv = __hip_atomic_load(flag_prev, __ATOMIC_RELAXED,
                             __HIP_MEMORY_SCOPE_AGENT);

    // ---- out_proj + residual -> paired dwordx2 coherent stores ----
    {
      const float4* yp = (const float4*)&yb[t_o][halfp * 40];
      float s = 0.f;
#pragma unroll
      for (int k = 0; k < 10; ++k) {
        float4 v = yp[k];
        s += w_out_r[4 * k] * v.x + w_out_r[4 * k + 1] * v.y
           + w_out_r[4 * k + 2] * v.z + w_out_r[4 * k + 3] * v.w;
      }
      s += __shfl_xor(s, 1);
      float r = xcur[cbi][p_o] + s;    // valid on pair leaders (halfp==0)
      float r2 = __shfl_xor(r, 2);     // leader tid+2's value (p_o+1)
      if ((tid & 3) == 0)              // even p_o leaders store the pair
        __hip_atomic_store((u64*)(dst + t0 * 40 + p_o), pack2(r, r2),
                           __ATOMIC_RELAXED, __HIP_MEMORY_SCOPE_AGENT);
    }
    __syncthreads();        // B4: drains vmcnt -> all stores acked at IF$
    if (tid == 0)
      __hip_atomic_store(flag_cur, c + 1, __ATOMIC_RELAXED,
                         __HIP_MEMORY_SCOPE_AGENT);

    // ---- prefetch chunk c+1 (latency hides across loop boundary) ----
    if (c + 1 < NCHUNK) {
      if (needpoll && fv <= c + 1) {
        while (__hip_atomic_load(flag_prev, __ATOMIC_RELAXED,
                                 __HIP_MEMORY_SCOPE_AGENT) <= c + 1)
          __builtin_amdgcn_s_sleep(1);
      }
      if (tid < 80)
        pf = __hip_atomic_load((const u64*)(src + (t0 + CH) * 40) + tid,
                               __ATOMIC_RELAXED, __HIP_MEMORY_SCOPE_AGENT);
    }
  }
}

// ---- context side of cross-attn: cn = LN(x_final), kv = cn @ ca_kv_w^T ----
__global__ __launch_bounds__(64) void kv_kernel(
    const float* __restrict__ xfin,
    const float* __restrict__ lnc_w, const float* __restrict__ lnc_b,
    const float* __restrict__ kv_w,
    float* __restrict__ kbuf, float* __restrict__ vbuf)
{
  int t = blockIdx.x;
  int lane = threadIdx.x;
  float x = (lane < 40) ? xfin[t * 40 + lane] : 0.f;
  float s = x;
#pragma unroll
  for (int o = 32; o >= 1; o >>= 1) s += __shfl_xor(s, o);
  float m = s * (1.f / 40.f);
  float dv = (lane < 40) ? (x - m) : 0.f;
  float v2 = dv * dv;
#pragma unroll
  for (int o = 32; o >= 1; o >>= 1) v2 += __shfl_xor(v2, o);
  float rstd = rsqrtf(v2 * (1.f / 40.f) + 1e-5f);
  __shared__ float cn[40];
  if (lane < 40) cn[lane] = dv * rstd * lnc_w[lane] + lnc_b[lane];
  __syncthreads();
  for (int e = lane; e < 80; e += 64) {
    float acc = 0.f;
#pragma unroll
    for (int d = 0; d < 40; ++d) acc += cn[d] * kv_w[e * 40 + d];
    if (e < 40) kbuf[t * 40 + e] = acc;
    else vbuf[t * 40 + (e - 40)] = acc;
  }
}

// ---- fast query decode: precomputed q, 4-way token split per query ----
__global__ __launch_bounds__(256) void query_fast(
    const float* __restrict__ qstore,    // q_t[e*65536 + n]
    const float* __restrict__ ow, const float* __restrict__ ob,
    const float* __restrict__ flw, const float* __restrict__ flb,
    const float* __restrict__ w1, const float* __restrict__ b1,
    const float* __restrict__ w2, const float* __restrict__ b2,
    const float* __restrict__ outw, const float* __restrict__ outb,
    const float* __restrict__ kbuf, const float* __restrict__ vbuf,
    float* __restrict__ out)
{
  const int tid = threadIdx.x;
  const int h = __builtin_amdgcn_readfirstlane((tid >> 6) & 3);  // wave 0..3
  const int lane = tid & 63;
  const int n = blockIdx.x * 64 + lane;
  const int p1 = tid ^ 64, p2 = tid ^ 128, p3 = tid ^ 192;
  __shared__ float colbuf[40 * 256];     // 40KB: merge staging (reused)

  // load precomputed q (coalesced per e-plane)
  float q[40];
#pragma unroll
  for (int e = 0; e < 40; ++e) q[e] = qstore[e * 65536 + n];

  // flash attention over this wave's 100 tokens, 2 tokens per step (ILP)
  float acc[40];
#pragma unroll
  for (int d = 0; d < 40; ++d) acc[d] = 0.f;
  float mx = -1e30f, l = 0.f;
  const float scale = 0.15811388300841897f;  // 40^-0.5
  const int tbeg = h * 100;
#pragma unroll 1
  for (int t = tbeg; t < tbeg + 100; t += 2) {
    const float4* ka = (const float4*)(kbuf + t * 40);
    const float4* kb = (const float4*)(kbuf + t * 40 + 40);
    float a0 = 0.f, a1 = 0.f, b0 = 0.f, b1s = 0.f;
#pragma unroll
    for (int k = 0; k < 10; ++k) {
      float4 k4 = ka[k];
      float4 j4 = kb[k];
      a0 += q[4 * k] * k4.x + q[4 * k + 1] * k4.y;
      a1 += q[4 * k + 2] * k4.z + q[4 * k + 3] * k4.w;
      b0 += q[4 * k] * j4.x + q[4 * k + 1] * j4.y;
      b1s += q[4 * k + 2] * j4.z + q[4 * k + 3] * j4.w;
    }
    float sa = (a0 + a1) * scale;
    float sb = (b0 + b1s) * scale;
    // sequential online-softmax updates (dots above carried the ILP)
    {
      if (sa > mx) {
        float corr = __expf(mx - sa);
        l *= corr;
#pragma unroll
        for (int d = 0; d < 40; ++d) acc[d] *= corr;
        mx = sa;
      }
      float p = __expf(sa - mx);
      l += p;
      const float4* vr = (const float4*)(vbuf + t * 40);
#pragma unroll
      for (int k = 0; k < 10; ++k) {
        float4 v4 = vr[k];
        acc[4 * k] += p * v4.x; acc[4 * k + 1] += p * v4.y;
        acc[4 * k + 2] += p * v4.z; acc[4 * k + 3] += p * v4.w;
      }
    }
    {
      if (sb > mx) {
        float corr = __expf(mx - sb);
        l *= corr;
#pragma unroll
        for (int d = 0; d < 40; ++d) acc[d] *= corr;
        mx = sb;
      }
      float p = __expf(sb - mx);
      l += p;
      const float4* vr = (const float4*)(vbuf + (t + 1) * 40);
#pragma unroll
      for (int k = 0; k < 10; ++k) {
        float4 v4 = vr[k];
        acc[4 * k] += p * v4.x; acc[4 * k + 1] += p * v4.y;
        acc[4 * k + 2] += p * v4.z; acc[4 * k + 3] += p * v4.w;
      }
    }
  }

  // ---- 4-way merge: m/l first (colbuf rows 0-1), then acc columns ----
  {
    float* redm = colbuf;          // [256]
    float* redl = colbuf + 256;    // [256]
    redm[tid] = mx; redl[tid] = l;
  }
  __syncthreads();                                    // B1
  float a0c, a1c, a2c, a3c, linv;
  {
    float m1 = colbuf[p1], m2 = colbuf[p2], m3 = colbuf[p3];
    float l1 = colbuf[256 + p1], l2 = colbuf[256 + p2], l3 = colbuf[256 + p3];
    float nm = fmaxf(fmaxf(mx, m1), fmaxf(m2, m3));
    a0c = __expf(mx - nm); a1c = __expf(m1 - nm);
    a2c = __expf(m2 - nm); a3c = __expf(m3 - nm);
    float L = l * a0c + l1 * a1c + l2 * a2c + l3 * a3c;
    linv = 1.f / L;
  }
  __syncthreads();                                    // B2 (m/l region free)
#pragma unroll
  for (int d = 0; d < 40; ++d) colbuf[d * 256 + tid] = acc[d];
  __syncthreads();                                    // B3
  float lat[40];
#pragma unroll
  for (int d = 0; d < 40; ++d)
    lat[d] = (acc[d] * a0c + colbuf[d * 256 + p1] * a1c
            + colbuf[d * 256 + p2] * a2c + colbuf[d * 256 + p3] * a3c) * linv;
  __syncthreads();                                    // B4 (colbuf free)

  // ---- lat2 = lat @ ca_out_w^T + ob, d-range split by wave (10 each) ----
  float lath[10];
#pragma unroll
  for (int dd = 0; dd < 10; ++dd) {
    float v = lat[dd];
    v = (h == 1) ? lat[dd + 10] : v;
    v = (h == 2) ? lat[dd + 20] : v;
    v = (h == 3) ? lat[dd + 30] : v;
    lath[dd] = v;
  }
  float lp[40];
#pragma unroll
  for (int e = 0; e < 40; ++e) lp[e] = 0.f;
#pragma unroll 1
  for (int dd = 0; dd < 10; ++dd) {
    const float lv = lath[dd];
    const int d = h * 10 + dd;
#pragma unroll
    for (int e = 0; e < 40; ++e) lp[e] += lv * ow[e * 40 + d];
  }
#pragma unroll
  for (int e = 0; e < 40; ++e) colbuf[e * 256 + tid] = lp[e];
  __syncthreads();                                    // B5
  float lat2[40];
#pragma unroll
  for (int e = 0; e < 40; ++e)
    lat2[e] = ob[e] + lp[e] + colbuf[e * 256 + p1]
            + colbuf[e * 256 + p2] + colbuf[e * 256 + p3];
  __syncthreads();                                    // B6 (colbuf free)

  // ---- LN + FFN (e-range split by wave: 40 each) ----
  float hh[40];
  {
    float m = 0.f;
#pragma unroll
    for (int d = 0; d < 40; ++d) m += lat2[d];
    m *= (1.f / 40.f);
    float var = 0.f;
#pragma unroll
    for (int d = 0; d < 40; ++d) { float dv = lat2[d] - m; var += dv * dv; }
    float rstd = rsqrtf(var * (1.f / 40.f) + 1e-5f);
#pragma unroll
    for (int d = 0; d < 40; ++d) hh[d] = (lat2[d] - m) * rstd * flw[d] + flb[d];
  }
  float ff[40];
#pragma unroll
  for (int d = 0; d < 40; ++d) ff[d] = 0.f;
#pragma unroll 1
  for (int ee = 0; ee < 40; ++ee) {
    const int e = h * 40 + ee;
    const float* r1 = w1 + e * 40;
    const float* r2 = w1 + (160 + e) * 40;
    float s0 = 0.f, s1 = 0.f;
#pragma unroll
    for (int d = 0; d < 40; ++d) { s0 += hh[d] * r1[d]; s1 += hh[d] * r2[d]; }
    float x1 = s0 + b1[e];
    float g = s1 + b1[160 + e];
    float tv = x1 * (0.5f * g * (1.f + erff(g * 0.70710678118654752f)));
#pragma unroll
    for (int d = 0; d < 40; ++d) ff[d] += tv * w2[d * 160 + e];
  }
#pragma unroll
  for (int d = 0; d < 40; ++d) colbuf[d * 256 + tid] = ff[d];
  __syncthreads();                                    // B7
  float r = outb[0];
#pragma unroll
  for (int d = 0; d < 40; ++d) {
    float f = ff[d] + colbuf[d * 256 + p1] + colbuf[d * 256 + p2]
            + colbuf[d * 256 + p3] + b2[d];
    r += (lat2[d] + f) * outw[d];
  }
  if (h == 0) out[n] = r;
}

// ---- fallback query (R8, PE inside) for small ws ----
__global__ __launch_bounds__(256) void query_kernel_fb(
    const float* __restrict__ qry,
    const float* __restrict__ pe_w, const float* __restrict__ pe_b,
    const float* __restrict__ lnq_w, const float* __restrict__ lnq_b,
    const float* __restrict__ qw,
    const float* __restrict__ ow, const float* __restrict__ ob,
    const float* __restrict__ flw, const float* __restrict__ flb,
    const float* __restrict__ w1, const float* __restrict__ b1,
    const float* __restrict__ w2, const float* __restrict__ b2,
    const float* __restrict__ outw, const float* __restrict__ outb,
    const float* __restrict__ kbuf, const float* __restrict__ vbuf,
    float* __restrict__ out)
{
  const int tid = threadIdx.x;
  const int h = __builtin_amdgcn_readfirstlane((tid >> 6) & 1);
  const int pj = tid >> 7;
  const int lane = tid & 63;
  const int n = blockIdx.x * 128 + pj * 64 + lane;
  const int ptn = tid ^ 64;
  __shared__ float colbuf[40 * 256];
  __shared__ float redm[256], redl[256];

  const float qx = qry[n * 3 + 0], qy = qry[n * 3 + 1], qz = qry[n * 3 + 2];
  float qp[40];
#pragma unroll
  for (int d = 0; d < 40; ++d) qp[d] = 0.f;
#pragma unroll
  for (int jj = 0; jj < 4; ++jj) {
    const int j = h * 4 + jj;
    float f = 3.14159265358979323846f * (float)(1 << j);
    float sx, cx, sy, cy, sz, cz;
    __sincosf(qx * f, &sx, &cx);
    __sincosf(qy * f, &sy, &cy);
    __sincosf(qz * f, &sz, &cz);
#pragma unroll
    for (int d = 0; d < 40; ++d) {
      const float* r = pe_w + d * 51;
      qp[d] += sx * r[j] + sy * r[j + 8] + sz * r[j + 16]
             + cx * r[j + 24] + cy * r[j + 32] + cz * r[j + 40];
    }
  }
#pragma unroll
  for (int d = 0; d < 40; ++d) colbuf[d * 256 + tid] = qp[d];
  __syncthreads();
  float qe[40];
#pragma unroll
  for (int d = 0; d < 40; ++d) {
    const float* r = pe_w + d * 51;
    qe[d] = pe_b[d] + qp[d] + colbuf[d * 256 + ptn]
          + qx * r[48] + qy * r[49] + qz * r[50];
  }
  __syncthreads();
  float qn[40];
  {
    float m = 0.f;
#pragma unroll
    for (int d = 0; d < 40; ++d) m += qe[d];
    m *= (1.f / 40.f);
    float var = 0.f;
#pragma unroll
    for (int d = 0; d < 40; ++d) { float dv = qe[d] - m; var += dv * dv; }
    float rstd = rsqrtf(var * (1.f / 40.f) + 1e-5f);
#pragma unroll
    for (int d = 0; d < 40; ++d) qn[d] = (qe[d] - m) * rstd * lnq_w[d] + lnq_b[d];
  }
  float qnh[20];
#pragma unroll
  for (int dd = 0; dd < 20; ++dd) qnh[dd] = h ? qn[dd + 20] : qn[dd];
  float q[40];
#pragma unroll
  for (int e = 0; e < 40; ++e) q[e] = 0.f;
#pragma unroll 1
  for (int dd = 0; dd < 20; ++dd) {
    const float qv = qnh[dd];
    const int d = h * 20 + dd;
#pragma unroll
    for (int e = 0; e < 40; ++e) q[e] += qv * qw[e * 40 + d];
  }
#pragma unroll
  for (int e = 0; e < 40; ++e) colbuf[e * 256 + tid] = q[e];
  __syncthreads();
#pragma unroll
  for (int e = 0; e < 40; ++e) q[e] += colbuf[e * 256 + ptn];
  __syncthreads();

  float acc[40];
#pragma unroll
  for (int d = 0; d < 40; ++d) acc[d] = 0.f;
  float mx = -1e30f, l = 0.f;
  const float scale = 0.15811388300841897f;
  const int tbeg = h * 200, tend = tbeg + 200;
#pragma unroll 1
  for (int t = tbeg; t < tend; ++t) {
    const float4* kr = (const float4*)(kbuf + t * 40);
    float s0 = 0.f, s1 = 0.f, s2 = 0.f, s3 = 0.f;
#pragma unroll
    for (int k = 0; k < 10; ++k) {
      float4 k4 = kr[k];
      s0 += q[4 * k] * k4.x; s1 += q[4 * k + 1] * k4.y;
      s2 += q[4 * k + 2] * k4.z; s3 += q[4 * k + 3] * k4.w;
    }
    float s = ((s0 + s1) + (s2 + s3)) * scale;
    if (s > mx) {
      float corr = __expf(mx - s);
      l *= corr;
#pragma unroll
      for (int d = 0; d < 40; ++d) acc[d] *= corr;
      mx = s;
    }
    float p = __expf(s - mx);
    l += p;
    const float4* vr = (const float4*)(vbuf + t * 40);
#pragma unroll
    for (int k = 0; k < 10; ++k) {
      float4 v4 = vr[k];
      acc[4 * k] += p * v4.x; acc[4 * k + 1] += p * v4.y;
      acc[4 * k + 2] += p * v4.z; acc[4 * k + 3] += p * v4.w;
    }
  }
#pragma unroll
  for (int d = 0; d < 40; ++d) colbuf[d * 256 + tid] = acc[d];
  redm[tid] = mx; redl[tid] = l;
  __syncthreads();
  float lat[40];
  {
    float m2 = redm[ptn];
    float l2 = redl[ptn];
    float nm = fmaxf(mx, m2);
    float a = __expf(mx - nm), b = __expf(m2 - nm);
    float lm = l * a + l2 * b;
    float linv = 1.f / lm;
#pragma unroll
    for (int d = 0; d < 40; ++d)
      lat[d] = (acc[d] * a + colbuf[d * 256 + ptn] * b) * linv;
  }
  __syncthreads();
  float lath[20];
#pragma unroll
  for (int dd = 0; dd < 20; ++dd) lath[dd] = h ? lat[dd + 20] : lat[dd];
  float lp[40];
#pragma unroll
  for (int e = 0; e < 40; ++e) lp[e] = 0.f;
#pragma unroll 1
  for (int dd = 0; dd < 20; ++dd) {
    const float lv = lath[dd];
    const int d = h * 20 + dd;
#pragma unroll
    for (int e = 0; e < 40; ++e) lp[e] += lv * ow[e * 40 + d];
  }
#pragma unroll
  for (int e = 0; e < 40; ++e) colbuf[e * 256 + tid] = lp[e];
  __syncthreads();
  float lat2[40];
#pragma unroll
  for (int e = 0; e < 40; ++e) lat2[e] = ob[e] + lp[e] + colbuf[e * 256 + ptn];
  __syncthreads();
  float hh[40];
  {
    float m = 0.f;
#pragma unroll
    for (int d = 0; d < 40; ++d) m += lat2[d];
    m *= (1.f / 40.f);
    float var = 0.f;
#pragma unroll
    for (int d = 0; d < 40; ++d) { float dv = lat2[d] - m; var += dv * dv; }
    float rstd = rsqrtf(var * (1.f / 40.f) + 1e-5f);
#pragma unroll
    for (int d = 0; d < 40; ++d) hh[d] = (lat2[d] - m) * rstd * flw[d] + flb[d];
  }
  float ff[40];
#pragma unroll
  for (int d = 0; d < 40; ++d) ff[d] = 0.f;
#pragma unroll 1
  for (int ee = 0; ee < 80; ++ee) {
    const int e = h * 80 + ee;
    const float* r1 = w1 + e * 40;
    const float* r2 = w1 + (160 + e) * 40;
    float s0 = 0.f, s1 = 0.f;
#pragma unroll
    for (int d = 0; d < 40; ++d) { s0 += hh[d] * r1[d]; s1 += hh[d] * r2[d]; }
    float x1 = s0 + b1[e];
    float g = s1 + b1[160 + e];
    float tv = x1 * (0.5f * g * (1.f + erff(g * 0.70710678118654752f)));
#pragma unroll
    for (int d = 0; d < 40; ++d) ff[d] += tv * w2[d * 160 + e];
  }
#pragma unroll
  for (int d = 0; d < 40; ++d) colbuf[d * 256 + tid] = ff[d];
  __syncthreads();
  float r = outb[0];
#pragma unroll
  for (int d = 0; d < 40; ++d) {
    float f = ff[d] + colbuf[d * 256 + ptn] + b2[d];
    r += (lat2[d] + f) * outw[d];
  }
  if (h == 0) out[n] = r;
}

extern "C" void kernel_launch(void* const* d_in, const int* in_sizes, int n_in,
                              void* d_out, int out_size, void* d_ws, size_t ws_size,
                              hipStream_t stream) {
  const float* mash   = (const float*)d_in[0];
  const float* qry    = (const float*)d_in[1];
  const float* lnw    = (const float*)d_in[2];
  const float* linw   = (const float*)d_in[3];
  const float* lconvw = (const float*)d_in[4];
  const float* lconvb = (const float*)d_in[5];
  const float* lxpw   = (const float*)d_in[6];
  const float* ldtw   = (const float*)d_in[7];
  const float* ldtb   = (const float*)d_in[8];
  const float* lAlog  = (const float*)d_in[9];
  const float* lD     = (const float*)d_in[10];
  const float* loutw  = (const float*)d_in[11];
  const float* pew    = (const float*)d_in[12];
  const float* peb    = (const float*)d_in[13];
  const float* lnqw   = (const float*)d_in[14];
  const float* lnqb   = (const float*)d_in[15];
  const float* lncw   = (const float*)d_in[16];
  const float* lncb   = (const float*)d_in[17];
  const float* qw     = (const float*)d_in[18];
  const float* kvw    = (const float*)d_in[19];
  const float* oww    = (const float*)d_in[20];
  const float* owb    = (const float*)d_in[21];
  const float* flnw   = (const float*)d_in[22];
  const float* flnb   = (const float*)d_in[23];
  const float* w1     = (const float*)d_in[24];
  const float* b1     = (const float*)d_in[25];
  const float* w2     = (const float*)d_in[26];
  const float* b2     = (const float*)d_in[27];
  const float* outw   = (const float*)d_in[28];
  const float* outb   = (const float*)d_in[29];

  // ws layout (floats): xb0[16000] xb1[16000] k[16000] v[16000]
  //                     flags[4096 ints] qstore[40*65536]
  float* wsf = (float*)d_ws;
  float* xb0 = wsf;
  float* xb1 = wsf + 16000;
  float* kbuf = wsf + 32000;
  float* vbuf = wsf + 48000;
  int* flags = (int*)(wsf + 64000);
  float* qstore = wsf + 68096;
  const size_t needed = (size_t)68096 * 4 + (size_t)40 * 65536 * 4;
  const bool pre = ws_size >= needed;   // constant across calls -> capture-safe

  hipLaunchKernelGGL(init_flags, dim3(16), dim3(256), 0, stream, flags);
  // 256 layer blocks + (pre ? 205 PE blocks : 0); layer blocks dispatch first
  hipLaunchKernelGGL(mamba_pipe, dim3(pre ? 461 : 256), dim3(TPB1), 0, stream,
                     mash, lnw, linw, lconvw, lconvb, lxpw, ldtw, ldtb, lAlog,
                     lD, loutw, xb0, xb1, flags,
                     qry, pew, peb, lnqw, lnqb, qw, qstore);
  // layer 255 (odd) writes xb1
  hipLaunchKernelGGL(kv_kernel, dim3(400), dim3(64), 0, stream,
                     xb1, lncw, lncb, kvw, kbuf, vbuf);
  if (pre) {
    hipLaunchKernelGGL(query_fast, dim3(1024), dim3(256), 0, stream,
                       qstore, oww, owb, flnw, flnb,
                       w1, b1, w2, b2, outw, outb, kbuf, vbuf, (float*)d_out);
  } else {
    hipLaunchKernelGGL(query_kernel_fb, dim3(512), dim3(256), 0, stream,
                       qry, pew, peb, lnqw, lnqb, qw, oww, owb, flnw, flnb,
                       w1, b1, w2, b2, outw, outb, kbuf, vbuf, (float*)d_out);
  }
}

// Round 8
// 2151.282 us; speedup vs baseline: 2.1531x; 1.1625x over previous
//
#include <hip/hip_runtime.h>

// ---------------------------------------------------------------------------
// MashDecoderV2: 256-layer mamba stack (L=400, D=40) + 65536-query cross-attn
// decoder. f32 throughout (threshold 1.56e-2).
//
// Round-17 = Round-16 with the pe_done ALIASING FIX:
//   R16 put the PE-completion counter at flags+4080, which IS layer 255's
//   chunk flag (255*16 = 4080) -> QA blocks saw flag255=205 instantly and
//   streamed garbage / spun on a corrupted counter (bench hang). pe_done now
//   lives at flags+4088 (unused word, zeroed by init_flags). QA-side polls
//   use s_sleep(32) (~0.85us) to cut poll traffic ~30x; QA only needs to
//   keep pace with the 4.4us chunk period. Layer-role polling untouched.
//
// Design (R16): layer pipeline = PROVEN R9 body (1820us mamba; R13/R14/R15
// established T~4.4us and skew=f+T are tight). The ~290us serial tail
// (kv + query attention) is STREAMED under the pipeline as a third block
// role (QA): layer-255 publishes chunks every ~4.4us from t~1.4ms; QA
// blocks (205 x 320thr, one query per thread) consume each chunk as
// published (flag[255] protocol), computing LN+KV in-block and an online-
// softmax update per lane. At pipeline end only the last chunk + per-lane
// FFN remain. kv_kernel/query_fast launches deleted on the pre path.
// qstore handoff PE->QA is intra-kernel -> agent-scope atomics + pe_done.
// ---------------------------------------------------------------------------

#define CH 4
#define NCHUNK 100       // 400 / CH
#define TPB1 320
#define NPE 205          // ceil(65536/320)
#define NQA 205

typedef unsigned long long u64;

__device__ __forceinline__ u64 pack2(float a, float b) {
  return ((u64)__float_as_uint(b) << 32) | (u64)__float_as_uint(a);
}
__device__ __forceinline__ float unplo(u64 a) {
  return __uint_as_float((unsigned)a);
}
__device__ __forceinline__ float unphi(u64 a) {
  return __uint_as_float((unsigned)(a >> 32));
}

__global__ void init_flags(int* __restrict__ flags) {
  int i = blockIdx.x * 256 + threadIdx.x;
  if (i < 256 * 16) flags[i] = 0;
}

__global__ __launch_bounds__(TPB1) void mamba_pipe(
    const float* __restrict__ mash,
    const float* __restrict__ g_norm_w,   // (256,40)
    const float* __restrict__ g_in_w,     // (256,160,40)
    const float* __restrict__ g_conv_w,   // (256,80,4)
    const float* __restrict__ g_conv_b,   // (256,80)
    const float* __restrict__ g_xp_w,     // (256,35,80)
    const float* __restrict__ g_dt_w,     // (256,80,3)
    const float* __restrict__ g_dt_b,     // (256,80)
    const float* __restrict__ g_alog,     // (256,80,16)
    const float* __restrict__ g_D,        // (256,80)
    const float* __restrict__ g_out_w,    // (256,40,80)
    float* __restrict__ xb0,
    float* __restrict__ xb1,
    int* __restrict__ flags,
    // PE-block inputs (blocks 256..256+NPE)
    const float* __restrict__ qry,
    const float* __restrict__ pe_w, const float* __restrict__ pe_b,
    const float* __restrict__ lnq_w, const float* __restrict__ lnq_b,
    const float* __restrict__ qw,
    float* __restrict__ qstore,           // q_t[e*65536 + n]
    // QA-block inputs (blocks >= 256+NPE)
    const float* __restrict__ lnc_w, const float* __restrict__ lnc_b,
    const float* __restrict__ kv_w,
    const float* __restrict__ ow, const float* __restrict__ ob,
    const float* __restrict__ flw, const float* __restrict__ flb,
    const float* __restrict__ w1, const float* __restrict__ b1,
    const float* __restrict__ w2, const float* __restrict__ b2,
    const float* __restrict__ outw, const float* __restrict__ outb,
    float* __restrict__ out)
{
  const int tid = threadIdx.x;

  // ---------------- PE blocks: query preprocessing under mamba's shadow ----
  if (blockIdx.x >= 256 && blockIdx.x < 256 + NPE) {
    const int n = (blockIdx.x - 256) * TPB1 + tid;
    if (n < 65536) {
      const float qx = qry[n * 3 + 0], qy = qry[n * 3 + 1], qz = qry[n * 3 + 2];
      float qe[40];
#pragma unroll
      for (int d = 0; d < 40; ++d) qe[d] = pe_b[d];
#pragma unroll 1
      for (int j = 0; j < 8; ++j) {
        float f = 3.14159265358979323846f * (float)(1 << j);
        float sx, cx, sy, cy, sz, cz;
        __sincosf(qx * f, &sx, &cx);
        __sincosf(qy * f, &sy, &cy);
        __sincosf(qz * f, &sz, &cz);
#pragma unroll
        for (int d = 0; d < 40; ++d) {
          const float* r = pe_w + d * 51;
          qe[d] += sx * r[j] + sy * r[j + 8] + sz * r[j + 16]
                 + cx * r[j + 24] + cy * r[j + 32] + cz * r[j + 40];
        }
      }
#pragma unroll
      for (int d = 0; d < 40; ++d) {
        const float* r = pe_w + d * 51;
        qe[d] += qx * r[48] + qy * r[49] + qz * r[50];
      }
      float qn[40];
      {
        float m = 0.f;
#pragma unroll
        for (int d = 0; d < 40; ++d) m += qe[d];
        m *= (1.f / 40.f);
        float var = 0.f;
#pragma unroll
        for (int d = 0; d < 40; ++d) { float dv = qe[d] - m; var += dv * dv; }
        float rstd = rsqrtf(var * (1.f / 40.f) + 1e-5f);
#pragma unroll
        for (int d = 0; d < 40; ++d)
          qn[d] = (qe[d] - m) * rstd * lnq_w[d] + lnq_b[d];
      }
      float q[40];
#pragma unroll
      for (int e = 0; e < 40; ++e) {
        const float* r = qw + e * 40;
        float s = 0.f;
#pragma unroll
        for (int d = 0; d < 40; ++d) s += qn[d] * r[d];
        q[e] = s;
      }
      // agent-scope stores: read by QA blocks within this same kernel
#pragma unroll
      for (int e = 0; e < 40; ++e)
        __hip_atomic_store(&qstore[e * 65536 + n], q[e],
                           __ATOMIC_RELAXED, __HIP_MEMORY_SCOPE_AGENT);
    }
    // publish PE completion: B-drain (vmcnt) orders qstore stores before add.
    // pe_done = flags + 4088 (UNUSED word; layer flags are at stride-16
    // offsets 0..4080 -- R16 aliased 4080 = flag255, the bug).
    __syncthreads();
    if (tid == 0)
      __hip_atomic_fetch_add(flags + 4088, 1,
                             __ATOMIC_RELAXED, __HIP_MEMORY_SCOPE_AGENT);
    return;
  }

  // ---------------- QA blocks: streamed cross-attn + FFN -------------------
  if (blockIdx.x >= 256 + NPE) {
    const int n = (blockIdx.x - 256 - NPE) * TPB1 + tid;  // query id
    const bool qvalid = (n < 65536);
    const int w = tid >> 6;          // wave 0..4
    const int lane = tid & 63;
    __shared__ __align__(16) float kvx[160];     // chunk raw tokens
    __shared__ __align__(16) float cns[4][40];   // LN'd tokens
    __shared__ __align__(16) float ks[4][40];
    __shared__ __align__(16) float vs[4][40];

    int* pe_done = flags + 4088;
    int* flag255 = flags + 255 * 16;

    // wait for qstore (PE blocks) -- completes ~100us, far before flag255>0
    while (__hip_atomic_load(pe_done, __ATOMIC_RELAXED,
                             __HIP_MEMORY_SCOPE_AGENT) < NPE)
      __builtin_amdgcn_s_sleep(32);

    float q[40];
#pragma unroll
    for (int e = 0; e < 40; ++e)
      q[e] = qvalid ? __hip_atomic_load(&qstore[e * 65536 + n],
                                        __ATOMIC_RELAXED,
                                        __HIP_MEMORY_SCOPE_AGENT) : 0.f;

    float acc[40];
#pragma unroll
    for (int d = 0; d < 40; ++d) acc[d] = 0.f;
    float mx = -1e30f, l = 0.f;
    const float scale = 0.15811388300841897f;    // 40^-0.5

#pragma unroll 1
    for (int c = 0; c < NCHUNK; ++c) {
      // wave-uniform poll; loads after observed flag are fresh (B-drained).
      // coarse sleep: QA only needs to keep pace with the ~4.4us period.
      while (__hip_atomic_load(flag255, __ATOMIC_RELAXED,
                               __HIP_MEMORY_SCOPE_AGENT) <= c)
        __builtin_amdgcn_s_sleep(32);
      if (tid < 80) {
        u64 a = __hip_atomic_load((const u64*)(xb1 + c * 160) + tid,
                                  __ATOMIC_RELAXED, __HIP_MEMORY_SCOPE_AGENT);
        kvx[2 * tid] = unplo(a);
        kvx[2 * tid + 1] = unphi(a);
      }
      __syncthreads();                           // QB1: kvx ready
      // LN per token (wave w -> token w), kv_kernel's reduce pattern
      {
        float x = (w < 4 && lane < 40) ? kvx[w * 40 + lane] : 0.f;
        float s = x;
#pragma unroll
        for (int o = 32; o >= 1; o >>= 1) s += __shfl_xor(s, o);
        float m = s * (1.f / 40.f);
        float dv = (lane < 40) ? (x - m) : 0.f;
        float v2 = dv * dv;
#pragma unroll
        for (int o = 32; o >= 1; o >>= 1) v2 += __shfl_xor(v2, o);
        float rstd = rsqrtf(v2 * (1.f / 40.f) + 1e-5f);
        if (w < 4 && lane < 40)
          cns[w][lane] = dv * rstd * lnc_w[lane] + lnc_b[lane];
      }
      __syncthreads();                           // QB2: cns ready
      if (w < 4) {
        for (int e = lane; e < 80; e += 64) {
          float a = 0.f;
#pragma unroll
          for (int d = 0; d < 40; ++d) a += cns[w][d] * kv_w[e * 40 + d];
          if (e < 40) ks[w][e] = a;
          else vs[w][e - 40] = a;
        }
      }
      __syncthreads();                           // QB3: ks/vs ready
      // online-softmax update, 4 tokens, per-lane query
#pragma unroll 1
      for (int t = 0; t < 4; ++t) {
        const float4* kr = (const float4*)&ks[t][0];
        float s0 = 0.f, s1 = 0.f, s2 = 0.f, s3 = 0.f;
#pragma unroll
        for (int k = 0; k < 10; ++k) {
          float4 k4 = kr[k];
          s0 += q[4 * k] * k4.x; s1 += q[4 * k + 1] * k4.y;
          s2 += q[4 * k + 2] * k4.z; s3 += q[4 * k + 3] * k4.w;
        }
        float s = ((s0 + s1) + (s2 + s3)) * scale;
        if (s > mx) {
          float corr = __expf(mx - s);
          l *= corr;
#pragma unroll
          for (int d = 0; d < 40; ++d) acc[d] *= corr;
          mx = s;
        }
        float p = __expf(s - mx);
        l += p;
        const float4* vr = (const float4*)&vs[t][0];
#pragma unroll
        for (int k = 0; k < 10; ++k) {
          float4 v4 = vr[k];
          acc[4 * k] += p * v4.x; acc[4 * k + 1] += p * v4.y;
          acc[4 * k + 2] += p * v4.z; acc[4 * k + 3] += p * v4.w;
        }
      }
      __syncthreads();                           // QB4: chunk consumed
    }

    // ---- finalize (per lane, no merge) + FFN ----
    float linv = 1.f / l;
#pragma unroll
    for (int d = 0; d < 40; ++d) acc[d] *= linv;   // acc = lat
    float lat2[40];
#pragma unroll 1
    for (int e = 0; e < 40; ++e) {
      const float* r = ow + e * 40;                // uniform -> broadcast
      float s = 0.f;
#pragma unroll
      for (int d = 0; d < 40; ++d) s += acc[d] * r[d];
      lat2[e] = ob[e] + s;
    }
    float hh[40];
    {
      float m = 0.f;
#pragma unroll
      for (int d = 0; d < 40; ++d) m += lat2[d];
      m *= (1.f / 40.f);
      float var = 0.f;
#pragma unroll
      for (int d = 0; d < 40; ++d) { float dv = lat2[d] - m; var += dv * dv; }
      float rstd = rsqrtf(var * (1.f / 40.f) + 1e-5f);
#pragma unroll
      for (int d = 0; d < 40; ++d)
        hh[d] = (lat2[d] - m) * rstd * flw[d] + flb[d];
    }
    float ff[40];
#pragma unroll
    for (int d = 0; d < 40; ++d) ff[d] = 0.f;
#pragma unroll 1
    for (int e = 0; e < 160; ++e) {
      const float* r1 = w1 + e * 40;               // uniform -> broadcast
      const float* r2 = w1 + (160 + e) * 40;
      float s0 = 0.f, s1 = 0.f;
#pragma unroll
      for (int d = 0; d < 40; ++d) { s0 += hh[d] * r1[d]; s1 += hh[d] * r2[d]; }
      float x1 = s0 + b1[e];
      float g = s1 + b1[160 + e];
      float tv = x1 * (0.5f * g * (1.f + erff(g * 0.70710678118654752f)));
#pragma unroll
      for (int d = 0; d < 40; ++d) ff[d] += tv * w2[d * 160 + e];
    }
    float r = outb[0];
#pragma unroll
    for (int d = 0; d < 40; ++d)
      r += (lat2[d] + ff[d] + b2[d]) * outw[d];
    if (qvalid) out[n] = r;
    return;
  }

  // ---------------- layer blocks: R9 mamba loop (byte-identical) -----------
  const int layer = blockIdx.x;

  __shared__ float xin[160];
  __shared__ float xz[640];
  __shared__ float xs[320];
  __shared__ float dbc[144];        // stride 36
  __shared__ float yb[320];
  __shared__ float xhist[240];      // conv tail

  const int e_in = tid % 160;
  const int tA = tid / 160;
  float w_in_r[40];                 // in_proj row with rmsnorm weight folded
  {
    const float4* g = (const float4*)(g_in_w + layer * 6400 + e_in * 40);
    const float4* nw = (const float4*)(g_norm_w + layer * 40);
#pragma unroll
    for (int k = 0; k < 10; ++k) {
      float4 v = g[k];
      float4 n = nw[k];
      w_in_r[4 * k] = v.x * n.x; w_in_r[4 * k + 1] = v.y * n.y;
      w_in_r[4 * k + 2] = v.z * n.z; w_in_r[4 * k + 3] = v.w * n.w;
    }
  }
  const int d_c = tid % 80;
  const int t_c = tid / 80;
  float cw[4]; float cb;
  {
    float4 v = *(const float4*)(g_conv_w + layer * 320 + d_c * 4);
    cw[0] = v.x; cw[1] = v.y; cw[2] = v.z; cw[3] = v.w;
    cb = g_conv_b[layer * 80 + d_c];
  }
  const int halfp = tid & 1;
  const int p_x = tid >> 1;              // <140 active for x_proj
  const int t_x = p_x / 35, e_x = p_x % 35;
  float w_xp_r[40];
  if (p_x < 140) {
    const float4* g = (const float4*)(g_xp_w + layer * 2800 + e_x * 80 + halfp * 40);
#pragma unroll
    for (int k = 0; k < 10; ++k) {
      float4 v = g[k];
      w_xp_r[4 * k] = v.x; w_xp_r[4 * k + 1] = v.y;
      w_xp_r[4 * k + 2] = v.z; w_xp_r[4 * k + 3] = v.w;
    }
  }
  const int d_ch = tid >> 2;
  const int qq = tid & 3;
  float negA[4], hst[4];
  {
    float4 v = *(const float4*)(g_alog + layer * 1280 + tid * 4);
    negA[0] = -__expf(v.x); negA[1] = -__expf(v.y);
    negA[2] = -__expf(v.z); negA[3] = -__expf(v.w);
    hst[0] = hst[1] = hst[2] = hst[3] = 0.f;
  }
  const float dtw0 = g_dt_w[layer * 240 + d_ch * 3 + 0];
  const float dtw1 = g_dt_w[layer * 240 + d_ch * 3 + 1];
  const float dtw2 = g_dt_w[layer * 240 + d_ch * 3 + 2];
  const float dtb = g_dt_b[layer * 80 + d_ch];
  const float wD = g_D[layer * 80 + d_ch];
  const int p_o = tid >> 1;
  const int t_o = p_o / 40, e_o = p_o % 40;
  float w_out_r[40];
  {
    const float4* g = (const float4*)(g_out_w + layer * 3200 + e_o * 80 + halfp * 40);
#pragma unroll
    for (int k = 0; k < 10; ++k) {
      float4 v = g[k];
      w_out_r[4 * k] = v.x; w_out_r[4 * k + 1] = v.y;
      w_out_r[4 * k + 2] = v.z; w_out_r[4 * k + 3] = v.w;
    }
  }

  for (int i = tid; i < 240; i += TPB1) xhist[i] = 0.f;
  __syncthreads();

  const float* src = (layer == 0) ? mash : ((layer & 1) ? xb0 : xb1);
  float* dst = (layer & 1) ? xb1 : xb0;
  int* flag_prev = flags + (layer - 1) * 16;
  int* flag_cur = flags + layer * 16;

  for (int c = 0; c < NCHUNK; ++c) {
    const int t0 = c * CH;

    // ---- Phase A: ordered acquire + in_proj (rmsnorm folded) ----
    if (layer == 0) {
#pragma unroll
      for (int tt = 0; tt < 2; ++tt) {
        const int t = tA + 2 * tt;
        const float4* sp = (const float4*)(src + (t0 + t) * 40);
        float ss = 0.f, sd = 0.f;
#pragma unroll
        for (int k = 0; k < 10; ++k) {
          float4 v = sp[k];
          ss += v.x * v.x + v.y * v.y + v.z * v.z + v.w * v.w;
          sd += w_in_r[4 * k] * v.x + w_in_r[4 * k + 1] * v.y
              + w_in_r[4 * k + 2] * v.z + w_in_r[4 * k + 3] * v.w;
        }
        xz[t * 160 + e_in] = sd * rsqrtf(ss * (1.f / 40.f) + 1e-5f);
      }
      if (tid < 160) xin[tid] = src[t0 * 40 + tid];
    } else {
      // every wave polls (wave-uniform); loads are program-ordered after the
      // observed flag -> guaranteed fresh (producer B5-drained before flag)
      while (__hip_atomic_load(flag_prev, __ATOMIC_RELAXED,
                               __HIP_MEMORY_SCOPE_AGENT) <= c)
        __builtin_amdgcn_s_sleep(1);
#pragma unroll
      for (int tt = 0; tt < 2; ++tt) {
        const int t = tA + 2 * tt;
        const u64* sp = (const u64*)(src + (t0 + t) * 40);
        float ss = 0.f, sd = 0.f;
#pragma unroll
        for (int k = 0; k < 20; ++k) {
          u64 a = __hip_atomic_load(sp + k, __ATOMIC_RELAXED,
                                    __HIP_MEMORY_SCOPE_AGENT);
          float v0 = unplo(a), v1 = unphi(a);
          ss += v0 * v0 + v1 * v1;
          sd += w_in_r[2 * k] * v0 + w_in_r[2 * k + 1] * v1;
        }
        xz[t * 160 + e_in] = sd * rsqrtf(ss * (1.f / 40.f) + 1e-5f);
      }
      if (tid < 80) {
        u64 a = __hip_atomic_load((const u64*)(src + t0 * 40) + tid,
                                  __ATOMIC_RELAXED, __HIP_MEMORY_SCOPE_AGENT);
        xin[2 * tid] = unplo(a);
        xin[2 * tid + 1] = unphi(a);
      }
    }
    __syncthreads();                                   // B1: xz, xin ready

    // ---- causal depthwise conv(4) + silu ----
    {
      float acc = cb;
#pragma unroll
      for (int j = 0; j < 4; ++j) {
        int lt = t_c - 3 + j;
        float xv = (lt >= 0) ? xz[lt * 160 + d_c] : xhist[(lt + 3) * 80 + d_c];
        acc += cw[j] * xv;
      }
      xs[t_c * 80 + d_c] = acc / (1.f + __expf(-acc));
    }
    __syncthreads();                                   // B2: xs ready

    // ---- x_proj: pair half-dots + shfl merge; idle threads refresh xhist ----
    if (p_x < 140) {
      const float4* xp = (const float4*)&xs[t_x * 80 + halfp * 40];
      float s = 0.f;
#pragma unroll
      for (int k = 0; k < 10; ++k) {
        float4 v = xp[k];
        s += w_xp_r[4 * k] * v.x + w_xp_r[4 * k + 1] * v.y
           + w_xp_r[4 * k + 2] * v.z + w_xp_r[4 * k + 3] * v.w;
      }
      s += __shfl_xor(s, 1);
      if (halfp == 0) dbc[t_x * 36 + e_x] = s;
    } else {
      for (int k = tid - 280; k < 240; k += 40)
        xhist[k] = xz[(1 + k / 80) * 160 + (k % 80)];
    }
    __syncthreads();                                   // B3: dbc ready

    // ---- selective scan; dt inline; state in regs ----
#pragma unroll
    for (int t = 0; t < CH; ++t) {
      const float* db = &dbc[t * 36];
      float sdt = dtb + db[0] * dtw0 + db[1] * dtw1 + db[2] * dtw2;
      float dtval = (sdt > 15.f) ? sdt : __logf(1.f + __expf(sdt));
      float xval = xs[t * 80 + d_ch];
      float part = 0.f;
#pragma unroll
      for (int j = 0; j < 4; ++j) {
        int s_i = qq * 4 + j;
        float Bv = db[3 + s_i];
        float Cv = db[19 + s_i];
        hst[j] = __expf(dtval * negA[j]) * hst[j] + dtval * Bv * xval;
        part += hst[j] * Cv;
      }
      part += __shfl_xor(part, 1);
      part += __shfl_xor(part, 2);
      if (qq == 0) {
        float yv = part + xval * wD;
        float z = xz[t * 160 + 80 + d_ch];
        yb[t * 80 + d_ch] = yv * z / (1.f + __expf(-z));
      }
    }
    __syncthreads();                                   // B4: yb ready

    // ---- out_proj + residual -> paired dwordx2 coherent stores ----
    {
      const float4* yp = (const float4*)&yb[t_o * 80 + halfp * 40];
      float s = 0.f;
#pragma unroll
      for (int k = 0; k < 10; ++k) {
        float4 v = yp[k];
        s += w_out_r[4 * k] * v.x + w_out_r[4 * k + 1] * v.y
           + w_out_r[4 * k + 2] * v.z + w_out_r[4 * k + 3] * v.w;
      }
      s += __shfl_xor(s, 1);
      float r = xin[p_o] + s;          // valid on pair leaders (halfp==0)
      float r2 = __shfl_xor(r, 2);     // leader tid+2's value (p_o+1)
      if ((tid & 3) == 0)              // even p_o leaders store the pair
        __hip_atomic_store((u64*)(dst + t0 * 40 + p_o), pack2(r, r2),
                           __ATOMIC_RELAXED, __HIP_MEMORY_SCOPE_AGENT);
    }
    __syncthreads();        // B5: drains vmcnt -> all stores acked at IF$
    if (tid == 0)
      __hip_atomic_store(flag_cur, c + 1, __ATOMIC_RELAXED,
                         __HIP_MEMORY_SCOPE_AGENT);
  }
}

// ---- context side of cross-attn (FALLBACK path only) ----
__global__ __launch_bounds__(64) void kv_kernel(
    const float* __restrict__ xfin,
    const float* __restrict__ lnc_w, const float* __restrict__ lnc_b,
    const float* __restrict__ kv_w,
    float* __restrict__ kbuf, float* __restrict__ vbuf)
{
  int t = blockIdx.x;
  int lane = threadIdx.x;
  float x = (lane < 40) ? xfin[t * 40 + lane] : 0.f;
  float s = x;
#pragma unroll
  for (int o = 32; o >= 1; o >>= 1) s += __shfl_xor(s, o);
  float m = s * (1.f / 40.f);
  float dv = (lane < 40) ? (x - m) : 0.f;
  float v2 = dv * dv;
#pragma unroll
  for (int o = 32; o >= 1; o >>= 1) v2 += __shfl_xor(v2, o);
  float rstd = rsqrtf(v2 * (1.f / 40.f) + 1e-5f);
  __shared__ float cn[40];
  if (lane < 40) cn[lane] = dv * rstd * lnc_w[lane] + lnc_b[lane];
  __syncthreads();
  for (int e = lane; e < 80; e += 64) {
    float acc = 0.f;
#pragma unroll
    for (int d = 0; d < 40; ++d) acc += cn[d] * kv_w[e * 40 + d];
    if (e < 40) kbuf[t * 40 + e] = acc;
    else vbuf[t * 40 + (e - 40)] = acc;
  }
}

// ---- fallback query (R8, PE inside) for small ws ----
__global__ __launch_bounds__(256) void query_kernel_fb(
    const float* __restrict__ qry,
    const float* __restrict__ pe_w, const float* __restrict__ pe_b,
    const float* __restrict__ lnq_w, const float* __restrict__ lnq_b,
    const float* __restrict__ qw,
    const float* __restrict__ ow, const float* __restrict__ ob,
    const float* __restrict__ flw, const float* __restrict__ flb,
    const float* __restrict__ w1, const float* __restrict__ b1,
    const float* __restrict__ w2, const float* __restrict__ b2,
    const float* __restrict__ outw, const float* __restrict__ outb,
    const float* __restrict__ kbuf, const float* __restrict__ vbuf,
    float* __restrict__ out)
{
  const int tid = threadIdx.x;
  const int h = __builtin_amdgcn_readfirstlane((tid >> 6) & 1);
  const int pj = tid >> 7;
  const int lane = tid & 63;
  const int n = blockIdx.x * 128 + pj * 64 + lane;
  const int ptn = tid ^ 64;
  __shared__ float colbuf[40 * 256];
  __shared__ float redm[256], redl[256];

  const float qx = qry[n * 3 + 0], qy = qry[n * 3 + 1], qz = qry[n * 3 + 2];
  float qp[40];
#pragma unroll
  for (int d = 0; d < 40; ++d) qp[d] = 0.f;
#pragma unroll
  for (int jj = 0; jj < 4; ++jj) {
    const int j = h * 4 + jj;
    float f = 3.14159265358979323846f * (float)(1 << j);
    float sx, cx, sy, cy, sz, cz;
    __sincosf(qx * f, &sx, &cx);
    __sincosf(qy * f, &sy, &cy);
    __sincosf(qz * f, &sz, &cz);
#pragma unroll
    for (int d = 0; d < 40; ++d) {
      const float* r = pe_w + d * 51;
      qp[d] += sx * r[j] + sy * r[j + 8] + sz * r[j + 16]
             + cx * r[j + 24] + cy * r[j + 32] + cz * r[j + 40];
    }
  }
#pragma unroll
  for (int d = 0; d < 40; ++d) colbuf[d * 256 + tid] = qp[d];
  __syncthreads();
  float qe[40];
#pragma unroll
  for (int d = 0; d < 40; ++d) {
    const float* r = pe_w + d * 51;
    qe[d] = pe_b[d] + qp[d] + colbuf[d * 256 + ptn]
          + qx * r[48] + qy * r[49] + qz * r[50];
  }
  __syncthreads();
  float qn[40];
  {
    float m = 0.f;
#pragma unroll
    for (int d = 0; d < 40; ++d) m += qe[d];
    m *= (1.f / 40.f);
    float var = 0.f;
#pragma unroll
    for (int d = 0; d < 40; ++d) { float dv = qe[d] - m; var += dv * dv; }
    float rstd = rsqrtf(var * (1.f / 40.f) + 1e-5f);
#pragma unroll
    for (int d = 0; d < 40; ++d) qn[d] = (qe[d] - m) * rstd * lnq_w[d] + lnq_b[d];
  }
  float qnh[20];
#pragma unroll
  for (int dd = 0; dd < 20; ++dd) qnh[dd] = h ? qn[dd + 20] : qn[dd];
  float q[40];
#pragma unroll
  for (int e = 0; e < 40; ++e) q[e] = 0.f;
#pragma unroll 1
  for (int dd = 0; dd < 20; ++dd) {
    const float qv = qnh[dd];
    const int d = h * 20 + dd;
#pragma unroll
    for (int e = 0; e < 40; ++e) q[e] += qv * qw[e * 40 + d];
  }
#pragma unroll
  for (int e = 0; e < 40; ++e) colbuf[e * 256 + tid] = q[e];
  __syncthreads();
#pragma unroll
  for (int e = 0; e < 40; ++e) q[e] += colbuf[e * 256 + ptn];
  __syncthreads();

  float acc[40];
#pragma unroll
  for (int d = 0; d < 40; ++d) acc[d] = 0.f;
  float mx = -1e30f, l = 0.f;
  const float scale = 0.15811388300841897f;
  const int tbeg = h * 200, tend = tbeg + 200;
#pragma unroll 1
  for (int t = tbeg; t < tend; ++t) {
    const float4* kr = (const float4*)(kbuf + t * 40);
    float s0 = 0.f, s1 = 0.f, s2 = 0.f, s3 = 0.f;
#pragma unroll
    for (int k = 0; k < 10; ++k) {
      float4 k4 = kr[k];
      s0 += q[4 * k] * k4.x; s1 += q[4 * k + 1] * k4.y;
      s2 += q[4 * k + 2] * k4.z; s3 += q[4 * k + 3] * k4.w;
    }
    float s = ((s0 + s1) + (s2 + s3)) * scale;
    if (s > mx) {
      float corr = __expf(mx - s);
      l *= corr;
#pragma unroll
      for (int d = 0; d < 40; ++d) acc[d] *= corr;
      mx = s;
    }
    float p = __expf(s - mx);
    l += p;
    const float4* vr = (const float4*)(vbuf + t * 40);
#pragma unroll
    for (int k = 0; k < 10; ++k) {
      float4 v4 = vr[k];
      acc[4 * k] += p * v4.x; acc[4 * k + 1] += p * v4.y;
      acc[4 * k + 2] += p * v4.z; acc[4 * k + 3] += p * v4.w;
    }
  }
#pragma unroll
  for (int d = 0; d < 40; ++d) colbuf[d * 256 + tid] = acc[d];
  redm[tid] = mx; redl[tid] = l;
  __syncthreads();
  float lat[40];
  {
    float m2 = redm[ptn];
    float l2 = redl[ptn];
    float nm = fmaxf(mx, m2);
    float a = __expf(mx - nm), b = __expf(m2 - nm);
    float lm = l * a + l2 * b;
    float linv = 1.f / lm;
#pragma unroll
    for (int d = 0; d < 40; ++d)
      lat[d] = (acc[d] * a + colbuf[d * 256 + ptn] * b) * linv;
  }
  __syncthreads();
  float lath[20];
#pragma unroll
  for (int dd = 0; dd < 20; ++dd) lath[dd] = h ? lat[dd + 20] : lat[dd];
  float lp[40];
#pragma unroll
  for (int e = 0; e < 40; ++e) lp[e] = 0.f;
#pragma unroll 1
  for (int dd = 0; dd < 20; ++dd) {
    const float lv = lath[dd];
    const int d = h * 20 + dd;
#pragma unroll
    for (int e = 0; e < 40; ++e) lp[e] += lv * ow[e * 40 + d];
  }
#pragma unroll
  for (int e = 0; e < 40; ++e) colbuf[e * 256 + tid] = lp[e];
  __syncthreads();
  float lat2[40];
#pragma unroll
  for (int e = 0; e < 40; ++e) lat2[e] = ob[e] + lp[e] + colbuf[e * 256 + ptn];
  __syncthreads();
  float hh[40];
  {
    float m = 0.f;
#pragma unroll
    for (int d = 0; d < 40; ++d) m += lat2[d];
    m *= (1.f / 40.f);
    float var = 0.f;
#pragma unroll
    for (int d = 0; d < 40; ++d) { float dv = lat2[d] - m; var += dv * dv; }
    float rstd = rsqrtf(var * (1.f / 40.f) + 1e-5f);
#pragma unroll
    for (int d = 0; d < 40; ++d) hh[d] = (lat2[d] - m) * rstd * flw[d] + flb[d];
  }
  float ff[40];
#pragma unroll
  for (int d = 0; d < 40; ++d) ff[d] = 0.f;
#pragma unroll 1
  for (int ee = 0; ee < 80; ++ee) {
    const int e = h * 80 + ee;
    const float* r1 = w1 + e * 40;
    const float* r2 = w1 + (160 + e) * 40;
    float s0 = 0.f, s1 = 0.f;
#pragma unroll
    for (int d = 0; d < 40; ++d) { s0 += hh[d] * r1[d]; s1 += hh[d] * r2[d]; }
    float x1 = s0 + b1[e];
    float g = s1 + b1[160 + e];
    float tv = x1 * (0.5f * g * (1.f + erff(g * 0.70710678118654752f)));
#pragma unroll
    for (int d = 0; d < 40; ++d) ff[d] += tv * w2[d * 160 + e];
  }
#pragma unroll
  for (int d = 0; d < 40; ++d) colbuf[d * 256 + tid] = ff[d];
  __syncthreads();
  float r = outb[0];
#pragma unroll
  for (int d = 0; d < 40; ++d) {
    float f = ff[d] + colbuf[d * 256 + ptn] + b2[d];
    r += (lat2[d] + f) * outw[d];
  }
  if (h == 0) out[n] = r;
}

extern "C" void kernel_launch(void* const* d_in, const int* in_sizes, int n_in,
                              void* d_out, int out_size, void* d_ws, size_t ws_size,
                              hipStream_t stream) {
  const float* mash   = (const float*)d_in[0];
  const float* qry    = (const float*)d_in[1];
  const float* lnw    = (const float*)d_in[2];
  const float* linw   = (const float*)d_in[3];
  const float* lconvw = (const float*)d_in[4];
  const float* lconvb = (const float*)d_in[5];
  const float* lxpw   = (const float*)d_in[6];
  const float* ldtw   = (const float*)d_in[7];
  const float* ldtb   = (const float*)d_in[8];
  const float* lAlog  = (const float*)d_in[9];
  const float* lD     = (const float*)d_in[10];
  const float* loutw  = (const float*)d_in[11];
  const float* pew    = (const float*)d_in[12];
  const float* peb    = (const float*)d_in[13];
  const float* lnqw   = (const float*)d_in[14];
  const float* lnqb   = (const float*)d_in[15];
  const float* lncw   = (const float*)d_in[16];
  const float* lncb   = (const float*)d_in[17];
  const float* qw     = (const float*)d_in[18];
  const float* kvw    = (const float*)d_in[19];
  const float* oww    = (const float*)d_in[20];
  const float* owb    = (const float*)d_in[21];
  const float* flnw   = (const float*)d_in[22];
  const float* flnb   = (const float*)d_in[23];
  const float* w1     = (const float*)d_in[24];
  const float* b1     = (const float*)d_in[25];
  const float* w2     = (const float*)d_in[26];
  const float* b2     = (const float*)d_in[27];
  const float* outw   = (const float*)d_in[28];
  const float* outb   = (const float*)d_in[29];

  // ws layout (floats): xb0[16000] xb1[16000] k[16000] v[16000]
  //                     flags[4096 ints] qstore[40*65536]
  float* wsf = (float*)d_ws;
  float* xb0 = wsf;
  float* xb1 = wsf + 16000;
  float* kbuf = wsf + 32000;
  float* vbuf = wsf + 48000;
  int* flags = (int*)(wsf + 64000);
  float* qstore = wsf + 68096;
  const size_t needed = (size_t)68096 * 4 + (size_t)40 * 65536 * 4;
  const bool pre = ws_size >= needed;   // constant across calls -> capture-safe

  hipLaunchKernelGGL(init_flags, dim3(16), dim3(256), 0, stream, flags);
  // 256 layer blocks + (pre ? NPE PE blocks + NQA QA blocks : 0)
  hipLaunchKernelGGL(mamba_pipe, dim3(pre ? 256 + NPE + NQA : 256), dim3(TPB1),
                     0, stream,
                     mash, lnw, linw, lconvw, lconvb, lxpw, ldtw, ldtb, lAlog,
                     lD, loutw, xb0, xb1, flags,
                     qry, pew, peb, lnqw, lnqb, qw, qstore,
                     lncw, lncb, kvw, oww, owb, flnw, flnb,
                     w1, b1, w2, b2, outw, outb, (float*)d_out);
  if (!pre) {
    // layer 255 (odd) writes xb1
    hipLaunchKernelGGL(kv_kernel, dim3(400), dim3(64), 0, stream,
                       xb1, lncw, lncb, kvw, kbuf, vbuf);
    hipLaunchKernelGGL(query_kernel_fb, dim3(512), dim3(256), 0, stream,
                       qry, pew, peb, lnqw, lnqb, qw, oww, owb, flnw, flnb,
                       w1, b1, w2, b2, outw, outb, kbuf, vbuf, (float*)d_out);
  }
}

// Round 9
// 2116.954 us; speedup vs baseline: 2.1880x; 1.0162x over previous
//
#include <hip/hip_runtime.h>

// ---------------------------------------------------------------------------
// MashDecoderV2: 256-layer mamba stack (L=400, D=40) + 65536-query cross-attn
// decoder. f32 throughout (threshold 1.56e-2).
//
// Round-18 = Round-17 (streamed QA, passed @2151us total / 2077 mamba) with
// three interference/tail cuts; layer-pipeline body byte-identical (R9):
//  1. QA polls via SINGLE WAVE + barrier (was 5 waves/block): R17 had 1025
//     waves hammering one MALL line at ~1200 loads/us -> queueing that
//     slowed the pipeline's own flag traffic (+240us vs pure pipeline).
//  2. Layer-255 replicates its chunk flag to 8 line-separated slots
//     (flags[4096 + 32*r]); QA block b polls replica b&7 -> ~30 loads/us
//     per line. Replicas live in a new 256-int region; qstore shifted.
//  3. QA finalize uses per-block precomputed w2o[e] = sum_d w2[d][e]*outw[d]
//     -> ff[40] array and 6400 FMA/query deleted (kills the ~10MB scratch
//     spill seen in WRITE_SIZE, trims the post-pipeline tail).
// ---------------------------------------------------------------------------

#define CH 4
#define NCHUNK 100       // 400 / CH
#define TPB1 320
#define NPE 205          // ceil(65536/320)
#define NQA 205

typedef unsigned long long u64;

__device__ __forceinline__ u64 pack2(float a, float b) {
  return ((u64)__float_as_uint(b) << 32) | (u64)__float_as_uint(a);
}
__device__ __forceinline__ float unplo(u64 a) {
  return __uint_as_float((unsigned)a);
}
__device__ __forceinline__ float unphi(u64 a) {
  return __uint_as_float((unsigned)(a >> 32));
}

__global__ void init_flags(int* __restrict__ flags) {
  int i = blockIdx.x * 256 + threadIdx.x;
  if (i < 4352) flags[i] = 0;    // 4096 layer/pe words + 256 replica region
}

__global__ __launch_bounds__(TPB1) void mamba_pipe(
    const float* __restrict__ mash,
    const float* __restrict__ g_norm_w,   // (256,40)
    const float* __restrict__ g_in_w,     // (256,160,40)
    const float* __restrict__ g_conv_w,   // (256,80,4)
    const float* __restrict__ g_conv_b,   // (256,80)
    const float* __restrict__ g_xp_w,     // (256,35,80)
    const float* __restrict__ g_dt_w,     // (256,80,3)
    const float* __restrict__ g_dt_b,     // (256,80)
    const float* __restrict__ g_alog,     // (256,80,16)
    const float* __restrict__ g_D,        // (256,80)
    const float* __restrict__ g_out_w,    // (256,40,80)
    float* __restrict__ xb0,
    float* __restrict__ xb1,
    int* __restrict__ flags,
    // PE-block inputs (blocks 256..256+NPE)
    const float* __restrict__ qry,
    const float* __restrict__ pe_w, const float* __restrict__ pe_b,
    const float* __restrict__ lnq_w, const float* __restrict__ lnq_b,
    const float* __restrict__ qw,
    float* __restrict__ qstore,           // q_t[e*65536 + n]
    // QA-block inputs (blocks >= 256+NPE)
    const float* __restrict__ lnc_w, const float* __restrict__ lnc_b,
    const float* __restrict__ kv_w,
    const float* __restrict__ ow, const float* __restrict__ ob,
    const float* __restrict__ flw, const float* __restrict__ flb,
    const float* __restrict__ w1, const float* __restrict__ b1,
    const float* __restrict__ w2, const float* __restrict__ b2,
    const float* __restrict__ outw, const float* __restrict__ outb,
    float* __restrict__ out)
{
  const int tid = threadIdx.x;

  // ---------------- PE blocks: query preprocessing under mamba's shadow ----
  if (blockIdx.x >= 256 && blockIdx.x < 256 + NPE) {
    const int n = (blockIdx.x - 256) * TPB1 + tid;
    if (n < 65536) {
      const float qx = qry[n * 3 + 0], qy = qry[n * 3 + 1], qz = qry[n * 3 + 2];
      float qe[40];
#pragma unroll
      for (int d = 0; d < 40; ++d) qe[d] = pe_b[d];
#pragma unroll 1
      for (int j = 0; j < 8; ++j) {
        float f = 3.14159265358979323846f * (float)(1 << j);
        float sx, cx, sy, cy, sz, cz;
        __sincosf(qx * f, &sx, &cx);
        __sincosf(qy * f, &sy, &cy);
        __sincosf(qz * f, &sz, &cz);
#pragma unroll
        for (int d = 0; d < 40; ++d) {
          const float* r = pe_w + d * 51;
          qe[d] += sx * r[j] + sy * r[j + 8] + sz * r[j + 16]
                 + cx * r[j + 24] + cy * r[j + 32] + cz * r[j + 40];
        }
      }
#pragma unroll
      for (int d = 0; d < 40; ++d) {
        const float* r = pe_w + d * 51;
        qe[d] += qx * r[48] + qy * r[49] + qz * r[50];
      }
      float qn[40];
      {
        float m = 0.f;
#pragma unroll
        for (int d = 0; d < 40; ++d) m += qe[d];
        m *= (1.f / 40.f);
        float var = 0.f;
#pragma unroll
        for (int d = 0; d < 40; ++d) { float dv = qe[d] - m; var += dv * dv; }
        float rstd = rsqrtf(var * (1.f / 40.f) + 1e-5f);
#pragma unroll
        for (int d = 0; d < 40; ++d)
          qn[d] = (qe[d] - m) * rstd * lnq_w[d] + lnq_b[d];
      }
      float q[40];
#pragma unroll
      for (int e = 0; e < 40; ++e) {
        const float* r = qw + e * 40;
        float s = 0.f;
#pragma unroll
        for (int d = 0; d < 40; ++d) s += qn[d] * r[d];
        q[e] = s;
      }
      // agent-scope stores: read by QA blocks within this same kernel
#pragma unroll
      for (int e = 0; e < 40; ++e)
        __hip_atomic_store(&qstore[e * 65536 + n], q[e],
                           __ATOMIC_RELAXED, __HIP_MEMORY_SCOPE_AGENT);
    }
    // publish PE completion: B-drain (vmcnt) orders qstore stores before add
    __syncthreads();
    if (tid == 0)
      __hip_atomic_fetch_add(flags + 4088, 1,
                             __ATOMIC_RELAXED, __HIP_MEMORY_SCOPE_AGENT);
    return;
  }

  // ---------------- QA blocks: streamed cross-attn + FFN -------------------
  if (blockIdx.x >= 256 + NPE) {
    const int n = (blockIdx.x - 256 - NPE) * TPB1 + tid;  // query id
    const bool qvalid = (n < 65536);
    const int w = tid >> 6;          // wave 0..4
    const int lane = tid & 63;
    __shared__ __align__(16) float kvx[160];     // chunk raw tokens
    __shared__ __align__(16) float cns[4][40];   // LN'd tokens
    __shared__ __align__(16) float ks[4][40];
    __shared__ __align__(16) float vs[4][40];
    __shared__ float w2o[160];                   // sum_d w2[d][e]*outw[d]

    int* pe_done = flags + 4088;
    int* rep = flags + 4096 + 32 * (blockIdx.x & 7);   // line-separated

    // per-block precompute for the finalize (used after many barriers)
    if (tid < 160) {
      float s = 0.f;
#pragma unroll
      for (int d = 0; d < 40; ++d) s += w2[d * 160 + tid] * outw[d];
      w2o[tid] = s;
    }

    // wait for qstore (PE blocks): single wave polls, barrier releases
    if (w == 0) {
      while (__hip_atomic_load(pe_done, __ATOMIC_RELAXED,
                               __HIP_MEMORY_SCOPE_AGENT) < NPE)
        __builtin_amdgcn_s_sleep(64);
    }
    __syncthreads();

    float q[40];
#pragma unroll
    for (int e = 0; e < 40; ++e)
      q[e] = qvalid ? __hip_atomic_load(&qstore[e * 65536 + n],
                                        __ATOMIC_RELAXED,
                                        __HIP_MEMORY_SCOPE_AGENT) : 0.f;

    float acc[40];
#pragma unroll
    for (int d = 0; d < 40; ++d) acc[d] = 0.f;
    float mx = -1e30f, l = 0.f;
    const float scale = 0.15811388300841897f;    // 40^-0.5

#pragma unroll 1
    for (int c = 0; c < NCHUNK; ++c) {
      // single-wave poll on this block's replica; barrier releases the rest.
      // data loads below are agent-scope (bypass L2); producer B5-drained
      // before writing the flag -> any load issued after the observation
      // (enforced by the barrier) sees fresh MALL data.
      if (w == 0) {
        while (__hip_atomic_load(rep, __ATOMIC_RELAXED,
                                 __HIP_MEMORY_SCOPE_AGENT) <= c)
          __builtin_amdgcn_s_sleep(32);
      }
      __syncthreads();                           // QB0: flag observed
      if (tid < 80) {
        u64 a = __hip_atomic_load((const u64*)(xb1 + c * 160) + tid,
                                  __ATOMIC_RELAXED, __HIP_MEMORY_SCOPE_AGENT);
        kvx[2 * tid] = unplo(a);
        kvx[2 * tid + 1] = unphi(a);
      }
      __syncthreads();                           // QB1: kvx ready
      // LN per token (wave w -> token w), kv_kernel's reduce pattern
      {
        float x = (w < 4 && lane < 40) ? kvx[w * 40 + lane] : 0.f;
        float s = x;
#pragma unroll
        for (int o = 32; o >= 1; o >>= 1) s += __shfl_xor(s, o);
        float m = s * (1.f / 40.f);
        float dv = (lane < 40) ? (x - m) : 0.f;
        float v2 = dv * dv;
#pragma unroll
        for (int o = 32; o >= 1; o >>= 1) v2 += __shfl_xor(v2, o);
        float rstd = rsqrtf(v2 * (1.f / 40.f) + 1e-5f);
        if (w < 4 && lane < 40)
          cns[w][lane] = dv * rstd * lnc_w[lane] + lnc_b[lane];
      }
      __syncthreads();                           // QB2: cns ready
      if (w < 4) {
        for (int e = lane; e < 80; e += 64) {
          float a = 0.f;
#pragma unroll
          for (int d = 0; d < 40; ++d) a += cns[w][d] * kv_w[e * 40 + d];
          if (e < 40) ks[w][e] = a;
          else vs[w][e - 40] = a;
        }
      }
      __syncthreads();                           // QB3: ks/vs ready
      // online-softmax update, 4 tokens, per-lane query
#pragma unroll 1
      for (int t = 0; t < 4; ++t) {
        const float4* kr = (const float4*)&ks[t][0];
        float s0 = 0.f, s1 = 0.f, s2 = 0.f, s3 = 0.f;
#pragma unroll
        for (int k = 0; k < 10; ++k) {
          float4 k4 = kr[k];
          s0 += q[4 * k] * k4.x; s1 += q[4 * k + 1] * k4.y;
          s2 += q[4 * k + 2] * k4.z; s3 += q[4 * k + 3] * k4.w;
        }
        float s = ((s0 + s1) + (s2 + s3)) * scale;
        if (s > mx) {
          float corr = __expf(mx - s);
          l *= corr;
#pragma unroll
          for (int d = 0; d < 40; ++d) acc[d] *= corr;
          mx = s;
        }
        float p = __expf(s - mx);
        l += p;
        const float4* vr = (const float4*)&vs[t][0];
#pragma unroll
        for (int k = 0; k < 10; ++k) {
          float4 v4 = vr[k];
          acc[4 * k] += p * v4.x; acc[4 * k + 1] += p * v4.y;
          acc[4 * k + 2] += p * v4.z; acc[4 * k + 3] += p * v4.w;
        }
      }
      __syncthreads();                           // QB4: chunk consumed
    }

    // ---- finalize (per lane, no merge) + FFN via w2o ----
    float linv = 1.f / l;
#pragma unroll
    for (int d = 0; d < 40; ++d) acc[d] *= linv;   // acc = lat
    float lat2[40];
#pragma unroll 1
    for (int e = 0; e < 40; ++e) {
      const float* r = ow + e * 40;                // uniform -> broadcast
      float s = 0.f;
#pragma unroll
      for (int d = 0; d < 40; ++d) s += acc[d] * r[d];
      lat2[e] = ob[e] + s;
    }
    float hh[40];
    {
      float m = 0.f;
#pragma unroll
      for (int d = 0; d < 40; ++d) m += lat2[d];
      m *= (1.f / 40.f);
      float var = 0.f;
#pragma unroll
      for (int d = 0; d < 40; ++d) { float dv = lat2[d] - m; var += dv * dv; }
      float rstd = rsqrtf(var * (1.f / 40.f) + 1e-5f);
#pragma unroll
      for (int d = 0; d < 40; ++d)
        hh[d] = (lat2[d] - m) * rstd * flw[d] + flb[d];
    }
    float r = outb[0];
#pragma unroll
    for (int d = 0; d < 40; ++d)
      r += (lat2[d] + b2[d]) * outw[d];
#pragma unroll 1
    for (int e = 0; e < 160; ++e) {
      const float* r1 = w1 + e * 40;               // uniform -> broadcast
      const float* r2 = w1 + (160 + e) * 40;
      float s0 = 0.f, s1 = 0.f;
#pragma unroll
      for (int d = 0; d < 40; ++d) { s0 += hh[d] * r1[d]; s1 += hh[d] * r2[d]; }
      float x1 = s0 + b1[e];
      float g = s1 + b1[160 + e];
      float tv = x1 * (0.5f * g * (1.f + erff(g * 0.70710678118654752f)));
      r += tv * w2o[e];
    }
    if (qvalid) out[n] = r;
    return;
  }

  // ---------------- layer blocks: R9 mamba loop (byte-identical) -----------
  const int layer = blockIdx.x;

  __shared__ float xin[160];
  __shared__ float xz[640];
  __shared__ float xs[320];
  __shared__ float dbc[144];        // stride 36
  __shared__ float yb[320];
  __shared__ float xhist[240];      // conv tail

  const int e_in = tid % 160;
  const int tA = tid / 160;
  float w_in_r[40];                 // in_proj row with rmsnorm weight folded
  {
    const float4* g = (const float4*)(g_in_w + layer * 6400 + e_in * 40);
    const float4* nw = (const float4*)(g_norm_w + layer * 40);
#pragma unroll
    for (int k = 0; k < 10; ++k) {
      float4 v = g[k];
      float4 n = nw[k];
      w_in_r[4 * k] = v.x * n.x; w_in_r[4 * k + 1] = v.y * n.y;
      w_in_r[4 * k + 2] = v.z * n.z; w_in_r[4 * k + 3] = v.w * n.w;
    }
  }
  const int d_c = tid % 80;
  const int t_c = tid / 80;
  float cw[4]; float cb;
  {
    float4 v = *(const float4*)(g_conv_w + layer * 320 + d_c * 4);
    cw[0] = v.x; cw[1] = v.y; cw[2] = v.z; cw[3] = v.w;
    cb = g_conv_b[layer * 80 + d_c];
  }
  const int halfp = tid & 1;
  const int p_x = tid >> 1;              // <140 active for x_proj
  const int t_x = p_x / 35, e_x = p_x % 35;
  float w_xp_r[40];
  if (p_x < 140) {
    const float4* g = (const float4*)(g_xp_w + layer * 2800 + e_x * 80 + halfp * 40);
#pragma unroll
    for (int k = 0; k < 10; ++k) {
      float4 v = g[k];
      w_xp_r[4 * k] = v.x; w_xp_r[4 * k + 1] = v.y;
      w_xp_r[4 * k + 2] = v.z; w_xp_r[4 * k + 3] = v.w;
    }
  }
  const int d_ch = tid >> 2;
  const int qq = tid & 3;
  float negA[4], hst[4];
  {
    float4 v = *(const float4*)(g_alog + layer * 1280 + tid * 4);
    negA[0] = -__expf(v.x); negA[1] = -__expf(v.y);
    negA[2] = -__expf(v.z); negA[3] = -__expf(v.w);
    hst[0] = hst[1] = hst[2] = hst[3] = 0.f;
  }
  const float dtw0 = g_dt_w[layer * 240 + d_ch * 3 + 0];
  const float dtw1 = g_dt_w[layer * 240 + d_ch * 3 + 1];
  const float dtw2 = g_dt_w[layer * 240 + d_ch * 3 + 2];
  const float dtb = g_dt_b[layer * 80 + d_ch];
  const float wD = g_D[layer * 80 + d_ch];
  const int p_o = tid >> 1;
  const int t_o = p_o / 40, e_o = p_o % 40;
  float w_out_r[40];
  {
    const float4* g = (const float4*)(g_out_w + layer * 3200 + e_o * 80 + halfp * 40);
#pragma unroll
    for (int k = 0; k < 10; ++k) {
      float4 v = g[k];
      w_out_r[4 * k] = v.x; w_out_r[4 * k + 1] = v.y;
      w_out_r[4 * k + 2] = v.z; w_out_r[4 * k + 3] = v.w;
    }
  }

  for (int i = tid; i < 240; i += TPB1) xhist[i] = 0.f;
  __syncthreads();

  const float* src = (layer == 0) ? mash : ((layer & 1) ? xb0 : xb1);
  float* dst = (layer & 1) ? xb1 : xb0;
  int* flag_prev = flags + (layer - 1) * 16;
  int* flag_cur = flags + layer * 16;

  for (int c = 0; c < NCHUNK; ++c) {
    const int t0 = c * CH;

    // ---- Phase A: ordered acquire + in_proj (rmsnorm folded) ----
    if (layer == 0) {
#pragma unroll
      for (int tt = 0; tt < 2; ++tt) {
        const int t = tA + 2 * tt;
        const float4* sp = (const float4*)(src + (t0 + t) * 40);
        float ss = 0.f, sd = 0.f;
#pragma unroll
        for (int k = 0; k < 10; ++k) {
          float4 v = sp[k];
          ss += v.x * v.x + v.y * v.y + v.z * v.z + v.w * v.w;
          sd += w_in_r[4 * k] * v.x + w_in_r[4 * k + 1] * v.y
              + w_in_r[4 * k + 2] * v.z + w_in_r[4 * k + 3] * v.w;
        }
        xz[t * 160 + e_in] = sd * rsqrtf(ss * (1.f / 40.f) + 1e-5f);
      }
      if (tid < 160) xin[tid] = src[t0 * 40 + tid];
    } else {
      // every wave polls (wave-uniform); loads are program-ordered after the
      // observed flag -> guaranteed fresh (producer B5-drained before flag)
      while (__hip_atomic_load(flag_prev, __ATOMIC_RELAXED,
                               __HIP_MEMORY_SCOPE_AGENT) <= c)
        __builtin_amdgcn_s_sleep(1);
#pragma unroll
      for (int tt = 0; tt < 2; ++tt) {
        const int t = tA + 2 * tt;
        const u64* sp = (const u64*)(src + (t0 + t) * 40);
        float ss = 0.f, sd = 0.f;
#pragma unroll
        for (int k = 0; k < 20; ++k) {
          u64 a = __hip_atomic_load(sp + k, __ATOMIC_RELAXED,
                                    __HIP_MEMORY_SCOPE_AGENT);
          float v0 = unplo(a), v1 = unphi(a);
          ss += v0 * v0 + v1 * v1;
          sd += w_in_r[2 * k] * v0 + w_in_r[2 * k + 1] * v1;
        }
        xz[t * 160 + e_in] = sd * rsqrtf(ss * (1.f / 40.f) + 1e-5f);
      }
      if (tid < 80) {
        u64 a = __hip_atomic_load((const u64*)(src + t0 * 40) + tid,
                                  __ATOMIC_RELAXED, __HIP_MEMORY_SCOPE_AGENT);
        xin[2 * tid] = unplo(a);
        xin[2 * tid + 1] = unphi(a);
      }
    }
    __syncthreads();                                   // B1: xz, xin ready

    // ---- causal depthwise conv(4) + silu ----
    {
      float acc = cb;
#pragma unroll
      for (int j = 0; j < 4; ++j) {
        int lt = t_c - 3 + j;
        float xv = (lt >= 0) ? xz[lt * 160 + d_c] : xhist[(lt + 3) * 80 + d_c];
        acc += cw[j] * xv;
      }
      xs[t_c * 80 + d_c] = acc / (1.f + __expf(-acc));
    }
    __syncthreads();                                   // B2: xs ready

    // ---- x_proj: pair half-dots + shfl merge; idle threads refresh xhist ----
    if (p_x < 140) {
      const float4* xp = (const float4*)&xs[t_x * 80 + halfp * 40];
      float s = 0.f;
#pragma unroll
      for (int k = 0; k < 10; ++k) {
        float4 v = xp[k];
        s += w_xp_r[4 * k] * v.x + w_xp_r[4 * k + 1] * v.y
           + w_xp_r[4 * k + 2] * v.z + w_xp_r[4 * k + 3] * v.w;
      }
      s += __shfl_xor(s, 1);
      if (halfp == 0) dbc[t_x * 36 + e_x] = s;
    } else {
      for (int k = tid - 280; k < 240; k += 40)
        xhist[k] = xz[(1 + k / 80) * 160 + (k % 80)];
    }
    __syncthreads();                                   // B3: dbc ready

    // ---- selective scan; dt inline; state in regs ----
#pragma unroll
    for (int t = 0; t < CH; ++t) {
      const float* db = &dbc[t * 36];
      float sdt = dtb + db[0] * dtw0 + db[1] * dtw1 + db[2] * dtw2;
      float dtval = (sdt > 15.f) ? sdt : __logf(1.f + __expf(sdt));
      float xval = xs[t * 80 + d_ch];
      float part = 0.f;
#pragma unroll
      for (int j = 0; j < 4; ++j) {
        int s_i = qq * 4 + j;
        float Bv = db[3 + s_i];
        float Cv = db[19 + s_i];
        hst[j] = __expf(dtval * negA[j]) * hst[j] + dtval * Bv * xval;
        part += hst[j] * Cv;
      }
      part += __shfl_xor(part, 1);
      part += __shfl_xor(part, 2);
      if (qq == 0) {
        float yv = part + xval * wD;
        float z = xz[t * 160 + 80 + d_ch];
        yb[t * 80 + d_ch] = yv * z / (1.f + __expf(-z));
      }
    }
    __syncthreads();                                   // B4: yb ready

    // ---- out_proj + residual -> paired dwordx2 coherent stores ----
    {
      const float4* yp = (const float4*)&yb[t_o * 80 + halfp * 40];
      float s = 0.f;
#pragma unroll
      for (int k = 0; k < 10; ++k) {
        float4 v = yp[k];
        s += w_out_r[4 * k] * v.x + w_out_r[4 * k + 1] * v.y
           + w_out_r[4 * k + 2] * v.z + w_out_r[4 * k + 3] * v.w;
      }
      s += __shfl_xor(s, 1);
      float r = xin[p_o] + s;          // valid on pair leaders (halfp==0)
      float r2 = __shfl_xor(r, 2);     // leader tid+2's value (p_o+1)
      if ((tid & 3) == 0)              // even p_o leaders store the pair
        __hip_atomic_store((u64*)(dst + t0 * 40 + p_o), pack2(r, r2),
                           __ATOMIC_RELAXED, __HIP_MEMORY_SCOPE_AGENT);
    }
    __syncthreads();        // B5: drains vmcnt -> all stores acked at IF$
    if (tid == 0)
      __hip_atomic_store(flag_cur, c + 1, __ATOMIC_RELAXED,
                         __HIP_MEMORY_SCOPE_AGENT);
    if (layer == 255 && tid < 8)   // replicate for QA pollers (8 lines)
      __hip_atomic_store(flags + 4096 + 32 * tid, c + 1,
                         __ATOMIC_RELAXED, __HIP_MEMORY_SCOPE_AGENT);
  }
}

// ---- context side of cross-attn (FALLBACK path only) ----
__global__ __launch_bounds__(64) void kv_kernel(
    const float* __restrict__ xfin,
    const float* __restrict__ lnc_w, const float* __restrict__ lnc_b,
    const float* __restrict__ kv_w,
    float* __restrict__ kbuf, float* __restrict__ vbuf)
{
  int t = blockIdx.x;
  int lane = threadIdx.x;
  float x = (lane < 40) ? xfin[t * 40 + lane] : 0.f;
  float s = x;
#pragma unroll
  for (int o = 32; o >= 1; o >>= 1) s += __shfl_xor(s, o);
  float m = s * (1.f / 40.f);
  float dv = (lane < 40) ? (x - m) : 0.f;
  float v2 = dv * dv;
#pragma unroll
  for (int o = 32; o >= 1; o >>= 1) v2 += __shfl_xor(v2, o);
  float rstd = rsqrtf(v2 * (1.f / 40.f) + 1e-5f);
  __shared__ float cn[40];
  if (lane < 40) cn[lane] = dv * rstd * lnc_w[lane] + lnc_b[lane];
  __syncthreads();
  for (int e = lane; e < 80; e += 64) {
    float acc = 0.f;
#pragma unroll
    for (int d = 0; d < 40; ++d) acc += cn[d] * kv_w[e * 40 + d];
    if (e < 40) kbuf[t * 40 + e] = acc;
    else vbuf[t * 40 + (e - 40)] = acc;
  }
}

// ---- fallback query (R8, PE inside) for small ws ----
__global__ __launch_bounds__(256) void query_kernel_fb(
    const float* __restrict__ qry,
    const float* __restrict__ pe_w, const float* __restrict__ pe_b,
    const float* __restrict__ lnq_w, const float* __restrict__ lnq_b,
    const float* __restrict__ qw,
    const float* __restrict__ ow, const float* __restrict__ ob,
    const float* __restrict__ flw, const float* __restrict__ flb,
    const float* __restrict__ w1, const float* __restrict__ b1,
    const float* __restrict__ w2, const float* __restrict__ b2,
    const float* __restrict__ outw, const float* __restrict__ outb,
    const float* __restrict__ kbuf, const float* __restrict__ vbuf,
    float* __restrict__ out)
{
  const int tid = threadIdx.x;
  const int h = __builtin_amdgcn_readfirstlane((tid >> 6) & 1);
  const int pj = tid >> 7;
  const int lane = tid & 63;
  const int n = blockIdx.x * 128 + pj * 64 + lane;
  const int ptn = tid ^ 64;
  __shared__ float colbuf[40 * 256];
  __shared__ float redm[256], redl[256];

  const float qx = qry[n * 3 + 0], qy = qry[n * 3 + 1], qz = qry[n * 3 + 2];
  float qp[40];
#pragma unroll
  for (int d = 0; d < 40; ++d) qp[d] = 0.f;
#pragma unroll
  for (int jj = 0; jj < 4; ++jj) {
    const int j = h * 4 + jj;
    float f = 3.14159265358979323846f * (float)(1 << j);
    float sx, cx, sy, cy, sz, cz;
    __sincosf(qx * f, &sx, &cx);
    __sincosf(qy * f, &sy, &cy);
    __sincosf(qz * f, &sz, &cz);
#pragma unroll
    for (int d = 0; d < 40; ++d) {
      const float* r = pe_w + d * 51;
      qp[d] += sx * r[j] + sy * r[j + 8] + sz * r[j + 16]
             + cx * r[j + 24] + cy * r[j + 32] + cz * r[j + 40];
    }
  }
#pragma unroll
  for (int d = 0; d < 40; ++d) colbuf[d * 256 + tid] = qp[d];
  __syncthreads();
  float qe[40];
#pragma unroll
  for (int d = 0; d < 40; ++d) {
    const float* r = pe_w + d * 51;
    qe[d] = pe_b[d] + qp[d] + colbuf[d * 256 + ptn]
          + qx * r[48] + qy * r[49] + qz * r[50];
  }
  __syncthreads();
  float qn[40];
  {
    float m = 0.f;
#pragma unroll
    for (int d = 0; d < 40; ++d) m += qe[d];
    m *= (1.f / 40.f);
    float var = 0.f;
#pragma unroll
    for (int d = 0; d < 40; ++d) { float dv = qe[d] - m; var += dv * dv; }
    float rstd = rsqrtf(var * (1.f / 40.f) + 1e-5f);
#pragma unroll
    for (int d = 0; d < 40; ++d) qn[d] = (qe[d] - m) * rstd * lnq_w[d] + lnq_b[d];
  }
  float qnh[20];
#pragma unroll
  for (int dd = 0; dd < 20; ++dd) qnh[dd] = h ? qn[dd + 20] : qn[dd];
  float q[40];
#pragma unroll
  for (int e = 0; e < 40; ++e) q[e] = 0.f;
#pragma unroll 1
  for (int dd = 0; dd < 20; ++dd) {
    const float qv = qnh[dd];
    const int d = h * 20 + dd;
#pragma unroll
    for (int e = 0; e < 40; ++e) q[e] += qv * qw[e * 40 + d];
  }
#pragma unroll
  for (int e = 0; e < 40; ++e) colbuf[e * 256 + tid] = q[e];
  __syncthreads();
#pragma unroll
  for (int e = 0; e < 40; ++e) q[e] += colbuf[e * 256 + ptn];
  __syncthreads();

  float acc[40];
#pragma unroll
  for (int d = 0; d < 40; ++d) acc[d] = 0.f;
  float mx = -1e30f, l = 0.f;
  const float scale = 0.15811388300841897f;
  const int tbeg = h * 200, tend = tbeg + 200;
#pragma unroll 1
  for (int t = tbeg; t < tend; ++t) {
    const float4* kr = (const float4*)(kbuf + t * 40);
    float s0 = 0.f, s1 = 0.f, s2 = 0.f, s3 = 0.f;
#pragma unroll
    for (int k = 0; k < 10; ++k) {
      float4 k4 = kr[k];
      s0 += q[4 * k] * k4.x; s1 += q[4 * k + 1] * k4.y;
      s2 += q[4 * k + 2] * k4.z; s3 += q[4 * k + 3] * k4.w;
    }
    float s = ((s0 + s1) + (s2 + s3)) * scale;
    if (s > mx) {
      float corr = __expf(mx - s);
      l *= corr;
#pragma unroll
      for (int d = 0; d < 40; ++d) acc[d] *= corr;
      mx = s;
    }
    float p = __expf(s - mx);
    l += p;
    const float4* vr = (const float4*)(vbuf + t * 40);
#pragma unroll
    for (int k = 0; k < 10; ++k) {
      float4 v4 = vr[k];
      acc[4 * k] += p * v4.x; acc[4 * k + 1] += p * v4.y;
      acc[4 * k + 2] += p * v4.z; acc[4 * k + 3] += p * v4.w;
    }
  }
#pragma unroll
  for (int d = 0; d < 40; ++d) colbuf[d * 256 + tid] = acc[d];
  redm[tid] = mx; redl[tid] = l;
  __syncthreads();
  float lat[40];
  {
    float m2 = redm[ptn];
    float l2 = redl[ptn];
    float nm = fmaxf(mx, m2);
    float a = __expf(mx - nm), b = __expf(m2 - nm);
    float lm = l * a + l2 * b;
    float linv = 1.f / lm;
#pragma unroll
    for (int d = 0; d < 40; ++d)
      lat[d] = (acc[d] * a + colbuf[d * 256 + ptn] * b) * linv;
  }
  __syncthreads();
  float lath[20];
#pragma unroll
  for (int dd = 0; dd < 20; ++dd) lath[dd] = h ? lat[dd + 20] : lat[dd];
  float lp[40];
#pragma unroll
  for (int e = 0; e < 40; ++e) lp[e] = 0.f;
#pragma unroll 1
  for (int dd = 0; dd < 20; ++dd) {
    const float lv = lath[dd];
    const int d = h * 20 + dd;
#pragma unroll
    for (int e = 0; e < 40; ++e) lp[e] += lv * ow[e * 40 + d];
  }
#pragma unroll
  for (int e = 0; e < 40; ++e) colbuf[e * 256 + tid] = lp[e];
  __syncthreads();
  float lat2[40];
#pragma unroll
  for (int e = 0; e < 40; ++e) lat2[e] = ob[e] + lp[e] + colbuf[e * 256 + ptn];
  __syncthreads();
  float hh[40];
  {
    float m = 0.f;
#pragma unroll
    for (int d = 0; d < 40; ++d) m += lat2[d];
    m *= (1.f / 40.f);
    float var = 0.f;
#pragma unroll
    for (int d = 0; d < 40; ++d) { float dv = lat2[d] - m; var += dv * dv; }
    float rstd = rsqrtf(var * (1.f / 40.f) + 1e-5f);
#pragma unroll
    for (int d = 0; d < 40; ++d) hh[d] = (lat2[d] - m) * rstd * flw[d] + flb[d];
  }
  float ff[40];
#pragma unroll
  for (int d = 0; d < 40; ++d) ff[d] = 0.f;
#pragma unroll 1
  for (int ee = 0; ee < 80; ++ee) {
    const int e = h * 80 + ee;
    const float* r1 = w1 + e * 40;
    const float* r2 = w1 + (160 + e) * 40;
    float s0 = 0.f, s1 = 0.f;
#pragma unroll
    for (int d = 0; d < 40; ++d) { s0 += hh[d] * r1[d]; s1 += hh[d] * r2[d]; }
    float x1 = s0 + b1[e];
    float g = s1 + b1[160 + e];
    float tv = x1 * (0.5f * g * (1.f + erff(g * 0.70710678118654752f)));
#pragma unroll
    for (int d = 0; d < 40; ++d) ff[d] += tv * w2[d * 160 + e];
  }
#pragma unroll
  for (int d = 0; d < 40; ++d) colbuf[d * 256 + tid] = ff[d];
  __syncthreads();
  float r = outb[0];
#pragma unroll
  for (int d = 0; d < 40; ++d) {
    float f = ff[d] + colbuf[d * 256 + ptn] + b2[d];
    r += (lat2[d] + f) * outw[d];
  }
  if (h == 0) out[n] = r;
}

extern "C" void kernel_launch(void* const* d_in, const int* in_sizes, int n_in,
                              void* d_out, int out_size, void* d_ws, size_t ws_size,
                              hipStream_t stream) {
  const float* mash   = (const float*)d_in[0];
  const float* qry    = (const float*)d_in[1];
  const float* lnw    = (const float*)d_in[2];
  const float* linw   = (const float*)d_in[3];
  const float* lconvw = (const float*)d_in[4];
  const float* lconvb = (const float*)d_in[5];
  const float* lxpw   = (const float*)d_in[6];
  const float* ldtw   = (const float*)d_in[7];
  const float* ldtb   = (const float*)d_in[8];
  const float* lAlog  = (const float*)d_in[9];
  const float* lD     = (const float*)d_in[10];
  const float* loutw  = (const float*)d_in[11];
  const float* pew    = (const float*)d_in[12];
  const float* peb    = (const float*)d_in[13];
  const float* lnqw   = (const float*)d_in[14];
  const float* lnqb   = (const float*)d_in[15];
  const float* lncw   = (const float*)d_in[16];
  const float* lncb   = (const float*)d_in[17];
  const float* qw     = (const float*)d_in[18];
  const float* kvw    = (const float*)d_in[19];
  const float* oww    = (const float*)d_in[20];
  const float* owb    = (const float*)d_in[21];
  const float* flnw   = (const float*)d_in[22];
  const float* flnb   = (const float*)d_in[23];
  const float* w1     = (const float*)d_in[24];
  const float* b1     = (const float*)d_in[25];
  const float* w2     = (const float*)d_in[26];
  const float* b2     = (const float*)d_in[27];
  const float* outw   = (const float*)d_in[28];
  const float* outb   = (const float*)d_in[29];

  // ws layout (floats): xb0[16000] xb1[16000] k[16000] v[16000]
  //                     flags[4352 ints incl. 256-int replica region]
  //                     qstore[40*65536]
  float* wsf = (float*)d_ws;
  float* xb0 = wsf;
  float* xb1 = wsf + 16000;
  float* kbuf = wsf + 32000;
  float* vbuf = wsf + 48000;
  int* flags = (int*)(wsf + 64000);
  float* qstore = wsf + 68352;
  const size_t needed = (size_t)68352 * 4 + (size_t)40 * 65536 * 4;
  const bool pre = ws_size >= needed;   // constant across calls -> capture-safe

  hipLaunchKernelGGL(init_flags, dim3(17), dim3(256), 0, stream, flags);
  // 256 layer blocks + (pre ? NPE PE blocks + NQA QA blocks : 0)
  hipLaunchKernelGGL(mamba_pipe, dim3(pre ? 256 + NPE + NQA : 256), dim3(TPB1),
                     0, stream,
                     mash, lnw, linw, lconvw, lconvb, lxpw, ldtw, ldtb, lAlog,
                     lD, loutw, xb0, xb1, flags,
                     qry, pew, peb, lnqw, lnqb, qw, qstore,
                     lncw, lncb, kvw, oww, owb, flnw, flnb,
                     w1, b1, w2, b2, outw, outb, (float*)d_out);
  if (!pre) {
    // layer 255 (odd) writes xb1
    hipLaunchKernelGGL(kv_kernel, dim3(400), dim3(64), 0, stream,
                       xb1, lncw, lncb, kvw, kbuf, vbuf);
    hipLaunchKernelGGL(query_kernel_fb, dim3(512), dim3(256), 0, stream,
                       qry, pew, peb, lnqw, lnqb, qw, oww, owb, flnw, flnb,
                       w1, b1, w2, b2, outw, outb, kbuf, vbuf, (float*)d_out);
  }
}